// Round 10
// baseline (471.971 us; speedup 1.0000x reference)
//
#include <hip/hip_runtime.h>
#include <stdint.h>

#define BATCH 4
#define NPTS 8192
#define KNN_K 16
#define GRID 24
#define NCELL (GRID * GRID * GRID)  // 13824
#define NCELLP (NCELL + 8)          // offs stride (sentinel slot)

typedef unsigned long long u64;
typedef unsigned short u16;

// ws layout (bytes)
#define WS_IDX 0u          // u16[4*8192*16]            = 1,048,576
#define WS_LT 1048576u     // float[4*8192*192]         = 25,165,824
#define WS_CNT 26214400u   // int[4*13824]              = 221,184
#define WS_OFF 26435584u   // int[4*13832]              = 221,312
#define WS_CUR 26656896u   // int[4*13824]              = 221,184
#define WS_SP 26878080u    // float4[4*8192]            = 524,288
#define WS_GP 27402368u    // float[4*8]                = 128
#define WS_SIDX 27402496u  // u16[4*8192]               = 65,536

__device__ __forceinline__ int cellof(float v, float o, float invs) {
  int c = (int)((v - o) * invs);
  return c < GRID - 1 ? c : GRID - 1;
}

// ---------------------------------------------------------------- K0: bbox + zero counters
__global__ __launch_bounds__(256) void k_minmax(const float4* __restrict__ xytp,
                                                float* __restrict__ gp,
                                                int* __restrict__ cnt) {
  const int b = blockIdx.x, t = threadIdx.x;
  for (int c = t; c < NCELL; c += 256) cnt[b * NCELL + c] = 0;
  const float4* pb = xytp + (b << 13);
  float mnx = INFINITY, mny = INFINITY, mnz = INFINITY;
  float mxx = -INFINITY, mxy = -INFINITY, mxz = -INFINITY;
  for (int i = t; i < NPTS; i += 256) {
    float4 p = pb[i];
    mnx = fminf(mnx, p.x); mny = fminf(mny, p.y); mnz = fminf(mnz, p.z);
    mxx = fmaxf(mxx, p.x); mxy = fmaxf(mxy, p.y); mxz = fmaxf(mxz, p.z);
  }
#pragma unroll
  for (int d = 1; d < 64; d <<= 1) {
    mnx = fminf(mnx, __shfl_xor(mnx, d)); mny = fminf(mny, __shfl_xor(mny, d));
    mnz = fminf(mnz, __shfl_xor(mnz, d)); mxx = fmaxf(mxx, __shfl_xor(mxx, d));
    mxy = fmaxf(mxy, __shfl_xor(mxy, d)); mxz = fmaxf(mxz, __shfl_xor(mxz, d));
  }
  __shared__ float red[4][6];
  const int lane = t & 63, wv = t >> 6;
  if (lane == 0) {
    red[wv][0] = mnx; red[wv][1] = mny; red[wv][2] = mnz;
    red[wv][3] = mxx; red[wv][4] = mxy; red[wv][5] = mxz;
  }
  __syncthreads();
  if (t == 0) {
    for (int w = 1; w < 4; ++w) {
      red[0][0] = fminf(red[0][0], red[w][0]);
      red[0][1] = fminf(red[0][1], red[w][1]);
      red[0][2] = fminf(red[0][2], red[w][2]);
      red[0][3] = fmaxf(red[0][3], red[w][3]);
      red[0][4] = fmaxf(red[0][4], red[w][4]);
      red[0][5] = fmaxf(red[0][5], red[w][5]);
    }
    float rmax = fmaxf(red[0][3] - red[0][0],
                       fmaxf(red[0][4] - red[0][1], red[0][5] - red[0][2]));
    float s = rmax / (float)GRID;
    float* g = gp + b * 8;
    g[0] = red[0][0]; g[1] = red[0][1]; g[2] = red[0][2];
    g[3] = s; g[4] = 1.0f / s;
  }
}

// ---------------------------------------------------------------- K2: count
__global__ __launch_bounds__(256) void k_count(const float4* __restrict__ xytp,
                                               const float* __restrict__ gp,
                                               int* __restrict__ cnt) {
  int i = blockIdx.x * 256 + threadIdx.x;
  int b = i >> 13;
  const float* g = gp + b * 8;
  float4 p = xytp[i];
  int cx = cellof(p.x, g[0], g[4]);
  int cy = cellof(p.y, g[1], g[4]);
  int cz = cellof(p.z, g[2], g[4]);
  atomicAdd(&cnt[b * NCELL + (cz * GRID + cy) * GRID + cx], 1);
}

// ---------------------------------------------------------------- K3: exclusive scan
// offs has stride NCELLP with offs[b*NCELLP + NCELL] = NPTS sentinel, so
// end(cell c) == offs[c+1] works for every cell including the last.
__global__ __launch_bounds__(1024) void k_scan(const int* __restrict__ cnt,
                                               int* __restrict__ offs,
                                               int* __restrict__ curs) {
  __shared__ int wsum[16];
  const int b = blockIdx.x, t = threadIdx.x;
  const int base = b * NCELL;
  const int base2 = b * NCELLP;
  const int lo = t * 14;
  const int hi = lo + 14 < NCELL ? lo + 14 : NCELL;
  int s = 0;
  for (int c = lo; c < hi; ++c) s += cnt[base + c];
  const int lane = t & 63, wv = t >> 6;
  int v = s;
#pragma unroll
  for (int d = 1; d < 64; d <<= 1) {
    int u = __shfl_up(v, d);
    if (lane >= d) v += u;
  }
  if (lane == 63) wsum[wv] = v;
  __syncthreads();
  if (wv == 0 && lane < 16) {
    int x = wsum[lane];
#pragma unroll
    for (int d = 1; d < 16; d <<= 1) {
      int u = __shfl_up(x, d, 16);
      if (lane >= d) x += u;
    }
    wsum[lane] = x;
  }
  __syncthreads();
  int excl = (wv > 0 ? wsum[wv - 1] : 0) + v - s;
  for (int c = lo; c < hi; ++c) {
    offs[base2 + c] = excl;
    curs[base + c] = excl;
    excl += cnt[base + c];
  }
  if (hi == NCELL) offs[base2 + NCELL] = excl;  // == NPTS
}

// ---------------------------------------------------------------- K4: scatter (cell-sorted points, sq in .w, idx in sidx)
__global__ __launch_bounds__(256) void k_scatter(const float4* __restrict__ xytp,
                                                 const float* __restrict__ gp,
                                                 int* __restrict__ curs,
                                                 float4* __restrict__ spts,
                                                 u16* __restrict__ sidx) {
  int i = blockIdx.x * 256 + threadIdx.x;
  int b = i >> 13, n = i & 8191;
  const float* g = gp + b * 8;
  float4 p = xytp[i];
  int cx = cellof(p.x, g[0], g[4]);
  int cy = cellof(p.y, g[1], g[4]);
  int cz = cellof(p.z, g[2], g[4]);
  int pos = atomicAdd(&curs[b * NCELL + (cz * GRID + cy) * GRID + cx], 1);
  float sq = fmaf(p.z, p.z, fmaf(p.y, p.y, p.x * p.x));
  spts[(b << 13) + pos] = make_float4(p.x, p.y, p.z, sq);
  sidx[(b << 13) + pos] = (u16)n;
}

// ---------------------------------------------------------------- K5: grid KNN query
// R19 = R18 (one query per wave) + UNIFORM-TRIP dealing loop.
// R18 bug: `for (vidx = lane; vidx < total; vidx += 64)` gave lanes
// different trip counts; on the final partial iteration the exited
// lanes are EXEC=0 and the binary search's __shfl read their (inactive)
// registers -> ds_bpermute from an inactive lane is UNDEFINED on CDNA
// -> garbage segment bases for the last total%64 candidates of every
// batch.  Fix: iterate vb=0,64,..<total with ALL lanes active; binary
// search + __shfl(base,e) run unconditionally (sources always active);
// only the lane-local gather+INSERTC is guarded by vidx<total.
// Everything else identical to R18 (prefix-sum concat dealing, wave-
// uniform count-stop, 6-level bitonic merge, no LDS).
#define INSERTC(Af, OI)                                                      \
  {                                                                          \
    float dot = q.x * (Af).x;                                                \
    dot = fmaf(q.y, (Af).y, dot);                                            \
    dot = fmaf(q.z, (Af).z, dot);                                            \
    float d2 = (qsq + (Af).w) - 2.0f * dot;                                  \
    unsigned u = __float_as_uint(d2);                                        \
    u ^= (0x80000000u | (unsigned)((int)u >> 31));                           \
    u64 key = ((u64)u << 32) | (OI);                                         \
    if (key < lst[15]) {                                                     \
      u64 x = key;                                                           \
      _Pragma("unroll") for (int p = 0; p < 16; ++p) {                       \
        bool sw = x < lst[p];                                                \
        u64 a = lst[p];                                                      \
        lst[p] = sw ? x : a;                                                 \
        x = sw ? a : x;                                                      \
      }                                                                      \
    }                                                                        \
  }

#define CSWAP(ia, ib)                                                        \
  {                                                                          \
    u64 ta = c[ia], tb2 = c[ib];                                             \
    bool sw = ta > tb2;                                                      \
    c[ia] = sw ? tb2 : ta;                                                   \
    c[ib] = sw ? ta : tb2;                                                   \
  }

__global__ __launch_bounds__(256) void k_query(const float4* __restrict__ spts,
                                               const u16* __restrict__ sidx,
                                               const int* __restrict__ offs,
                                               const float* __restrict__ gp,
                                               u16* __restrict__ oidx) {
  const int lane = threadIdx.x & 63;
  const int wave = threadIdx.x >> 6;
  const int qid = blockIdx.x * 4 + wave;  // one query per wave
  const int b = qid >> 13, i = qid & 8191;
  const float4* __restrict__ sp = spts + (b << 13);
  const u16* __restrict__ sx = sidx + (b << 13);
  const int* __restrict__ ob = offs + b * NCELLP;
  const float* g = gp + b * 8;
  float4 q = sp[i];
  const float qsq = q.w;  // sq precomputed
  const unsigned orig = sx[i];
  const int cx = cellof(q.x, g[0], g[4]);
  const int cy = cellof(q.y, g[1], g[4]);
  const int cz = cellof(q.z, g[2], g[4]);
  const float s = g[3];

  u64 lst[16];
#pragma unroll
  for (int p = 0; p < 16; ++p) lst[p] = ~0ULL;

  for (int r = 0; r <= GRID; ++r) {
    const int W = 2 * r + 1;
    const int nent = 2 * W * W;
    for (int cb = 0; cb < nent; cb += 64) {
      // phase A: each lane loads bounds of its own entry (parallel chains)
      int ms0 = 0, ms1 = 0;
      const int eid = cb + lane;
      if (eid < nent) {
        const int rid = eid >> 1, side = eid & 1;
        const int dz = rid / W - r;
        const int dy = rid % W - r;
        const int z2 = cz + dz, y2 = cy + dy;
        if ((unsigned)z2 < GRID && (unsigned)y2 < GRID) {
          const int rowb = (z2 * GRID + y2) * GRID;
          const bool bdry = (dz == -r) || (dz == r) || (dy == -r) || (dy == r);
          if (bdry) {
            if (side == 0) {
              const int xl = cx - r < 0 ? 0 : cx - r;
              const int xh = cx + r > GRID - 1 ? GRID - 1 : cx + r;
              ms0 = ob[rowb + xl];
              ms1 = ob[rowb + xh + 1];
            }
          } else {
            const int x2 = side ? cx + r : cx - r;
            if ((unsigned)x2 < GRID) {
              ms0 = ob[rowb + x2];
              ms1 = ob[rowb + x2 + 1];
            }
          }
        }
      }
      // phase B: concatenate the 64 segments (wave-wide prefix sum),
      // deal flattened range stride-64 with a UNIFORM trip count; all
      // cross-lane ops (binary search, base fetch) run with every lane
      // active; only the gather+insert is predicated.
      const int len = ms1 - ms0;  // >= 0
      int pre = len;
#pragma unroll
      for (int d = 1; d < 64; d <<= 1) {
        int u2 = __shfl_up(pre, d);
        if (lane >= d) pre += u2;
      }
      const int total = __shfl(pre, 63);
      if (total == 0) continue;
      const int base = ms0 - (pre - len);  // ms0 - exclusive_prefix
      for (int vb = 0; vb < total; vb += 64) {
        const int vidx = vb + lane;
        // e = #lanes with inclusive_prefix <= vidx (first seg covering vidx)
        int e = 0;
#pragma unroll
        for (int s2 = 32; s2 >= 1; s2 >>= 1) {
          int pv = __shfl(pre, e + s2 - 1);
          if (pv <= vidx) e += s2;
        }
        const int jb = __shfl(base, e);
        if (vidx < total) {
          const int j = jb + vidx;
          float4 A = sp[j];
          unsigned oi = sx[j];
          INSERTC(A, oi)
        }
      }
    }
    // stop check (R10): count wave candidates with d2 <= (r*s)^2 - eps;
    // >=16 proves union-16th <= Chebyshev bound (exact).
    const float rs = (float)r * s;
    const float T = fmaf(rs, rs, -1e-4f);
    unsigned tu = __float_as_uint(T);
    tu ^= (0x80000000u | (unsigned)((int)tu >> 31));
    int c = 0;
#pragma unroll
    for (int p = 0; p < 16; ++p) c += ((unsigned)(lst[p] >> 32) <= tu) ? 1 : 0;
    c += __shfl_xor(c, 1);
    c += __shfl_xor(c, 2);
    c += __shfl_xor(c, 4);
    c += __shfl_xor(c, 8);
    c += __shfl_xor(c, 16);
    c += __shfl_xor(c, 32);
    if (c >= 16) break;  // wave-uniform break (one query per wave)
  }

  // ---- in-register cross-lane merge (6 bitonic levels across wave) ----
  // Level m: lane pair (l, l^m); keep-min lanes ((l&m)==0) take the 16
  // smallest of the 32 via min(A[p], B[15-p]) (bitonic), then 4-stage
  // clean keeps the kept list sorted.  After m=32, lane 0 = global top-16.
#pragma unroll
  for (int mm = 1; mm <= 32; mm <<= 1) {
    u64 c[16];
    const bool keepmin = (lane & mm) == 0;
#pragma unroll
    for (int p = 0; p < 16; ++p) {
      u64 o = __shfl_xor(lst[15 - p], mm);
      u64 a = lst[p];
      u64 lo = a < o ? a : o;
      u64 hi = a < o ? o : a;
      c[p] = keepmin ? lo : hi;
    }
    CSWAP(0, 8) CSWAP(1, 9) CSWAP(2, 10) CSWAP(3, 11)
    CSWAP(4, 12) CSWAP(5, 13) CSWAP(6, 14) CSWAP(7, 15)
    CSWAP(0, 4) CSWAP(1, 5) CSWAP(2, 6) CSWAP(3, 7)
    CSWAP(8, 12) CSWAP(9, 13) CSWAP(10, 14) CSWAP(11, 15)
    CSWAP(0, 2) CSWAP(1, 3) CSWAP(4, 6) CSWAP(5, 7)
    CSWAP(8, 10) CSWAP(9, 11) CSWAP(12, 14) CSWAP(13, 15)
    CSWAP(0, 1) CSWAP(2, 3) CSWAP(4, 5) CSWAP(6, 7)
    CSWAP(8, 9) CSWAP(10, 11) CSWAP(12, 13) CSWAP(14, 15)
#pragma unroll
    for (int p = 0; p < 16; ++p) lst[p] = c[p];
  }

  if (lane == 0) {  // lane 0 holds the sorted global top-16
    unsigned pk[8];
#pragma unroll
    for (int k = 0; k < 16; k += 2)
      pk[k >> 1] = (unsigned)(lst[k] & 0xFFFFull) |
                   ((unsigned)(lst[k + 1] & 0xFFFFull) << 16);
    unsigned* od = (unsigned*)(oidx + (((size_t)(b << 13) + orig) << 4));
#pragma unroll
    for (int k = 0; k < 8; ++k) od[k] = pk[k];
  }
}

// ---------------------------------------------------------------- K6: lt = feat @ lt_w + lt_b
__global__ __launch_bounds__(256) void k_lt(const float* __restrict__ feat,
                                            const float* __restrict__ ltw,
                                            const float* __restrict__ ltb,
                                            float* __restrict__ lt) {
  __shared__ float sw[64][196];
  __shared__ float sf[32][68];
  const int tid = threadIdx.x;
  const int r0 = blockIdx.x * 32;
#pragma unroll
  for (int i = 0; i < 12; ++i) {
    int v = tid + i * 256;
    float4 w4 = ((const float4*)ltw)[v];
    int row = (v * 4) / 192, col = (v * 4) % 192;
    *(float4*)&sw[row][col] = w4;
  }
#pragma unroll
  for (int i = 0; i < 2; ++i) {
    int v = tid + i * 256;
    int row = v >> 4, c4 = v & 15;
    float4 f4 = ((const float4*)(feat + (size_t)(r0 + row) * 64))[c4];
    *(float4*)&sf[row][c4 * 4] = f4;
  }
  __syncthreads();
  const int r = tid >> 3;
  const int c0 = (tid & 7) * 24;
  float acc[24];
#pragma unroll
  for (int ll = 0; ll < 24; ++ll) acc[ll] = ltb[c0 + ll];
#pragma unroll 4
  for (int j = 0; j < 64; ++j) {
    float f = sf[r][j];
#pragma unroll
    for (int l4 = 0; l4 < 6; ++l4) {
      float4 w4 = *(const float4*)&sw[j][c0 + l4 * 4];
      acc[l4 * 4 + 0] = fmaf(f, w4.x, acc[l4 * 4 + 0]);
      acc[l4 * 4 + 1] = fmaf(f, w4.y, acc[l4 * 4 + 1]);
      acc[l4 * 4 + 2] = fmaf(f, w4.z, acc[l4 * 4 + 2]);
      acc[l4 * 4 + 3] = fmaf(f, w4.w, acc[l4 * 4 + 3]);
    }
  }
  float* orow = lt + (size_t)(r0 + r) * 192 + c0;
#pragma unroll
  for (int l4 = 0; l4 < 6; ++l4)
    *(float4*)&orow[l4 * 4] = make_float4(acc[l4 * 4], acc[l4 * 4 + 1],
                                          acc[l4 * 4 + 2], acc[l4 * 4 + 3]);
}

// ---------------------------------------------------------------- K7: main
// R12: online softmax (no pre/apd/xk arrays), prefetch-1 psi/alp gathers,
// DPP+readlane LN reductions (VALU pipe) instead of __shfl_xor (DS pipe).
// DPP ctrl must be a compile-time constant -> template parameter.
template <int CTRL>
__device__ __forceinline__ float dpp_add_f(float x) {
  int y = __builtin_amdgcn_update_dpp(0, __float_as_int(x), CTRL, 0xf, 0xf,
                                      true);
  return x + __int_as_float(y);
}
// full-wave (64-lane) sum -> wave-uniform via readlane 63.
// row_shr 1/2/4/8: lane15 of each row16 = row sum; row_bcast:15 add:
// lane31 = rows0+1, lane63 = rows2+3; row_bcast:31 add: lane63 = total.
__device__ __forceinline__ float wave_sum64(float x) {
  x = dpp_add_f<0x111>(x);  // row_shr:1
  x = dpp_add_f<0x112>(x);  // row_shr:2
  x = dpp_add_f<0x114>(x);  // row_shr:4
  x = dpp_add_f<0x118>(x);  // row_shr:8
  x = dpp_add_f<0x142>(x);  // row_bcast:15
  x = dpp_add_f<0x143>(x);  // row_bcast:31
  return __int_as_float(__builtin_amdgcn_readlane(__float_as_int(x), 63));
}

__global__ __launch_bounds__(256) void k_main(
    const float4* __restrict__ xytp, const float* __restrict__ lt,
    const u16* __restrict__ knn, const float* __restrict__ pe_w1,
    const float* __restrict__ pe_b1, const float* __restrict__ pe_w2,
    const float* __restrict__ pe_b2, const float* __restrict__ ln_g,
    const float* __restrict__ ln_b, float* __restrict__ out) {
  __shared__ float s_h[4][16][64];
  const int lane = threadIdx.x & 63;
  const int wave = threadIdx.x >> 6;
  const int pid = __builtin_amdgcn_readfirstlane(blockIdx.x * 4 + wave);
  const int b = pid >> 13;
  const int n = pid & 8191;

  float w1c[4];
#pragma unroll
  for (int d = 0; d < 4; ++d) w1c[d] = pe_w1[d * 64 + lane];
  const float b1c = pe_b1[lane];
  float w2c[64];
#pragma unroll
  for (int j = 0; j < 64; ++j) w2c[j] = pe_w2[j * 64 + lane];
  const float b2c = pe_b2[lane];
  const float gc = ln_g[lane], bc = ln_b[lane];

  int nb[16];
#pragma unroll
  for (int k = 0; k < 16; ++k) nb[k] = knn[pid * 16 + k];

  const float* __restrict__ ltb = lt + (size_t)(b << 13) * 192;
  const float vc = ltb[(size_t)n * 192 + lane];

  const float4 qv = xytp[(b << 13) + n];
#pragma unroll
  for (int k = 0; k < 16; ++k) {
    float4 g = xytp[(b << 13) + nb[k]];
    float r0 = qv.x - g.x, r1 = qv.y - g.y, r2 = qv.z - g.z, r3 = qv.w - g.w;
    float h = fmaf(r3, w1c[3],
                   fmaf(r2, w1c[2], fmaf(r1, w1c[1], fmaf(r0, w1c[0], b1c))));
    s_h[wave][k][lane] = fmaxf(h, 0.0f);
  }
  __syncthreads();

  float psi_c = ltb[(size_t)nb[0] * 192 + 64 + lane];
  float alp_c = ltb[(size_t)nb[0] * 192 + 128 + lane];
  float m = -INFINITY, se = 0.f, oacc = 0.f;
#pragma unroll
  for (int k = 0; k < 16; ++k) {
    float psi_n = 0.f, alp_n = 0.f;
    if (k < 15) {  // prefetch next neighbor's psi/alp (distance-1)
      const float* row = ltb + (size_t)nb[k + 1] * 192;
      psi_n = row[64 + lane];
      alp_n = row[128 + lane];
    }
    float acc = b2c;
#pragma unroll
    for (int j4 = 0; j4 < 16; ++j4) {
      float4 h4 = *(const float4*)&s_h[wave][k][j4 * 4];
      acc = fmaf(h4.x, w2c[j4 * 4 + 0], acc);
      acc = fmaf(h4.y, w2c[j4 * 4 + 1], acc);
      acc = fmaf(h4.z, w2c[j4 * 4 + 2], acc);
      acc = fmaf(h4.w, w2c[j4 * 4 + 3], acc);
    }
    const float pre = (vc - psi_c) + acc;
    const float apd = alp_c + acc;
    const float sm = wave_sum64(pre);
    const float ssm = wave_sum64(pre * pre);
    const float mu = sm * 0.015625f;
    const float var = fmaf(ssm, 0.015625f, -mu * mu);
    const float inv = rsqrtf(var + 1e-5f);
    const float x = fmaf((pre - mu) * inv, gc, bc) * 0.125f;
    // online softmax update (first iter: m=-inf -> corr = exp(-inf) = 0)
    const float mn = fmaxf(m, x);
    const float corr = __expf(m - mn);
    const float e = __expf(x - mn);
    se = fmaf(se, corr, e);
    oacc = fmaf(oacc, corr, e * apd);
    m = mn;
    psi_c = psi_n;
    alp_c = alp_n;
  }
  out[(size_t)pid * 64 + lane] = oacc / se;
}

// ---------------------------------------------------------------- launch
extern "C" void kernel_launch(void* const* d_in, const int* in_sizes, int n_in,
                              void* d_out, int out_size, void* d_ws,
                              size_t ws_size, hipStream_t stream) {
  const float4* xytp = (const float4*)d_in[0];
  const float* features = (const float*)d_in[1];
  const float* pe_w1 = (const float*)d_in[2];
  const float* pe_b1 = (const float*)d_in[3];
  const float* pe_w2 = (const float*)d_in[4];
  const float* pe_b2 = (const float*)d_in[5];
  const float* lt_w = (const float*)d_in[6];
  const float* lt_b = (const float*)d_in[7];
  const float* ln_g = (const float*)d_in[8];
  const float* ln_b = (const float*)d_in[9];
  float* out = (float*)d_out;

  char* ws = (char*)d_ws;
  u16* idxbuf = (u16*)(ws + WS_IDX);
  float* lt = (float*)(ws + WS_LT);
  int* cnt = (int*)(ws + WS_CNT);
  int* offs = (int*)(ws + WS_OFF);
  int* curs = (int*)(ws + WS_CUR);
  float4* spts = (float4*)(ws + WS_SP);
  float* gp = (float*)(ws + WS_GP);
  u16* sidx = (u16*)(ws + WS_SIDX);

  k_minmax<<<BATCH, 256, 0, stream>>>(xytp, gp, cnt);
  k_count<<<(BATCH * NPTS) / 256, 256, 0, stream>>>(xytp, gp, cnt);
  k_scan<<<BATCH, 1024, 0, stream>>>(cnt, offs, curs);
  k_scatter<<<(BATCH * NPTS) / 256, 256, 0, stream>>>(xytp, gp, curs, spts,
                                                      sidx);
  k_query<<<(BATCH * NPTS) / 4, 256, 0, stream>>>(spts, sidx, offs, gp,
                                                  idxbuf);
  k_lt<<<(BATCH * NPTS) / 32, 256, 0, stream>>>(features, lt_w, lt_b, lt);
  k_main<<<(BATCH * NPTS) / 4, 256, 0, stream>>>(xytp, lt, idxbuf, pe_w1,
                                                 pe_b1, pe_w2, pe_b2, ln_g,
                                                 ln_b, out);
}

// Round 11
// 428.263 us; speedup vs baseline: 1.1021x; 1.1021x over previous
//
#include <hip/hip_runtime.h>
#include <stdint.h>

#define BATCH 4
#define NPTS 8192
#define KNN_K 16
#define GRID 24
#define NCELL (GRID * GRID * GRID)  // 13824
#define NCELLP (NCELL + 8)          // offs stride (sentinel slot)

typedef unsigned long long u64;
typedef unsigned short u16;

// ws layout (bytes)
#define WS_IDX 0u          // u16[4*8192*16]            = 1,048,576
#define WS_LT 1048576u     // float[4*8192*192]         = 25,165,824
#define WS_CNT 26214400u   // int[4*13824]              = 221,184
#define WS_OFF 26435584u   // int[4*13832]              = 221,312
#define WS_CUR 26656896u   // int[4*13824]              = 221,184
#define WS_SP 26878080u    // float4[4*8192]            = 524,288
#define WS_GP 27402368u    // float[4*8]                = 128
#define WS_SIDX 27402496u  // u16[4*8192]               = 65,536

__device__ __forceinline__ int cellof(float v, float o, float invs) {
  int c = (int)((v - o) * invs);
  return c < GRID - 1 ? c : GRID - 1;
}

// ---------------------------------------------------------------- K0: bbox + zero counters
__global__ __launch_bounds__(256) void k_minmax(const float4* __restrict__ xytp,
                                                float* __restrict__ gp,
                                                int* __restrict__ cnt) {
  const int b = blockIdx.x, t = threadIdx.x;
  for (int c = t; c < NCELL; c += 256) cnt[b * NCELL + c] = 0;
  const float4* pb = xytp + (b << 13);
  float mnx = INFINITY, mny = INFINITY, mnz = INFINITY;
  float mxx = -INFINITY, mxy = -INFINITY, mxz = -INFINITY;
  for (int i = t; i < NPTS; i += 256) {
    float4 p = pb[i];
    mnx = fminf(mnx, p.x); mny = fminf(mny, p.y); mnz = fminf(mnz, p.z);
    mxx = fmaxf(mxx, p.x); mxy = fmaxf(mxy, p.y); mxz = fmaxf(mxz, p.z);
  }
#pragma unroll
  for (int d = 1; d < 64; d <<= 1) {
    mnx = fminf(mnx, __shfl_xor(mnx, d)); mny = fminf(mny, __shfl_xor(mny, d));
    mnz = fminf(mnz, __shfl_xor(mnz, d)); mxx = fmaxf(mxx, __shfl_xor(mxx, d));
    mxy = fmaxf(mxy, __shfl_xor(mxy, d)); mxz = fmaxf(mxz, __shfl_xor(mxz, d));
  }
  __shared__ float red[4][6];
  const int lane = t & 63, wv = t >> 6;
  if (lane == 0) {
    red[wv][0] = mnx; red[wv][1] = mny; red[wv][2] = mnz;
    red[wv][3] = mxx; red[wv][4] = mxy; red[wv][5] = mxz;
  }
  __syncthreads();
  if (t == 0) {
    for (int w = 1; w < 4; ++w) {
      red[0][0] = fminf(red[0][0], red[w][0]);
      red[0][1] = fminf(red[0][1], red[w][1]);
      red[0][2] = fminf(red[0][2], red[w][2]);
      red[0][3] = fmaxf(red[0][3], red[w][3]);
      red[0][4] = fmaxf(red[0][4], red[w][4]);
      red[0][5] = fmaxf(red[0][5], red[w][5]);
    }
    float rmax = fmaxf(red[0][3] - red[0][0],
                       fmaxf(red[0][4] - red[0][1], red[0][5] - red[0][2]));
    float s = rmax / (float)GRID;
    float* g = gp + b * 8;
    g[0] = red[0][0]; g[1] = red[0][1]; g[2] = red[0][2];
    g[3] = s; g[4] = 1.0f / s;
  }
}

// ---------------------------------------------------------------- K2: count
__global__ __launch_bounds__(256) void k_count(const float4* __restrict__ xytp,
                                               const float* __restrict__ gp,
                                               int* __restrict__ cnt) {
  int i = blockIdx.x * 256 + threadIdx.x;
  int b = i >> 13;
  const float* g = gp + b * 8;
  float4 p = xytp[i];
  int cx = cellof(p.x, g[0], g[4]);
  int cy = cellof(p.y, g[1], g[4]);
  int cz = cellof(p.z, g[2], g[4]);
  atomicAdd(&cnt[b * NCELL + (cz * GRID + cy) * GRID + cx], 1);
}

// ---------------------------------------------------------------- K3: exclusive scan
// offs has stride NCELLP with offs[b*NCELLP + NCELL] = NPTS sentinel, so
// end(cell c) == offs[c+1] works for every cell including the last.
__global__ __launch_bounds__(1024) void k_scan(const int* __restrict__ cnt,
                                               int* __restrict__ offs,
                                               int* __restrict__ curs) {
  __shared__ int wsum[16];
  const int b = blockIdx.x, t = threadIdx.x;
  const int base = b * NCELL;
  const int base2 = b * NCELLP;
  const int lo = t * 14;
  const int hi = lo + 14 < NCELL ? lo + 14 : NCELL;
  int s = 0;
  for (int c = lo; c < hi; ++c) s += cnt[base + c];
  const int lane = t & 63, wv = t >> 6;
  int v = s;
#pragma unroll
  for (int d = 1; d < 64; d <<= 1) {
    int u = __shfl_up(v, d);
    if (lane >= d) v += u;
  }
  if (lane == 63) wsum[wv] = v;
  __syncthreads();
  if (wv == 0 && lane < 16) {
    int x = wsum[lane];
#pragma unroll
    for (int d = 1; d < 16; d <<= 1) {
      int u = __shfl_up(x, d, 16);
      if (lane >= d) x += u;
    }
    wsum[lane] = x;
  }
  __syncthreads();
  int excl = (wv > 0 ? wsum[wv - 1] : 0) + v - s;
  for (int c = lo; c < hi; ++c) {
    offs[base2 + c] = excl;
    curs[base + c] = excl;
    excl += cnt[base + c];
  }
  if (hi == NCELL) offs[base2 + NCELL] = excl;  // == NPTS
}

// ---------------------------------------------------------------- K4: scatter (cell-sorted points, sq in .w, idx in sidx)
__global__ __launch_bounds__(256) void k_scatter(const float4* __restrict__ xytp,
                                                 const float* __restrict__ gp,
                                                 int* __restrict__ curs,
                                                 float4* __restrict__ spts,
                                                 u16* __restrict__ sidx) {
  int i = blockIdx.x * 256 + threadIdx.x;
  int b = i >> 13, n = i & 8191;
  const float* g = gp + b * 8;
  float4 p = xytp[i];
  int cx = cellof(p.x, g[0], g[4]);
  int cy = cellof(p.y, g[1], g[4]);
  int cz = cellof(p.z, g[2], g[4]);
  int pos = atomicAdd(&curs[b * NCELL + (cz * GRID + cy) * GRID + cx], 1);
  float sq = fmaf(p.z, p.z, fmaf(p.y, p.y, p.x * p.x));
  spts[(b << 13) + pos] = make_float4(p.x, p.y, p.z, sq);
  sidx[(b << 13) + pos] = (u16)n;
}

// ---------------------------------------------------------------- K5: grid KNN query
// R20: 32-WIDE TEAMS (2 queries per wave) — measured interpolation.
// 16-wide (R17) = 192us latency-bound (VALU 32%, occ 15%); 64-wide
// (R19) = 220us VALU-bound (78%, occ 35%; per-query VALU doubled as
// merge/stop/prefix became per-query instead of lane-parallel-shared).
// 32-wide: chain steps = cands/32 (2x fewer than 16-wide), merge = 5
// bitonic levels shared by 2 queries (~650 wave-instrs/query vs 1500),
// 16384 waves = 2x oversubscription for tail, uniform-trip dealing
// (R19 exactness fix kept).  All cross-lane ops stay inside the
// aligned 32-lane team, so team-divergent break/continue never reads
// inactive lanes (xor masks < 32; shfl targets tb+e).
#define INSERTC(Af, OI)                                                      \
  {                                                                          \
    float dot = q.x * (Af).x;                                                \
    dot = fmaf(q.y, (Af).y, dot);                                            \
    dot = fmaf(q.z, (Af).z, dot);                                            \
    float d2 = (qsq + (Af).w) - 2.0f * dot;                                  \
    unsigned u = __float_as_uint(d2);                                        \
    u ^= (0x80000000u | (unsigned)((int)u >> 31));                           \
    u64 key = ((u64)u << 32) | (OI);                                         \
    if (key < lst[15]) {                                                     \
      u64 x = key;                                                           \
      _Pragma("unroll") for (int p = 0; p < 16; ++p) {                       \
        bool sw = x < lst[p];                                                \
        u64 a = lst[p];                                                      \
        lst[p] = sw ? x : a;                                                 \
        x = sw ? a : x;                                                      \
      }                                                                      \
    }                                                                        \
  }

#define CSWAP(ia, ib)                                                        \
  {                                                                          \
    u64 ta = c[ia], tb2 = c[ib];                                             \
    bool sw = ta > tb2;                                                      \
    c[ia] = sw ? tb2 : ta;                                                   \
    c[ib] = sw ? ta : tb2;                                                   \
  }

__global__ __launch_bounds__(256) void k_query(const float4* __restrict__ spts,
                                               const u16* __restrict__ sidx,
                                               const int* __restrict__ offs,
                                               const float* __restrict__ gp,
                                               u16* __restrict__ oidx) {
  const int lane = threadIdx.x & 63;
  const int l = threadIdx.x & 31;        // team lane
  const int qid = blockIdx.x * 8 + (threadIdx.x >> 5);  // 8 teams/block
  const int b = qid >> 13, i = qid & 8191;
  const int tb = lane & 32;              // team base within wave (0 or 32)
  const float4* __restrict__ sp = spts + (b << 13);
  const u16* __restrict__ sx = sidx + (b << 13);
  const int* __restrict__ ob = offs + b * NCELLP;
  const float* g = gp + b * 8;
  float4 q = sp[i];
  const float qsq = q.w;  // sq precomputed
  const unsigned orig = sx[i];
  const int cx = cellof(q.x, g[0], g[4]);
  const int cy = cellof(q.y, g[1], g[4]);
  const int cz = cellof(q.z, g[2], g[4]);
  const float s = g[3];

  u64 lst[16];
#pragma unroll
  for (int p = 0; p < 16; ++p) lst[p] = ~0ULL;

  for (int r = 0; r <= GRID; ++r) {
    const int W = 2 * r + 1;
    const int nent = 2 * W * W;
    for (int cb = 0; cb < nent; cb += 32) {
      // phase A: each lane loads bounds of its own entry (parallel chains)
      int ms0 = 0, ms1 = 0;
      const int eid = cb + l;
      if (eid < nent) {
        const int rid = eid >> 1, side = eid & 1;
        const int dz = rid / W - r;
        const int dy = rid % W - r;
        const int z2 = cz + dz, y2 = cy + dy;
        if ((unsigned)z2 < GRID && (unsigned)y2 < GRID) {
          const int rowb = (z2 * GRID + y2) * GRID;
          const bool bdry = (dz == -r) || (dz == r) || (dy == -r) || (dy == r);
          if (bdry) {
            if (side == 0) {
              const int xl = cx - r < 0 ? 0 : cx - r;
              const int xh = cx + r > GRID - 1 ? GRID - 1 : cx + r;
              ms0 = ob[rowb + xl];
              ms1 = ob[rowb + xh + 1];
            }
          } else {
            const int x2 = side ? cx + r : cx - r;
            if ((unsigned)x2 < GRID) {
              ms0 = ob[rowb + x2];
              ms1 = ob[rowb + x2 + 1];
            }
          }
        }
      }
      // phase B: concatenate the 32 segments (team prefix sum), deal
      // flattened range stride-32 with UNIFORM trip count (team-wide);
      // cross-lane ops run with the whole team active.
      const int len = ms1 - ms0;  // >= 0
      int pre = len;
#pragma unroll
      for (int d = 1; d < 32; d <<= 1) {
        int u2 = __shfl_up(pre, d);
        if (l >= d) pre += u2;
      }
      const int total = __shfl(pre, tb + 31);
      if (total == 0) continue;
      const int base = ms0 - (pre - len);  // ms0 - exclusive_prefix
      for (int vb = 0; vb < total; vb += 32) {
        const int vidx = vb + l;
        // e = #team lanes with inclusive_prefix <= vidx
        int e = 0;
#pragma unroll
        for (int s2 = 16; s2 >= 1; s2 >>= 1) {
          int pv = __shfl(pre, tb + e + s2 - 1);
          if (pv <= vidx) e += s2;
        }
        const int jb = __shfl(base, tb + e);
        if (vidx < total) {
          const int j = jb + vidx;
          float4 A = sp[j];
          unsigned oi = sx[j];
          INSERTC(A, oi)
        }
      }
    }
    // stop check (R10): count team candidates with d2 <= (r*s)^2 - eps;
    // >=16 proves union-16th <= Chebyshev bound (exact).
    const float rs = (float)r * s;
    const float T = fmaf(rs, rs, -1e-4f);
    unsigned tu = __float_as_uint(T);
    tu ^= (0x80000000u | (unsigned)((int)tu >> 31));
    int c = 0;
#pragma unroll
    for (int p = 0; p < 16; ++p) c += ((unsigned)(lst[p] >> 32) <= tu) ? 1 : 0;
    c += __shfl_xor(c, 1);
    c += __shfl_xor(c, 2);
    c += __shfl_xor(c, 4);
    c += __shfl_xor(c, 8);
    c += __shfl_xor(c, 16);
    if (c >= 16) break;  // team-uniform break
  }

  // ---- in-register cross-lane merge (5 bitonic levels within team) ----
  // Level m: lane pair (l, l^m); keep-min lanes ((l&m)==0) take the 16
  // smallest of the 32 via min(A[p], B[15-p]) (bitonic), then 4-stage
  // clean keeps the kept list sorted.  After m=16, lane l=0 of each
  // team holds that query's sorted top-16.
#pragma unroll
  for (int mm = 1; mm <= 16; mm <<= 1) {
    u64 c[16];
    const bool keepmin = (l & mm) == 0;
#pragma unroll
    for (int p = 0; p < 16; ++p) {
      u64 o = __shfl_xor(lst[15 - p], mm);
      u64 a = lst[p];
      u64 lo = a < o ? a : o;
      u64 hi = a < o ? o : a;
      c[p] = keepmin ? lo : hi;
    }
    CSWAP(0, 8) CSWAP(1, 9) CSWAP(2, 10) CSWAP(3, 11)
    CSWAP(4, 12) CSWAP(5, 13) CSWAP(6, 14) CSWAP(7, 15)
    CSWAP(0, 4) CSWAP(1, 5) CSWAP(2, 6) CSWAP(3, 7)
    CSWAP(8, 12) CSWAP(9, 13) CSWAP(10, 14) CSWAP(11, 15)
    CSWAP(0, 2) CSWAP(1, 3) CSWAP(4, 6) CSWAP(5, 7)
    CSWAP(8, 10) CSWAP(9, 11) CSWAP(12, 14) CSWAP(13, 15)
    CSWAP(0, 1) CSWAP(2, 3) CSWAP(4, 5) CSWAP(6, 7)
    CSWAP(8, 9) CSWAP(10, 11) CSWAP(12, 13) CSWAP(14, 15)
#pragma unroll
    for (int p = 0; p < 16; ++p) lst[p] = c[p];
  }

  if (l == 0) {  // team lane 0 holds the sorted team top-16
    unsigned pk[8];
#pragma unroll
    for (int k = 0; k < 16; k += 2)
      pk[k >> 1] = (unsigned)(lst[k] & 0xFFFFull) |
                   ((unsigned)(lst[k + 1] & 0xFFFFull) << 16);
    unsigned* od = (unsigned*)(oidx + (((size_t)(b << 13) + orig) << 4));
#pragma unroll
    for (int k = 0; k < 8; ++k) od[k] = pk[k];
  }
}

// ---------------------------------------------------------------- K6: lt = feat @ lt_w + lt_b
__global__ __launch_bounds__(256) void k_lt(const float* __restrict__ feat,
                                            const float* __restrict__ ltw,
                                            const float* __restrict__ ltb,
                                            float* __restrict__ lt) {
  __shared__ float sw[64][196];
  __shared__ float sf[32][68];
  const int tid = threadIdx.x;
  const int r0 = blockIdx.x * 32;
#pragma unroll
  for (int i = 0; i < 12; ++i) {
    int v = tid + i * 256;
    float4 w4 = ((const float4*)ltw)[v];
    int row = (v * 4) / 192, col = (v * 4) % 192;
    *(float4*)&sw[row][col] = w4;
  }
#pragma unroll
  for (int i = 0; i < 2; ++i) {
    int v = tid + i * 256;
    int row = v >> 4, c4 = v & 15;
    float4 f4 = ((const float4*)(feat + (size_t)(r0 + row) * 64))[c4];
    *(float4*)&sf[row][c4 * 4] = f4;
  }
  __syncthreads();
  const int r = tid >> 3;
  const int c0 = (tid & 7) * 24;
  float acc[24];
#pragma unroll
  for (int ll = 0; ll < 24; ++ll) acc[ll] = ltb[c0 + ll];
#pragma unroll 4
  for (int j = 0; j < 64; ++j) {
    float f = sf[r][j];
#pragma unroll
    for (int l4 = 0; l4 < 6; ++l4) {
      float4 w4 = *(const float4*)&sw[j][c0 + l4 * 4];
      acc[l4 * 4 + 0] = fmaf(f, w4.x, acc[l4 * 4 + 0]);
      acc[l4 * 4 + 1] = fmaf(f, w4.y, acc[l4 * 4 + 1]);
      acc[l4 * 4 + 2] = fmaf(f, w4.z, acc[l4 * 4 + 2]);
      acc[l4 * 4 + 3] = fmaf(f, w4.w, acc[l4 * 4 + 3]);
    }
  }
  float* orow = lt + (size_t)(r0 + r) * 192 + c0;
#pragma unroll
  for (int l4 = 0; l4 < 6; ++l4)
    *(float4*)&orow[l4 * 4] = make_float4(acc[l4 * 4], acc[l4 * 4 + 1],
                                          acc[l4 * 4 + 2], acc[l4 * 4 + 3]);
}

// ---------------------------------------------------------------- K7: main
// R12: online softmax (no pre/apd/xk arrays), prefetch-1 psi/alp gathers,
// DPP+readlane LN reductions (VALU pipe) instead of __shfl_xor (DS pipe).
// DPP ctrl must be a compile-time constant -> template parameter.
template <int CTRL>
__device__ __forceinline__ float dpp_add_f(float x) {
  int y = __builtin_amdgcn_update_dpp(0, __float_as_int(x), CTRL, 0xf, 0xf,
                                      true);
  return x + __int_as_float(y);
}
// full-wave (64-lane) sum -> wave-uniform via readlane 63.
// row_shr 1/2/4/8: lane15 of each row16 = row sum; row_bcast:15 add:
// lane31 = rows0+1, lane63 = rows2+3; row_bcast:31 add: lane63 = total.
__device__ __forceinline__ float wave_sum64(float x) {
  x = dpp_add_f<0x111>(x);  // row_shr:1
  x = dpp_add_f<0x112>(x);  // row_shr:2
  x = dpp_add_f<0x114>(x);  // row_shr:4
  x = dpp_add_f<0x118>(x);  // row_shr:8
  x = dpp_add_f<0x142>(x);  // row_bcast:15
  x = dpp_add_f<0x143>(x);  // row_bcast:31
  return __int_as_float(__builtin_amdgcn_readlane(__float_as_int(x), 63));
}

__global__ __launch_bounds__(256) void k_main(
    const float4* __restrict__ xytp, const float* __restrict__ lt,
    const u16* __restrict__ knn, const float* __restrict__ pe_w1,
    const float* __restrict__ pe_b1, const float* __restrict__ pe_w2,
    const float* __restrict__ pe_b2, const float* __restrict__ ln_g,
    const float* __restrict__ ln_b, float* __restrict__ out) {
  __shared__ float s_h[4][16][64];
  const int lane = threadIdx.x & 63;
  const int wave = threadIdx.x >> 6;
  const int pid = __builtin_amdgcn_readfirstlane(blockIdx.x * 4 + wave);
  const int b = pid >> 13;
  const int n = pid & 8191;

  float w1c[4];
#pragma unroll
  for (int d = 0; d < 4; ++d) w1c[d] = pe_w1[d * 64 + lane];
  const float b1c = pe_b1[lane];
  float w2c[64];
#pragma unroll
  for (int j = 0; j < 64; ++j) w2c[j] = pe_w2[j * 64 + lane];
  const float b2c = pe_b2[lane];
  const float gc = ln_g[lane], bc = ln_b[lane];

  int nb[16];
#pragma unroll
  for (int k = 0; k < 16; ++k) nb[k] = knn[pid * 16 + k];

  const float* __restrict__ ltb = lt + (size_t)(b << 13) * 192;
  const float vc = ltb[(size_t)n * 192 + lane];

  const float4 qv = xytp[(b << 13) + n];
#pragma unroll
  for (int k = 0; k < 16; ++k) {
    float4 g = xytp[(b << 13) + nb[k]];
    float r0 = qv.x - g.x, r1 = qv.y - g.y, r2 = qv.z - g.z, r3 = qv.w - g.w;
    float h = fmaf(r3, w1c[3],
                   fmaf(r2, w1c[2], fmaf(r1, w1c[1], fmaf(r0, w1c[0], b1c))));
    s_h[wave][k][lane] = fmaxf(h, 0.0f);
  }
  __syncthreads();

  float psi_c = ltb[(size_t)nb[0] * 192 + 64 + lane];
  float alp_c = ltb[(size_t)nb[0] * 192 + 128 + lane];
  float m = -INFINITY, se = 0.f, oacc = 0.f;
#pragma unroll
  for (int k = 0; k < 16; ++k) {
    float psi_n = 0.f, alp_n = 0.f;
    if (k < 15) {  // prefetch next neighbor's psi/alp (distance-1)
      const float* row = ltb + (size_t)nb[k + 1] * 192;
      psi_n = row[64 + lane];
      alp_n = row[128 + lane];
    }
    float acc = b2c;
#pragma unroll
    for (int j4 = 0; j4 < 16; ++j4) {
      float4 h4 = *(const float4*)&s_h[wave][k][j4 * 4];
      acc = fmaf(h4.x, w2c[j4 * 4 + 0], acc);
      acc = fmaf(h4.y, w2c[j4 * 4 + 1], acc);
      acc = fmaf(h4.z, w2c[j4 * 4 + 2], acc);
      acc = fmaf(h4.w, w2c[j4 * 4 + 3], acc);
    }
    const float pre = (vc - psi_c) + acc;
    const float apd = alp_c + acc;
    const float sm = wave_sum64(pre);
    const float ssm = wave_sum64(pre * pre);
    const float mu = sm * 0.015625f;
    const float var = fmaf(ssm, 0.015625f, -mu * mu);
    const float inv = rsqrtf(var + 1e-5f);
    const float x = fmaf((pre - mu) * inv, gc, bc) * 0.125f;
    // online softmax update (first iter: m=-inf -> corr = exp(-inf) = 0)
    const float mn = fmaxf(m, x);
    const float corr = __expf(m - mn);
    const float e = __expf(x - mn);
    se = fmaf(se, corr, e);
    oacc = fmaf(oacc, corr, e * apd);
    m = mn;
    psi_c = psi_n;
    alp_c = alp_n;
  }
  out[(size_t)pid * 64 + lane] = oacc / se;
}

// ---------------------------------------------------------------- launch
extern "C" void kernel_launch(void* const* d_in, const int* in_sizes, int n_in,
                              void* d_out, int out_size, void* d_ws,
                              size_t ws_size, hipStream_t stream) {
  const float4* xytp = (const float4*)d_in[0];
  const float* features = (const float*)d_in[1];
  const float* pe_w1 = (const float*)d_in[2];
  const float* pe_b1 = (const float*)d_in[3];
  const float* pe_w2 = (const float*)d_in[4];
  const float* pe_b2 = (const float*)d_in[5];
  const float* lt_w = (const float*)d_in[6];
  const float* lt_b = (const float*)d_in[7];
  const float* ln_g = (const float*)d_in[8];
  const float* ln_b = (const float*)d_in[9];
  float* out = (float*)d_out;

  char* ws = (char*)d_ws;
  u16* idxbuf = (u16*)(ws + WS_IDX);
  float* lt = (float*)(ws + WS_LT);
  int* cnt = (int*)(ws + WS_CNT);
  int* offs = (int*)(ws + WS_OFF);
  int* curs = (int*)(ws + WS_CUR);
  float4* spts = (float4*)(ws + WS_SP);
  float* gp = (float*)(ws + WS_GP);
  u16* sidx = (u16*)(ws + WS_SIDX);

  k_minmax<<<BATCH, 256, 0, stream>>>(xytp, gp, cnt);
  k_count<<<(BATCH * NPTS) / 256, 256, 0, stream>>>(xytp, gp, cnt);
  k_scan<<<BATCH, 1024, 0, stream>>>(cnt, offs, curs);
  k_scatter<<<(BATCH * NPTS) / 256, 256, 0, stream>>>(xytp, gp, curs, spts,
                                                      sidx);
  k_query<<<(BATCH * NPTS) / 8, 256, 0, stream>>>(spts, sidx, offs, gp,
                                                  idxbuf);
  k_lt<<<(BATCH * NPTS) / 32, 256, 0, stream>>>(features, lt_w, lt_b, lt);
  k_main<<<(BATCH * NPTS) / 4, 256, 0, stream>>>(xytp, lt, idxbuf, pe_w1,
                                                 pe_b1, pe_w2, pe_b2, ln_g,
                                                 ln_b, out);
}

// Round 12
// 419.242 us; speedup vs baseline: 1.1258x; 1.0215x over previous
//
#include <hip/hip_runtime.h>
#include <stdint.h>

#define BATCH 4
#define NPTS 8192
#define KNN_K 16
#define GRID 24
#define NCELL (GRID * GRID * GRID)  // 13824
#define NCELLP (NCELL + 8)          // offs stride (sentinel slot)

typedef unsigned long long u64;
typedef unsigned short u16;

// ws layout (bytes)
#define WS_IDX 0u          // u16[4*8192*16]            = 1,048,576
#define WS_LT 1048576u     // float[4*8192*192]         = 25,165,824
#define WS_CNT 26214400u   // int[4*13824]              = 221,184
#define WS_OFF 26435584u   // int[4*13832]              = 221,312
#define WS_CUR 26656896u   // int[4*13824]              = 221,184  (also bbox partials before k_scan)
#define WS_SP 26878080u    // float4[4*8192]            = 524,288
#define WS_GP 27402368u    // float[4*8]                = 128
#define WS_SIDX 27402496u  // u16[4*8192]               = 65,536

__device__ __forceinline__ int cellof(float v, float o, float invs) {
  int c = (int)((v - o) * invs);
  return c < GRID - 1 ? c : GRID - 1;
}

// ---------------------------------------------------------------- K0a: partial bbox (128 blocks) + zero counters
// R21: old k_minmax was 4 blocks x 256 thr on a 256-CU chip — a serial
// pipeline front (~1024 threads for 512KB of reads + 221KB of zeroing).
// Now 128 blocks, one point per thread; partial min/max per block into
// the curs buffer (unused until k_scan); cnt zeroing spread across all
// 128 blocks (432 ints each, 128*432 == 4*13824 exactly).
__global__ __launch_bounds__(256) void k_bbox1(const float4* __restrict__ xytp,
                                               float* __restrict__ part,
                                               int* __restrict__ cnt) {
  const int blk = blockIdx.x;  // 0..127
  const int b = blk >> 5, sub = blk & 31;
  const int t = threadIdx.x;
#pragma unroll
  for (int i = 0; i < 2; ++i) {
    int v = t + i * 256;
    if (v < 432) cnt[blk * 432 + v] = 0;
  }
  float4 p = xytp[(b << 13) + (sub << 8) + t];
  float mnx = p.x, mny = p.y, mnz = p.z;
  float mxx = p.x, mxy = p.y, mxz = p.z;
#pragma unroll
  for (int d = 1; d < 64; d <<= 1) {
    mnx = fminf(mnx, __shfl_xor(mnx, d)); mny = fminf(mny, __shfl_xor(mny, d));
    mnz = fminf(mnz, __shfl_xor(mnz, d)); mxx = fmaxf(mxx, __shfl_xor(mxx, d));
    mxy = fmaxf(mxy, __shfl_xor(mxy, d)); mxz = fmaxf(mxz, __shfl_xor(mxz, d));
  }
  __shared__ float red[4][6];
  const int lane = t & 63, wv = t >> 6;
  if (lane == 0) {
    red[wv][0] = mnx; red[wv][1] = mny; red[wv][2] = mnz;
    red[wv][3] = mxx; red[wv][4] = mxy; red[wv][5] = mxz;
  }
  __syncthreads();
  if (t == 0) {
    for (int w = 1; w < 4; ++w) {
      red[0][0] = fminf(red[0][0], red[w][0]);
      red[0][1] = fminf(red[0][1], red[w][1]);
      red[0][2] = fminf(red[0][2], red[w][2]);
      red[0][3] = fmaxf(red[0][3], red[w][3]);
      red[0][4] = fmaxf(red[0][4], red[w][4]);
      red[0][5] = fmaxf(red[0][5], red[w][5]);
    }
    float* o = part + blk * 8;
    o[0] = red[0][0]; o[1] = red[0][1]; o[2] = red[0][2];
    o[3] = red[0][3]; o[4] = red[0][4]; o[5] = red[0][5];
  }
}

// ---------------------------------------------------------------- K0b: final bbox reduce (4 blocks x 64 thr)
__global__ __launch_bounds__(64) void k_bbox2(const float* __restrict__ part,
                                              float* __restrict__ gp) {
  const int b = blockIdx.x, t = threadIdx.x;
  const float* pp = part + (b * 32 + (t & 31)) * 8;  // lanes 32..63 duplicate
  float mnx = pp[0], mny = pp[1], mnz = pp[2];
  float mxx = pp[3], mxy = pp[4], mxz = pp[5];
#pragma unroll
  for (int d = 1; d < 64; d <<= 1) {
    mnx = fminf(mnx, __shfl_xor(mnx, d)); mny = fminf(mny, __shfl_xor(mny, d));
    mnz = fminf(mnz, __shfl_xor(mnz, d)); mxx = fmaxf(mxx, __shfl_xor(mxx, d));
    mxy = fmaxf(mxy, __shfl_xor(mxy, d)); mxz = fmaxf(mxz, __shfl_xor(mxz, d));
  }
  if (t == 0) {
    float rmax = fmaxf(mxx - mnx, fmaxf(mxy - mny, mxz - mnz));
    float s = rmax / (float)GRID;
    float* g = gp + b * 8;
    g[0] = mnx; g[1] = mny; g[2] = mnz;
    g[3] = s; g[4] = 1.0f / s;
  }
}

// ---------------------------------------------------------------- K2: count
__global__ __launch_bounds__(256) void k_count(const float4* __restrict__ xytp,
                                               const float* __restrict__ gp,
                                               int* __restrict__ cnt) {
  int i = blockIdx.x * 256 + threadIdx.x;
  int b = i >> 13;
  const float* g = gp + b * 8;
  float4 p = xytp[i];
  int cx = cellof(p.x, g[0], g[4]);
  int cy = cellof(p.y, g[1], g[4]);
  int cz = cellof(p.z, g[2], g[4]);
  atomicAdd(&cnt[b * NCELL + (cz * GRID + cy) * GRID + cx], 1);
}

// ---------------------------------------------------------------- K3: exclusive scan
// offs has stride NCELLP with offs[b*NCELLP + NCELL] = NPTS sentinel, so
// end(cell c) == offs[c+1] works for every cell including the last.
__global__ __launch_bounds__(1024) void k_scan(const int* __restrict__ cnt,
                                               int* __restrict__ offs,
                                               int* __restrict__ curs) {
  __shared__ int wsum[16];
  const int b = blockIdx.x, t = threadIdx.x;
  const int base = b * NCELL;
  const int base2 = b * NCELLP;
  const int lo = t * 14;
  const int hi = lo + 14 < NCELL ? lo + 14 : NCELL;
  int s = 0;
  for (int c = lo; c < hi; ++c) s += cnt[base + c];
  const int lane = t & 63, wv = t >> 6;
  int v = s;
#pragma unroll
  for (int d = 1; d < 64; d <<= 1) {
    int u = __shfl_up(v, d);
    if (lane >= d) v += u;
  }
  if (lane == 63) wsum[wv] = v;
  __syncthreads();
  if (wv == 0 && lane < 16) {
    int x = wsum[lane];
#pragma unroll
    for (int d = 1; d < 16; d <<= 1) {
      int u = __shfl_up(x, d, 16);
      if (lane >= d) x += u;
    }
    wsum[lane] = x;
  }
  __syncthreads();
  int excl = (wv > 0 ? wsum[wv - 1] : 0) + v - s;
  for (int c = lo; c < hi; ++c) {
    offs[base2 + c] = excl;
    curs[base + c] = excl;
    excl += cnt[base + c];
  }
  if (hi == NCELL) offs[base2 + NCELL] = excl;  // == NPTS
}

// ---------------------------------------------------------------- K4: scatter (cell-sorted points, sq in .w, idx in sidx)
__global__ __launch_bounds__(256) void k_scatter(const float4* __restrict__ xytp,
                                                 const float* __restrict__ gp,
                                                 int* __restrict__ curs,
                                                 float4* __restrict__ spts,
                                                 u16* __restrict__ sidx) {
  int i = blockIdx.x * 256 + threadIdx.x;
  int b = i >> 13, n = i & 8191;
  const float* g = gp + b * 8;
  float4 p = xytp[i];
  int cx = cellof(p.x, g[0], g[4]);
  int cy = cellof(p.y, g[1], g[4]);
  int cz = cellof(p.z, g[2], g[4]);
  int pos = atomicAdd(&curs[b * NCELL + (cz * GRID + cy) * GRID + cx], 1);
  float sq = fmaf(p.z, p.z, fmaf(p.y, p.y, p.x * p.x));
  spts[(b << 13) + pos] = make_float4(p.x, p.y, p.z, sq);
  sidx[(b << 13) + pos] = (u16)n;
}

// ---------------------------------------------------------------- K5: grid KNN query
// R21 = R20 (32-wide teams, 2 queries/wave, uniform-trip concat dealing)
// + TIGHTENED STOP BOUND.  After scanning shells 0..r, any unscanned
// point is at distance >= r*s + mn where mn = min(fx, s-fx, fy, s-fy,
// fz, s-fz) is the query's distance to its nearest cell wall (proof
// per direction: +x face gives (r+1)s - fx, -x face gives fx + r*s,
// etc.).  T = (r*s+mn)^2 - eps raises the r=1 acceptance area ~1.3-1.6x
// -> many queries stop one shell earlier (shell 2 costs ~4x shells 0-1).
// mn clamped >= 0 so grid-edge cell clamping only makes T conservative
// -> exactness preserved; count-stop proof otherwise unchanged (R10).
#define INSERTC(Af, OI)                                                      \
  {                                                                          \
    float dot = q.x * (Af).x;                                                \
    dot = fmaf(q.y, (Af).y, dot);                                            \
    dot = fmaf(q.z, (Af).z, dot);                                            \
    float d2 = (qsq + (Af).w) - 2.0f * dot;                                  \
    unsigned u = __float_as_uint(d2);                                        \
    u ^= (0x80000000u | (unsigned)((int)u >> 31));                           \
    u64 key = ((u64)u << 32) | (OI);                                         \
    if (key < lst[15]) {                                                     \
      u64 x = key;                                                           \
      _Pragma("unroll") for (int p = 0; p < 16; ++p) {                       \
        bool sw = x < lst[p];                                                \
        u64 a = lst[p];                                                      \
        lst[p] = sw ? x : a;                                                 \
        x = sw ? a : x;                                                      \
      }                                                                      \
    }                                                                        \
  }

#define CSWAP(ia, ib)                                                        \
  {                                                                          \
    u64 ta = c[ia], tb2 = c[ib];                                             \
    bool sw = ta > tb2;                                                      \
    c[ia] = sw ? tb2 : ta;                                                   \
    c[ib] = sw ? ta : tb2;                                                   \
  }

__global__ __launch_bounds__(256) void k_query(const float4* __restrict__ spts,
                                               const u16* __restrict__ sidx,
                                               const int* __restrict__ offs,
                                               const float* __restrict__ gp,
                                               u16* __restrict__ oidx) {
  const int lane = threadIdx.x & 63;
  const int l = threadIdx.x & 31;        // team lane
  const int qid = blockIdx.x * 8 + (threadIdx.x >> 5);  // 8 teams/block
  const int b = qid >> 13, i = qid & 8191;
  const int tb = lane & 32;              // team base within wave (0 or 32)
  const float4* __restrict__ sp = spts + (b << 13);
  const u16* __restrict__ sx = sidx + (b << 13);
  const int* __restrict__ ob = offs + b * NCELLP;
  const float* g = gp + b * 8;
  float4 q = sp[i];
  const float qsq = q.w;  // sq precomputed
  const unsigned orig = sx[i];
  const int cx = cellof(q.x, g[0], g[4]);
  const int cy = cellof(q.y, g[1], g[4]);
  const int cz = cellof(q.z, g[2], g[4]);
  const float s = g[3];
  // distance from query to its nearest cell wall (>=0); tightens the
  // unscanned-region bound from r*s to r*s + mn.
  const float fx = q.x - fmaf((float)cx, s, g[0]);
  const float fy = q.y - fmaf((float)cy, s, g[1]);
  const float fz = q.z - fmaf((float)cz, s, g[2]);
  const float mn = fmaxf(
      0.0f, fminf(fminf(fminf(fx, s - fx), fminf(fy, s - fy)),
                  fminf(fz, s - fz)));

  u64 lst[16];
#pragma unroll
  for (int p = 0; p < 16; ++p) lst[p] = ~0ULL;

  for (int r = 0; r <= GRID; ++r) {
    const int W = 2 * r + 1;
    const int nent = 2 * W * W;
    for (int cb = 0; cb < nent; cb += 32) {
      // phase A: each lane loads bounds of its own entry (parallel chains)
      int ms0 = 0, ms1 = 0;
      const int eid = cb + l;
      if (eid < nent) {
        const int rid = eid >> 1, side = eid & 1;
        const int dz = rid / W - r;
        const int dy = rid % W - r;
        const int z2 = cz + dz, y2 = cy + dy;
        if ((unsigned)z2 < GRID && (unsigned)y2 < GRID) {
          const int rowb = (z2 * GRID + y2) * GRID;
          const bool bdry = (dz == -r) || (dz == r) || (dy == -r) || (dy == r);
          if (bdry) {
            if (side == 0) {
              const int xl = cx - r < 0 ? 0 : cx - r;
              const int xh = cx + r > GRID - 1 ? GRID - 1 : cx + r;
              ms0 = ob[rowb + xl];
              ms1 = ob[rowb + xh + 1];
            }
          } else {
            const int x2 = side ? cx + r : cx - r;
            if ((unsigned)x2 < GRID) {
              ms0 = ob[rowb + x2];
              ms1 = ob[rowb + x2 + 1];
            }
          }
        }
      }
      // phase B: concatenate the 32 segments (team prefix sum), deal
      // flattened range stride-32 with UNIFORM trip count (team-wide);
      // cross-lane ops run with the whole team active.
      const int len = ms1 - ms0;  // >= 0
      int pre = len;
#pragma unroll
      for (int d = 1; d < 32; d <<= 1) {
        int u2 = __shfl_up(pre, d);
        if (l >= d) pre += u2;
      }
      const int total = __shfl(pre, tb + 31);
      if (total == 0) continue;
      const int base = ms0 - (pre - len);  // ms0 - exclusive_prefix
      for (int vb = 0; vb < total; vb += 32) {
        const int vidx = vb + l;
        // e = #team lanes with inclusive_prefix <= vidx
        int e = 0;
#pragma unroll
        for (int s2 = 16; s2 >= 1; s2 >>= 1) {
          int pv = __shfl(pre, tb + e + s2 - 1);
          if (pv <= vidx) e += s2;
        }
        const int jb = __shfl(base, tb + e);
        if (vidx < total) {
          const int j = jb + vidx;
          float4 A = sp[j];
          unsigned oi = sx[j];
          INSERTC(A, oi)
        }
      }
    }
    // stop check: count team candidates with d2 <= (r*s + mn)^2 - eps;
    // >=16 proves union-16th <= tightened Chebyshev bound (exact).
    const float rs = fmaf((float)r, s, mn);
    const float T = fmaf(rs, rs, -1e-4f);
    unsigned tu = __float_as_uint(T);
    tu ^= (0x80000000u | (unsigned)((int)tu >> 31));
    int c = 0;
#pragma unroll
    for (int p = 0; p < 16; ++p) c += ((unsigned)(lst[p] >> 32) <= tu) ? 1 : 0;
    c += __shfl_xor(c, 1);
    c += __shfl_xor(c, 2);
    c += __shfl_xor(c, 4);
    c += __shfl_xor(c, 8);
    c += __shfl_xor(c, 16);
    if (c >= 16) break;  // team-uniform break
  }

  // ---- in-register cross-lane merge (5 bitonic levels within team) ----
#pragma unroll
  for (int mm = 1; mm <= 16; mm <<= 1) {
    u64 c[16];
    const bool keepmin = (l & mm) == 0;
#pragma unroll
    for (int p = 0; p < 16; ++p) {
      u64 o = __shfl_xor(lst[15 - p], mm);
      u64 a = lst[p];
      u64 lo = a < o ? a : o;
      u64 hi = a < o ? o : a;
      c[p] = keepmin ? lo : hi;
    }
    CSWAP(0, 8) CSWAP(1, 9) CSWAP(2, 10) CSWAP(3, 11)
    CSWAP(4, 12) CSWAP(5, 13) CSWAP(6, 14) CSWAP(7, 15)
    CSWAP(0, 4) CSWAP(1, 5) CSWAP(2, 6) CSWAP(3, 7)
    CSWAP(8, 12) CSWAP(9, 13) CSWAP(10, 14) CSWAP(11, 15)
    CSWAP(0, 2) CSWAP(1, 3) CSWAP(4, 6) CSWAP(5, 7)
    CSWAP(8, 10) CSWAP(9, 11) CSWAP(12, 14) CSWAP(13, 15)
    CSWAP(0, 1) CSWAP(2, 3) CSWAP(4, 5) CSWAP(6, 7)
    CSWAP(8, 9) CSWAP(10, 11) CSWAP(12, 13) CSWAP(14, 15)
#pragma unroll
    for (int p = 0; p < 16; ++p) lst[p] = c[p];
  }

  if (l == 0) {  // team lane 0 holds the sorted team top-16
    unsigned pk[8];
#pragma unroll
    for (int k = 0; k < 16; k += 2)
      pk[k >> 1] = (unsigned)(lst[k] & 0xFFFFull) |
                   ((unsigned)(lst[k + 1] & 0xFFFFull) << 16);
    unsigned* od = (unsigned*)(oidx + (((size_t)(b << 13) + orig) << 4));
#pragma unroll
    for (int k = 0; k < 8; ++k) od[k] = pk[k];
  }
}

// ---------------------------------------------------------------- K6: lt = feat @ lt_w + lt_b
__global__ __launch_bounds__(256) void k_lt(const float* __restrict__ feat,
                                            const float* __restrict__ ltw,
                                            const float* __restrict__ ltb,
                                            float* __restrict__ lt) {
  __shared__ float sw[64][196];
  __shared__ float sf[32][68];
  const int tid = threadIdx.x;
  const int r0 = blockIdx.x * 32;
#pragma unroll
  for (int i = 0; i < 12; ++i) {
    int v = tid + i * 256;
    float4 w4 = ((const float4*)ltw)[v];
    int row = (v * 4) / 192, col = (v * 4) % 192;
    *(float4*)&sw[row][col] = w4;
  }
#pragma unroll
  for (int i = 0; i < 2; ++i) {
    int v = tid + i * 256;
    int row = v >> 4, c4 = v & 15;
    float4 f4 = ((const float4*)(feat + (size_t)(r0 + row) * 64))[c4];
    *(float4*)&sf[row][c4 * 4] = f4;
  }
  __syncthreads();
  const int r = tid >> 3;
  const int c0 = (tid & 7) * 24;
  float acc[24];
#pragma unroll
  for (int ll = 0; ll < 24; ++ll) acc[ll] = ltb[c0 + ll];
#pragma unroll 4
  for (int j = 0; j < 64; ++j) {
    float f = sf[r][j];
#pragma unroll
    for (int l4 = 0; l4 < 6; ++l4) {
      float4 w4 = *(const float4*)&sw[j][c0 + l4 * 4];
      acc[l4 * 4 + 0] = fmaf(f, w4.x, acc[l4 * 4 + 0]);
      acc[l4 * 4 + 1] = fmaf(f, w4.y, acc[l4 * 4 + 1]);
      acc[l4 * 4 + 2] = fmaf(f, w4.z, acc[l4 * 4 + 2]);
      acc[l4 * 4 + 3] = fmaf(f, w4.w, acc[l4 * 4 + 3]);
    }
  }
  float* orow = lt + (size_t)(r0 + r) * 192 + c0;
#pragma unroll
  for (int l4 = 0; l4 < 6; ++l4)
    *(float4*)&orow[l4 * 4] = make_float4(acc[l4 * 4], acc[l4 * 4 + 1],
                                          acc[l4 * 4 + 2], acc[l4 * 4 + 3]);
}

// ---------------------------------------------------------------- K7: main
// R12: online softmax (no pre/apd/xk arrays), prefetch-1 psi/alp gathers,
// DPP+readlane LN reductions (VALU pipe) instead of __shfl_xor (DS pipe).
// DPP ctrl must be a compile-time constant -> template parameter.
template <int CTRL>
__device__ __forceinline__ float dpp_add_f(float x) {
  int y = __builtin_amdgcn_update_dpp(0, __float_as_int(x), CTRL, 0xf, 0xf,
                                      true);
  return x + __int_as_float(y);
}
// full-wave (64-lane) sum -> wave-uniform via readlane 63.
// row_shr 1/2/4/8: lane15 of each row16 = row sum; row_bcast:15 add:
// lane31 = rows0+1, lane63 = rows2+3; row_bcast:31 add: lane63 = total.
__device__ __forceinline__ float wave_sum64(float x) {
  x = dpp_add_f<0x111>(x);  // row_shr:1
  x = dpp_add_f<0x112>(x);  // row_shr:2
  x = dpp_add_f<0x114>(x);  // row_shr:4
  x = dpp_add_f<0x118>(x);  // row_shr:8
  x = dpp_add_f<0x142>(x);  // row_bcast:15
  x = dpp_add_f<0x143>(x);  // row_bcast:31
  return __int_as_float(__builtin_amdgcn_readlane(__float_as_int(x), 63));
}

__global__ __launch_bounds__(256) void k_main(
    const float4* __restrict__ xytp, const float* __restrict__ lt,
    const u16* __restrict__ knn, const float* __restrict__ pe_w1,
    const float* __restrict__ pe_b1, const float* __restrict__ pe_w2,
    const float* __restrict__ pe_b2, const float* __restrict__ ln_g,
    const float* __restrict__ ln_b, float* __restrict__ out) {
  __shared__ float s_h[4][16][64];
  const int lane = threadIdx.x & 63;
  const int wave = threadIdx.x >> 6;
  const int pid = __builtin_amdgcn_readfirstlane(blockIdx.x * 4 + wave);
  const int b = pid >> 13;
  const int n = pid & 8191;

  float w1c[4];
#pragma unroll
  for (int d = 0; d < 4; ++d) w1c[d] = pe_w1[d * 64 + lane];
  const float b1c = pe_b1[lane];
  float w2c[64];
#pragma unroll
  for (int j = 0; j < 64; ++j) w2c[j] = pe_w2[j * 64 + lane];
  const float b2c = pe_b2[lane];
  const float gc = ln_g[lane], bc = ln_b[lane];

  int nb[16];
#pragma unroll
  for (int k = 0; k < 16; ++k) nb[k] = knn[pid * 16 + k];

  const float* __restrict__ ltb = lt + (size_t)(b << 13) * 192;
  const float vc = ltb[(size_t)n * 192 + lane];

  const float4 qv = xytp[(b << 13) + n];
#pragma unroll
  for (int k = 0; k < 16; ++k) {
    float4 g = xytp[(b << 13) + nb[k]];
    float r0 = qv.x - g.x, r1 = qv.y - g.y, r2 = qv.z - g.z, r3 = qv.w - g.w;
    float h = fmaf(r3, w1c[3],
                   fmaf(r2, w1c[2], fmaf(r1, w1c[1], fmaf(r0, w1c[0], b1c))));
    s_h[wave][k][lane] = fmaxf(h, 0.0f);
  }
  __syncthreads();

  float psi_c = ltb[(size_t)nb[0] * 192 + 64 + lane];
  float alp_c = ltb[(size_t)nb[0] * 192 + 128 + lane];
  float m = -INFINITY, se = 0.f, oacc = 0.f;
#pragma unroll
  for (int k = 0; k < 16; ++k) {
    float psi_n = 0.f, alp_n = 0.f;
    if (k < 15) {  // prefetch next neighbor's psi/alp (distance-1)
      const float* row = ltb + (size_t)nb[k + 1] * 192;
      psi_n = row[64 + lane];
      alp_n = row[128 + lane];
    }
    float acc = b2c;
#pragma unroll
    for (int j4 = 0; j4 < 16; ++j4) {
      float4 h4 = *(const float4*)&s_h[wave][k][j4 * 4];
      acc = fmaf(h4.x, w2c[j4 * 4 + 0], acc);
      acc = fmaf(h4.y, w2c[j4 * 4 + 1], acc);
      acc = fmaf(h4.z, w2c[j4 * 4 + 2], acc);
      acc = fmaf(h4.w, w2c[j4 * 4 + 3], acc);
    }
    const float pre = (vc - psi_c) + acc;
    const float apd = alp_c + acc;
    const float sm = wave_sum64(pre);
    const float ssm = wave_sum64(pre * pre);
    const float mu = sm * 0.015625f;
    const float var = fmaf(ssm, 0.015625f, -mu * mu);
    const float inv = rsqrtf(var + 1e-5f);
    const float x = fmaf((pre - mu) * inv, gc, bc) * 0.125f;
    // online softmax update (first iter: m=-inf -> corr = exp(-inf) = 0)
    const float mn = fmaxf(m, x);
    const float corr = __expf(m - mn);
    const float e = __expf(x - mn);
    se = fmaf(se, corr, e);
    oacc = fmaf(oacc, corr, e * apd);
    m = mn;
    psi_c = psi_n;
    alp_c = alp_n;
  }
  out[(size_t)pid * 64 + lane] = oacc / se;
}

// ---------------------------------------------------------------- launch
extern "C" void kernel_launch(void* const* d_in, const int* in_sizes, int n_in,
                              void* d_out, int out_size, void* d_ws,
                              size_t ws_size, hipStream_t stream) {
  const float4* xytp = (const float4*)d_in[0];
  const float* features = (const float*)d_in[1];
  const float* pe_w1 = (const float*)d_in[2];
  const float* pe_b1 = (const float*)d_in[3];
  const float* pe_w2 = (const float*)d_in[4];
  const float* pe_b2 = (const float*)d_in[5];
  const float* lt_w = (const float*)d_in[6];
  const float* lt_b = (const float*)d_in[7];
  const float* ln_g = (const float*)d_in[8];
  const float* ln_b = (const float*)d_in[9];
  float* out = (float*)d_out;

  char* ws = (char*)d_ws;
  u16* idxbuf = (u16*)(ws + WS_IDX);
  float* lt = (float*)(ws + WS_LT);
  int* cnt = (int*)(ws + WS_CNT);
  int* offs = (int*)(ws + WS_OFF);
  int* curs = (int*)(ws + WS_CUR);
  float4* spts = (float4*)(ws + WS_SP);
  float* gp = (float*)(ws + WS_GP);
  u16* sidx = (u16*)(ws + WS_SIDX);

  k_bbox1<<<128, 256, 0, stream>>>(xytp, (float*)(ws + WS_CUR), cnt);
  k_bbox2<<<BATCH, 64, 0, stream>>>((const float*)(ws + WS_CUR), gp);
  k_count<<<(BATCH * NPTS) / 256, 256, 0, stream>>>(xytp, gp, cnt);
  k_scan<<<BATCH, 1024, 0, stream>>>(cnt, offs, curs);
  k_scatter<<<(BATCH * NPTS) / 256, 256, 0, stream>>>(xytp, gp, curs, spts,
                                                      sidx);
  k_query<<<(BATCH * NPTS) / 8, 256, 0, stream>>>(spts, sidx, offs, gp,
                                                  idxbuf);
  k_lt<<<(BATCH * NPTS) / 32, 256, 0, stream>>>(features, lt_w, lt_b, lt);
  k_main<<<(BATCH * NPTS) / 4, 256, 0, stream>>>(xytp, lt, idxbuf, pe_w1,
                                                 pe_b1, pe_w2, pe_b2, ln_g,
                                                 ln_b, out);
}

// Round 13
// 384.556 us; speedup vs baseline: 1.2273x; 1.0902x over previous
//
#include <hip/hip_runtime.h>
#include <stdint.h>

#define BATCH 4
#define NPTS 8192
#define KNN_K 16
#define GRID 24
#define NCELL (GRID * GRID * GRID)  // 13824
#define NCELLP (NCELL + 8)          // offs stride (sentinel slot)

typedef unsigned long long u64;
typedef unsigned short u16;

// ws layout (bytes)
#define WS_IDX 0u          // u16[4*8192*16]            = 1,048,576
#define WS_LT 1048576u     // float[4*8192*192]         = 25,165,824
#define WS_CNT 26214400u   // int[4*13824]              = 221,184  (cnt; dead after k_scan -> reused as ord u16[4*8192])
#define WS_OFF 26435584u   // int[4*13832]              = 221,312
#define WS_CUR 26656896u   // int[4*13824]              = 221,184  (also bbox partials before k_scan)
#define WS_SP 26878080u    // float4[4*8192]            = 524,288
#define WS_GP 27402368u    // float[4*8]                = 128
#define WS_SIDX 27402496u  // u16[4*8192]               = 65,536

__device__ __forceinline__ int cellof(float v, float o, float invs) {
  int c = (int)((v - o) * invs);
  return c < GRID - 1 ? c : GRID - 1;
}

// ---------------------------------------------------------------- K0a: partial bbox (128 blocks) + zero counters
__global__ __launch_bounds__(256) void k_bbox1(const float4* __restrict__ xytp,
                                               float* __restrict__ part,
                                               int* __restrict__ cnt) {
  const int blk = blockIdx.x;  // 0..127
  const int b = blk >> 5, sub = blk & 31;
  const int t = threadIdx.x;
#pragma unroll
  for (int i = 0; i < 2; ++i) {
    int v = t + i * 256;
    if (v < 432) cnt[blk * 432 + v] = 0;
  }
  float4 p = xytp[(b << 13) + (sub << 8) + t];
  float mnx = p.x, mny = p.y, mnz = p.z;
  float mxx = p.x, mxy = p.y, mxz = p.z;
#pragma unroll
  for (int d = 1; d < 64; d <<= 1) {
    mnx = fminf(mnx, __shfl_xor(mnx, d)); mny = fminf(mny, __shfl_xor(mny, d));
    mnz = fminf(mnz, __shfl_xor(mnz, d)); mxx = fmaxf(mxx, __shfl_xor(mxx, d));
    mxy = fmaxf(mxy, __shfl_xor(mxy, d)); mxz = fmaxf(mxz, __shfl_xor(mxz, d));
  }
  __shared__ float red[4][6];
  const int lane = t & 63, wv = t >> 6;
  if (lane == 0) {
    red[wv][0] = mnx; red[wv][1] = mny; red[wv][2] = mnz;
    red[wv][3] = mxx; red[wv][4] = mxy; red[wv][5] = mxz;
  }
  __syncthreads();
  if (t == 0) {
    for (int w = 1; w < 4; ++w) {
      red[0][0] = fminf(red[0][0], red[w][0]);
      red[0][1] = fminf(red[0][1], red[w][1]);
      red[0][2] = fminf(red[0][2], red[w][2]);
      red[0][3] = fmaxf(red[0][3], red[w][3]);
      red[0][4] = fmaxf(red[0][4], red[w][4]);
      red[0][5] = fmaxf(red[0][5], red[w][5]);
    }
    float* o = part + blk * 8;
    o[0] = red[0][0]; o[1] = red[0][1]; o[2] = red[0][2];
    o[3] = red[0][3]; o[4] = red[0][4]; o[5] = red[0][5];
  }
}

// ---------------------------------------------------------------- K0b: final bbox reduce (4 blocks x 64 thr)
__global__ __launch_bounds__(64) void k_bbox2(const float* __restrict__ part,
                                              float* __restrict__ gp) {
  const int b = blockIdx.x, t = threadIdx.x;
  const float* pp = part + (b * 32 + (t & 31)) * 8;  // lanes 32..63 duplicate
  float mnx = pp[0], mny = pp[1], mnz = pp[2];
  float mxx = pp[3], mxy = pp[4], mxz = pp[5];
#pragma unroll
  for (int d = 1; d < 64; d <<= 1) {
    mnx = fminf(mnx, __shfl_xor(mnx, d)); mny = fminf(mny, __shfl_xor(mny, d));
    mnz = fminf(mnz, __shfl_xor(mnz, d)); mxx = fmaxf(mxx, __shfl_xor(mxx, d));
    mxy = fmaxf(mxy, __shfl_xor(mxy, d)); mxz = fmaxf(mxz, __shfl_xor(mxz, d));
  }
  if (t == 0) {
    float rmax = fmaxf(mxx - mnx, fmaxf(mxy - mny, mxz - mnz));
    float s = rmax / (float)GRID;
    float* g = gp + b * 8;
    g[0] = mnx; g[1] = mny; g[2] = mnz;
    g[3] = s; g[4] = 1.0f / s;
  }
}

// ---------------------------------------------------------------- K2: count
__global__ __launch_bounds__(256) void k_count(const float4* __restrict__ xytp,
                                               const float* __restrict__ gp,
                                               int* __restrict__ cnt) {
  int i = blockIdx.x * 256 + threadIdx.x;
  int b = i >> 13;
  const float* g = gp + b * 8;
  float4 p = xytp[i];
  int cx = cellof(p.x, g[0], g[4]);
  int cy = cellof(p.y, g[1], g[4]);
  int cz = cellof(p.z, g[2], g[4]);
  atomicAdd(&cnt[b * NCELL + (cz * GRID + cy) * GRID + cx], 1);
}

// ---------------------------------------------------------------- K3: exclusive scan
// offs has stride NCELLP with offs[b*NCELLP + NCELL] = NPTS sentinel, so
// end(cell c) == offs[c+1] works for every cell including the last.
__global__ __launch_bounds__(1024) void k_scan(const int* __restrict__ cnt,
                                               int* __restrict__ offs,
                                               int* __restrict__ curs) {
  __shared__ int wsum[16];
  const int b = blockIdx.x, t = threadIdx.x;
  const int base = b * NCELL;
  const int base2 = b * NCELLP;
  const int lo = t * 14;
  const int hi = lo + 14 < NCELL ? lo + 14 : NCELL;
  int s = 0;
  for (int c = lo; c < hi; ++c) s += cnt[base + c];
  const int lane = t & 63, wv = t >> 6;
  int v = s;
#pragma unroll
  for (int d = 1; d < 64; d <<= 1) {
    int u = __shfl_up(v, d);
    if (lane >= d) v += u;
  }
  if (lane == 63) wsum[wv] = v;
  __syncthreads();
  if (wv == 0 && lane < 16) {
    int x = wsum[lane];
#pragma unroll
    for (int d = 1; d < 16; d <<= 1) {
      int u = __shfl_up(x, d, 16);
      if (lane >= d) x += u;
    }
    wsum[lane] = x;
  }
  __syncthreads();
  int excl = (wv > 0 ? wsum[wv - 1] : 0) + v - s;
  for (int c = lo; c < hi; ++c) {
    offs[base2 + c] = excl;
    curs[base + c] = excl;
    excl += cnt[base + c];
  }
  if (hi == NCELL) offs[base2 + NCELL] = excl;  // == NPTS
}

// ---------------------------------------------------------------- K4: scatter (cell-sorted points, sq in .w, idx in sidx)
__global__ __launch_bounds__(256) void k_scatter(const float4* __restrict__ xytp,
                                                 const float* __restrict__ gp,
                                                 int* __restrict__ curs,
                                                 float4* __restrict__ spts,
                                                 u16* __restrict__ sidx) {
  int i = blockIdx.x * 256 + threadIdx.x;
  int b = i >> 13, n = i & 8191;
  const float* g = gp + b * 8;
  float4 p = xytp[i];
  int cx = cellof(p.x, g[0], g[4]);
  int cy = cellof(p.y, g[1], g[4]);
  int cz = cellof(p.z, g[2], g[4]);
  int pos = atomicAdd(&curs[b * NCELL + (cz * GRID + cy) * GRID + cx], 1);
  float sq = fmaf(p.z, p.z, fmaf(p.y, p.y, p.x * p.x));
  spts[(b << 13) + pos] = make_float4(p.x, p.y, p.z, sq);
  sidx[(b << 13) + pos] = (u16)n;
}

// ---------------------------------------------------------------- K4b: LPT query ordering (R22)
// Counting-sort the 8192 queries per batch by own-cell occupancy
// ASCENDING (sparse cell -> expensive query -> scheduled FIRST = LPT).
// k_query's measured residual is tail scheduling (occ 24% at 2x
// oversubscription): expensive waves straggle at the end.  Dispatch
// them first, backfill with cheap ones.  Any bijection is correctness-
// neutral (q/orig fetched via i).  ord lives in the dead cnt buffer.
__global__ __launch_bounds__(1024) void k_order(const float4* __restrict__ spts,
                                                const int* __restrict__ offs,
                                                const float* __restrict__ gp,
                                                u16* __restrict__ ord) {
  __shared__ int hist[32];
  __shared__ int strt[32];
  const int b = blockIdx.x, t = threadIdx.x;
  if (t < 32) hist[t] = 0;
  __syncthreads();
  const float* g = gp + b * 8;
  const int* ob = offs + b * NCELLP;
  const float4* sp = spts + (b << 13);
  int key[8];
#pragma unroll
  for (int it = 0; it < 8; ++it) {
    const int i = t + it * 1024;
    float4 p = sp[i];
    int cx = cellof(p.x, g[0], g[4]);
    int cy = cellof(p.y, g[1], g[4]);
    int cz = cellof(p.z, g[2], g[4]);
    int c = (cz * GRID + cy) * GRID + cx;
    int cc = ob[c + 1] - ob[c];  // >= 1 (query itself)
    key[it] = cc - 1 < 31 ? cc - 1 : 31;
    atomicAdd(&hist[key[it]], 1);
  }
  __syncthreads();
  if (t == 0) {
    int acc = 0;
    for (int k2 = 0; k2 < 32; ++k2) { strt[k2] = acc; acc += hist[k2]; }
  }
  __syncthreads();
  u16* ob2 = ord + (b << 13);
#pragma unroll
  for (int it = 0; it < 8; ++it) {
    const int i = t + it * 1024;
    int pos = atomicAdd(&strt[key[it]], 1);
    ob2[pos] = (u16)i;
  }
}

// ---------------------------------------------------------------- K5: grid KNN query
// R22 = R21 (32-wide teams, uniform-trip concat dealing, mn-tightened
// count-stop) + LPT slot->query indirection via ord.
#define INSERTC(Af, OI)                                                      \
  {                                                                          \
    float dot = q.x * (Af).x;                                                \
    dot = fmaf(q.y, (Af).y, dot);                                            \
    dot = fmaf(q.z, (Af).z, dot);                                            \
    float d2 = (qsq + (Af).w) - 2.0f * dot;                                  \
    unsigned u = __float_as_uint(d2);                                        \
    u ^= (0x80000000u | (unsigned)((int)u >> 31));                           \
    u64 key = ((u64)u << 32) | (OI);                                         \
    if (key < lst[15]) {                                                     \
      u64 x = key;                                                           \
      _Pragma("unroll") for (int p = 0; p < 16; ++p) {                       \
        bool sw = x < lst[p];                                                \
        u64 a = lst[p];                                                      \
        lst[p] = sw ? x : a;                                                 \
        x = sw ? a : x;                                                      \
      }                                                                      \
    }                                                                        \
  }

#define CSWAP(ia, ib)                                                        \
  {                                                                          \
    u64 ta = c[ia], tb2 = c[ib];                                             \
    bool sw = ta > tb2;                                                      \
    c[ia] = sw ? tb2 : ta;                                                   \
    c[ib] = sw ? ta : tb2;                                                   \
  }

__global__ __launch_bounds__(256) void k_query(const float4* __restrict__ spts,
                                               const u16* __restrict__ sidx,
                                               const int* __restrict__ offs,
                                               const float* __restrict__ gp,
                                               const u16* __restrict__ ord,
                                               u16* __restrict__ oidx) {
  const int lane = threadIdx.x & 63;
  const int l = threadIdx.x & 31;        // team lane
  const int qid = blockIdx.x * 8 + (threadIdx.x >> 5);  // 8 teams/block
  const int b = qid >> 13;
  const int i = ord[(b << 13) + (qid & 8191)];  // LPT permutation
  const int tb = lane & 32;              // team base within wave (0 or 32)
  const float4* __restrict__ sp = spts + (b << 13);
  const u16* __restrict__ sx = sidx + (b << 13);
  const int* __restrict__ ob = offs + b * NCELLP;
  const float* g = gp + b * 8;
  float4 q = sp[i];
  const float qsq = q.w;  // sq precomputed
  const unsigned orig = sx[i];
  const int cx = cellof(q.x, g[0], g[4]);
  const int cy = cellof(q.y, g[1], g[4]);
  const int cz = cellof(q.z, g[2], g[4]);
  const float s = g[3];
  // distance from query to its nearest cell wall (>=0); tightens the
  // unscanned-region bound from r*s to r*s + mn.
  const float fx = q.x - fmaf((float)cx, s, g[0]);
  const float fy = q.y - fmaf((float)cy, s, g[1]);
  const float fz = q.z - fmaf((float)cz, s, g[2]);
  const float mn = fmaxf(
      0.0f, fminf(fminf(fminf(fx, s - fx), fminf(fy, s - fy)),
                  fminf(fz, s - fz)));

  u64 lst[16];
#pragma unroll
  for (int p = 0; p < 16; ++p) lst[p] = ~0ULL;

  for (int r = 0; r <= GRID; ++r) {
    const int W = 2 * r + 1;
    const int nent = 2 * W * W;
    for (int cb = 0; cb < nent; cb += 32) {
      // phase A: each lane loads bounds of its own entry (parallel chains)
      int ms0 = 0, ms1 = 0;
      const int eid = cb + l;
      if (eid < nent) {
        const int rid = eid >> 1, side = eid & 1;
        const int dz = rid / W - r;
        const int dy = rid % W - r;
        const int z2 = cz + dz, y2 = cy + dy;
        if ((unsigned)z2 < GRID && (unsigned)y2 < GRID) {
          const int rowb = (z2 * GRID + y2) * GRID;
          const bool bdry = (dz == -r) || (dz == r) || (dy == -r) || (dy == r);
          if (bdry) {
            if (side == 0) {
              const int xl = cx - r < 0 ? 0 : cx - r;
              const int xh = cx + r > GRID - 1 ? GRID - 1 : cx + r;
              ms0 = ob[rowb + xl];
              ms1 = ob[rowb + xh + 1];
            }
          } else {
            const int x2 = side ? cx + r : cx - r;
            if ((unsigned)x2 < GRID) {
              ms0 = ob[rowb + x2];
              ms1 = ob[rowb + x2 + 1];
            }
          }
        }
      }
      // phase B: concatenate the 32 segments (team prefix sum), deal
      // flattened range stride-32 with UNIFORM trip count (team-wide);
      // cross-lane ops run with the whole team active.
      const int len = ms1 - ms0;  // >= 0
      int pre = len;
#pragma unroll
      for (int d = 1; d < 32; d <<= 1) {
        int u2 = __shfl_up(pre, d);
        if (l >= d) pre += u2;
      }
      const int total = __shfl(pre, tb + 31);
      if (total == 0) continue;
      const int base = ms0 - (pre - len);  // ms0 - exclusive_prefix
      for (int vb = 0; vb < total; vb += 32) {
        const int vidx = vb + l;
        // e = #team lanes with inclusive_prefix <= vidx
        int e = 0;
#pragma unroll
        for (int s2 = 16; s2 >= 1; s2 >>= 1) {
          int pv = __shfl(pre, tb + e + s2 - 1);
          if (pv <= vidx) e += s2;
        }
        const int jb = __shfl(base, tb + e);
        if (vidx < total) {
          const int j = jb + vidx;
          float4 A = sp[j];
          unsigned oi = sx[j];
          INSERTC(A, oi)
        }
      }
    }
    // stop check: count team candidates with d2 <= (r*s + mn)^2 - eps;
    // >=16 proves union-16th <= tightened Chebyshev bound (exact).
    const float rs = fmaf((float)r, s, mn);
    const float T = fmaf(rs, rs, -1e-4f);
    unsigned tu = __float_as_uint(T);
    tu ^= (0x80000000u | (unsigned)((int)tu >> 31));
    int c = 0;
#pragma unroll
    for (int p = 0; p < 16; ++p) c += ((unsigned)(lst[p] >> 32) <= tu) ? 1 : 0;
    c += __shfl_xor(c, 1);
    c += __shfl_xor(c, 2);
    c += __shfl_xor(c, 4);
    c += __shfl_xor(c, 8);
    c += __shfl_xor(c, 16);
    if (c >= 16) break;  // team-uniform break
  }

  // ---- in-register cross-lane merge (5 bitonic levels within team) ----
#pragma unroll
  for (int mm = 1; mm <= 16; mm <<= 1) {
    u64 c[16];
    const bool keepmin = (l & mm) == 0;
#pragma unroll
    for (int p = 0; p < 16; ++p) {
      u64 o = __shfl_xor(lst[15 - p], mm);
      u64 a = lst[p];
      u64 lo = a < o ? a : o;
      u64 hi = a < o ? o : a;
      c[p] = keepmin ? lo : hi;
    }
    CSWAP(0, 8) CSWAP(1, 9) CSWAP(2, 10) CSWAP(3, 11)
    CSWAP(4, 12) CSWAP(5, 13) CSWAP(6, 14) CSWAP(7, 15)
    CSWAP(0, 4) CSWAP(1, 5) CSWAP(2, 6) CSWAP(3, 7)
    CSWAP(8, 12) CSWAP(9, 13) CSWAP(10, 14) CSWAP(11, 15)
    CSWAP(0, 2) CSWAP(1, 3) CSWAP(4, 6) CSWAP(5, 7)
    CSWAP(8, 10) CSWAP(9, 11) CSWAP(12, 14) CSWAP(13, 15)
    CSWAP(0, 1) CSWAP(2, 3) CSWAP(4, 5) CSWAP(6, 7)
    CSWAP(8, 9) CSWAP(10, 11) CSWAP(12, 13) CSWAP(14, 15)
#pragma unroll
    for (int p = 0; p < 16; ++p) lst[p] = c[p];
  }

  if (l == 0) {  // team lane 0 holds the sorted team top-16
    unsigned pk[8];
#pragma unroll
    for (int k = 0; k < 16; k += 2)
      pk[k >> 1] = (unsigned)(lst[k] & 0xFFFFull) |
                   ((unsigned)(lst[k + 1] & 0xFFFFull) << 16);
    unsigned* od = (unsigned*)(oidx + (((size_t)(b << 13) + orig) << 4));
#pragma unroll
    for (int k = 0; k < 8; ++k) od[k] = pk[k];
  }
}

// ---------------------------------------------------------------- K6: lt = feat @ lt_w + lt_b
__global__ __launch_bounds__(256) void k_lt(const float* __restrict__ feat,
                                            const float* __restrict__ ltw,
                                            const float* __restrict__ ltb,
                                            float* __restrict__ lt) {
  __shared__ float sw[64][196];
  __shared__ float sf[32][68];
  const int tid = threadIdx.x;
  const int r0 = blockIdx.x * 32;
#pragma unroll
  for (int i = 0; i < 12; ++i) {
    int v = tid + i * 256;
    float4 w4 = ((const float4*)ltw)[v];
    int row = (v * 4) / 192, col = (v * 4) % 192;
    *(float4*)&sw[row][col] = w4;
  }
#pragma unroll
  for (int i = 0; i < 2; ++i) {
    int v = tid + i * 256;
    int row = v >> 4, c4 = v & 15;
    float4 f4 = ((const float4*)(feat + (size_t)(r0 + row) * 64))[c4];
    *(float4*)&sf[row][c4 * 4] = f4;
  }
  __syncthreads();
  const int r = tid >> 3;
  const int c0 = (tid & 7) * 24;
  float acc[24];
#pragma unroll
  for (int ll = 0; ll < 24; ++ll) acc[ll] = ltb[c0 + ll];
#pragma unroll 4
  for (int j = 0; j < 64; ++j) {
    float f = sf[r][j];
#pragma unroll
    for (int l4 = 0; l4 < 6; ++l4) {
      float4 w4 = *(const float4*)&sw[j][c0 + l4 * 4];
      acc[l4 * 4 + 0] = fmaf(f, w4.x, acc[l4 * 4 + 0]);
      acc[l4 * 4 + 1] = fmaf(f, w4.y, acc[l4 * 4 + 1]);
      acc[l4 * 4 + 2] = fmaf(f, w4.z, acc[l4 * 4 + 2]);
      acc[l4 * 4 + 3] = fmaf(f, w4.w, acc[l4 * 4 + 3]);
    }
  }
  float* orow = lt + (size_t)(r0 + r) * 192 + c0;
#pragma unroll
  for (int l4 = 0; l4 < 6; ++l4)
    *(float4*)&orow[l4 * 4] = make_float4(acc[l4 * 4], acc[l4 * 4 + 1],
                                          acc[l4 * 4 + 2], acc[l4 * 4 + 3]);
}

// ---------------------------------------------------------------- K7: main
// R22: prefetch distance 2 for psi/alp (static A/B register rotation in
// the fully-unrolled k-loop) to cover ~500cy L3 gather latency that
// pf-1's ~460cy of per-k compute just misses.  Online softmax + DPP LN
// reductions unchanged (R12).
template <int CTRL>
__device__ __forceinline__ float dpp_add_f(float x) {
  int y = __builtin_amdgcn_update_dpp(0, __float_as_int(x), CTRL, 0xf, 0xf,
                                      true);
  return x + __int_as_float(y);
}
__device__ __forceinline__ float wave_sum64(float x) {
  x = dpp_add_f<0x111>(x);  // row_shr:1
  x = dpp_add_f<0x112>(x);  // row_shr:2
  x = dpp_add_f<0x114>(x);  // row_shr:4
  x = dpp_add_f<0x118>(x);  // row_shr:8
  x = dpp_add_f<0x142>(x);  // row_bcast:15
  x = dpp_add_f<0x143>(x);  // row_bcast:31
  return __int_as_float(__builtin_amdgcn_readlane(__float_as_int(x), 63));
}

__global__ __launch_bounds__(256) void k_main(
    const float4* __restrict__ xytp, const float* __restrict__ lt,
    const u16* __restrict__ knn, const float* __restrict__ pe_w1,
    const float* __restrict__ pe_b1, const float* __restrict__ pe_w2,
    const float* __restrict__ pe_b2, const float* __restrict__ ln_g,
    const float* __restrict__ ln_b, float* __restrict__ out) {
  __shared__ float s_h[4][16][64];
  const int lane = threadIdx.x & 63;
  const int wave = threadIdx.x >> 6;
  const int pid = __builtin_amdgcn_readfirstlane(blockIdx.x * 4 + wave);
  const int b = pid >> 13;
  const int n = pid & 8191;

  float w1c[4];
#pragma unroll
  for (int d = 0; d < 4; ++d) w1c[d] = pe_w1[d * 64 + lane];
  const float b1c = pe_b1[lane];
  float w2c[64];
#pragma unroll
  for (int j = 0; j < 64; ++j) w2c[j] = pe_w2[j * 64 + lane];
  const float b2c = pe_b2[lane];
  const float gc = ln_g[lane], bc = ln_b[lane];

  int nb[16];
#pragma unroll
  for (int k = 0; k < 16; ++k) nb[k] = knn[pid * 16 + k];

  const float* __restrict__ ltb = lt + (size_t)(b << 13) * 192;
  const float vc = ltb[(size_t)n * 192 + lane];

  const float4 qv = xytp[(b << 13) + n];
#pragma unroll
  for (int k = 0; k < 16; ++k) {
    float4 g = xytp[(b << 13) + nb[k]];
    float r0 = qv.x - g.x, r1 = qv.y - g.y, r2 = qv.z - g.z, r3 = qv.w - g.w;
    float h = fmaf(r3, w1c[3],
                   fmaf(r2, w1c[2], fmaf(r1, w1c[1], fmaf(r0, w1c[0], b1c))));
    s_h[wave][k][lane] = fmaxf(h, 0.0f);
  }
  __syncthreads();

  // prefetch distance 2: A/B slots, static rotation (k compile-time)
  float psiA = ltb[(size_t)nb[0] * 192 + 64 + lane];
  float alpA = ltb[(size_t)nb[0] * 192 + 128 + lane];
  float psiB = ltb[(size_t)nb[1] * 192 + 64 + lane];
  float alpB = ltb[(size_t)nb[1] * 192 + 128 + lane];
  float m = -INFINITY, se = 0.f, oacc = 0.f;
#pragma unroll
  for (int k = 0; k < 16; ++k) {
    const float psi_c = (k & 1) ? psiB : psiA;
    const float alp_c = (k & 1) ? alpB : alpA;
    if (k < 14) {  // refill the slot just consumed with row k+2
      const float* row = ltb + (size_t)nb[k + 2] * 192;
      if (k & 1) { psiB = row[64 + lane]; alpB = row[128 + lane]; }
      else       { psiA = row[64 + lane]; alpA = row[128 + lane]; }
    }
    float acc = b2c;
#pragma unroll
    for (int j4 = 0; j4 < 16; ++j4) {
      float4 h4 = *(const float4*)&s_h[wave][k][j4 * 4];
      acc = fmaf(h4.x, w2c[j4 * 4 + 0], acc);
      acc = fmaf(h4.y, w2c[j4 * 4 + 1], acc);
      acc = fmaf(h4.z, w2c[j4 * 4 + 2], acc);
      acc = fmaf(h4.w, w2c[j4 * 4 + 3], acc);
    }
    const float pre = (vc - psi_c) + acc;
    const float apd = alp_c + acc;
    const float sm = wave_sum64(pre);
    const float ssm = wave_sum64(pre * pre);
    const float mu = sm * 0.015625f;
    const float var = fmaf(ssm, 0.015625f, -mu * mu);
    const float inv = rsqrtf(var + 1e-5f);
    const float x = fmaf((pre - mu) * inv, gc, bc) * 0.125f;
    // online softmax update (first iter: m=-inf -> corr = exp(-inf) = 0)
    const float mn = fmaxf(m, x);
    const float corr = __expf(m - mn);
    const float e = __expf(x - mn);
    se = fmaf(se, corr, e);
    oacc = fmaf(oacc, corr, e * apd);
    m = mn;
  }
  out[(size_t)pid * 64 + lane] = oacc / se;
}

// ---------------------------------------------------------------- launch
extern "C" void kernel_launch(void* const* d_in, const int* in_sizes, int n_in,
                              void* d_out, int out_size, void* d_ws,
                              size_t ws_size, hipStream_t stream) {
  const float4* xytp = (const float4*)d_in[0];
  const float* features = (const float*)d_in[1];
  const float* pe_w1 = (const float*)d_in[2];
  const float* pe_b1 = (const float*)d_in[3];
  const float* pe_w2 = (const float*)d_in[4];
  const float* pe_b2 = (const float*)d_in[5];
  const float* lt_w = (const float*)d_in[6];
  const float* lt_b = (const float*)d_in[7];
  const float* ln_g = (const float*)d_in[8];
  const float* ln_b = (const float*)d_in[9];
  float* out = (float*)d_out;

  char* ws = (char*)d_ws;
  u16* idxbuf = (u16*)(ws + WS_IDX);
  float* lt = (float*)(ws + WS_LT);
  int* cnt = (int*)(ws + WS_CNT);
  int* offs = (int*)(ws + WS_OFF);
  int* curs = (int*)(ws + WS_CUR);
  float4* spts = (float4*)(ws + WS_SP);
  float* gp = (float*)(ws + WS_GP);
  u16* sidx = (u16*)(ws + WS_SIDX);
  u16* ordb = (u16*)(ws + WS_CNT);  // cnt is dead after k_scan

  k_bbox1<<<128, 256, 0, stream>>>(xytp, (float*)(ws + WS_CUR), cnt);
  k_bbox2<<<BATCH, 64, 0, stream>>>((const float*)(ws + WS_CUR), gp);
  k_count<<<(BATCH * NPTS) / 256, 256, 0, stream>>>(xytp, gp, cnt);
  k_scan<<<BATCH, 1024, 0, stream>>>(cnt, offs, curs);
  k_scatter<<<(BATCH * NPTS) / 256, 256, 0, stream>>>(xytp, gp, curs, spts,
                                                      sidx);
  k_order<<<BATCH, 1024, 0, stream>>>(spts, offs, gp, ordb);
  k_query<<<(BATCH * NPTS) / 8, 256, 0, stream>>>(spts, sidx, offs, gp, ordb,
                                                  idxbuf);
  k_lt<<<(BATCH * NPTS) / 32, 256, 0, stream>>>(features, lt_w, lt_b, lt);
  k_main<<<(BATCH * NPTS) / 4, 256, 0, stream>>>(xytp, lt, idxbuf, pe_w1,
                                                 pe_b1, pe_w2, pe_b2, ln_g,
                                                 ln_b, out);
}

// Round 14
// 379.490 us; speedup vs baseline: 1.2437x; 1.0134x over previous
//
#include <hip/hip_runtime.h>
#include <stdint.h>

#define BATCH 4
#define NPTS 8192
#define KNN_K 16
#define GRID 24
#define NCELL (GRID * GRID * GRID)  // 13824
#define NCELLP (NCELL + 8)          // offs stride (sentinel slot)

typedef unsigned long long u64;
typedef unsigned int u32;
typedef unsigned short u16;

// ws layout (bytes)
#define WS_IDX 0u          // u16[4*8192*16]            = 1,048,576
#define WS_LT 1048576u     // row=[varphi f32 x64 | packed bf16 (psi,alp) u32 x64] = 512B/pt -> 16,777,216 (slot sized for 25MB, fine)
#define WS_CNT 26214400u   // int[4*13824]              = 221,184  (cnt; dead after k_scan -> reused as ord u16[4*8192])
#define WS_OFF 26435584u   // int[4*13832]              = 221,312
#define WS_CUR 26656896u   // int[4*13824]              = 221,184  (also bbox partials before k_scan)
#define WS_SP 26878080u    // float4[4*8192]            = 524,288
#define WS_GP 27402368u    // float[4*8]                = 128
#define WS_SIDX 27402496u  // u16[4*8192]               = 65,536

__device__ __forceinline__ int cellof(float v, float o, float invs) {
  int c = (int)((v - o) * invs);
  return c < GRID - 1 ? c : GRID - 1;
}

__device__ __forceinline__ u32 f2bf(float v) {  // RNE bf16 (high 16 bits)
  u32 x = __float_as_uint(v);
  return (x + 0x7FFFu + ((x >> 16) & 1u)) >> 16;
}

// ---------------------------------------------------------------- K0a: partial bbox (128 blocks) + zero counters
__global__ __launch_bounds__(256) void k_bbox1(const float4* __restrict__ xytp,
                                               float* __restrict__ part,
                                               int* __restrict__ cnt) {
  const int blk = blockIdx.x;  // 0..127
  const int b = blk >> 5, sub = blk & 31;
  const int t = threadIdx.x;
#pragma unroll
  for (int i = 0; i < 2; ++i) {
    int v = t + i * 256;
    if (v < 432) cnt[blk * 432 + v] = 0;
  }
  float4 p = xytp[(b << 13) + (sub << 8) + t];
  float mnx = p.x, mny = p.y, mnz = p.z;
  float mxx = p.x, mxy = p.y, mxz = p.z;
#pragma unroll
  for (int d = 1; d < 64; d <<= 1) {
    mnx = fminf(mnx, __shfl_xor(mnx, d)); mny = fminf(mny, __shfl_xor(mny, d));
    mnz = fminf(mnz, __shfl_xor(mnz, d)); mxx = fmaxf(mxx, __shfl_xor(mxx, d));
    mxy = fmaxf(mxy, __shfl_xor(mxy, d)); mxz = fmaxf(mxz, __shfl_xor(mxz, d));
  }
  __shared__ float red[4][6];
  const int lane = t & 63, wv = t >> 6;
  if (lane == 0) {
    red[wv][0] = mnx; red[wv][1] = mny; red[wv][2] = mnz;
    red[wv][3] = mxx; red[wv][4] = mxy; red[wv][5] = mxz;
  }
  __syncthreads();
  if (t == 0) {
    for (int w = 1; w < 4; ++w) {
      red[0][0] = fminf(red[0][0], red[w][0]);
      red[0][1] = fminf(red[0][1], red[w][1]);
      red[0][2] = fminf(red[0][2], red[w][2]);
      red[0][3] = fmaxf(red[0][3], red[w][3]);
      red[0][4] = fmaxf(red[0][4], red[w][4]);
      red[0][5] = fmaxf(red[0][5], red[w][5]);
    }
    float* o = part + blk * 8;
    o[0] = red[0][0]; o[1] = red[0][1]; o[2] = red[0][2];
    o[3] = red[0][3]; o[4] = red[0][4]; o[5] = red[0][5];
  }
}

// ---------------------------------------------------------------- K0b: final bbox reduce (4 blocks x 64 thr)
__global__ __launch_bounds__(64) void k_bbox2(const float* __restrict__ part,
                                              float* __restrict__ gp) {
  const int b = blockIdx.x, t = threadIdx.x;
  const float* pp = part + (b * 32 + (t & 31)) * 8;  // lanes 32..63 duplicate
  float mnx = pp[0], mny = pp[1], mnz = pp[2];
  float mxx = pp[3], mxy = pp[4], mxz = pp[5];
#pragma unroll
  for (int d = 1; d < 64; d <<= 1) {
    mnx = fminf(mnx, __shfl_xor(mnx, d)); mny = fminf(mny, __shfl_xor(mny, d));
    mnz = fminf(mnz, __shfl_xor(mnz, d)); mxx = fmaxf(mxx, __shfl_xor(mxx, d));
    mxy = fmaxf(mxy, __shfl_xor(mxy, d)); mxz = fmaxf(mxz, __shfl_xor(mxz, d));
  }
  if (t == 0) {
    float rmax = fmaxf(mxx - mnx, fmaxf(mxy - mny, mxz - mnz));
    float s = rmax / (float)GRID;
    float* g = gp + b * 8;
    g[0] = mnx; g[1] = mny; g[2] = mnz;
    g[3] = s; g[4] = 1.0f / s;
  }
}

// ---------------------------------------------------------------- K2: count
__global__ __launch_bounds__(256) void k_count(const float4* __restrict__ xytp,
                                               const float* __restrict__ gp,
                                               int* __restrict__ cnt) {
  int i = blockIdx.x * 256 + threadIdx.x;
  int b = i >> 13;
  const float* g = gp + b * 8;
  float4 p = xytp[i];
  int cx = cellof(p.x, g[0], g[4]);
  int cy = cellof(p.y, g[1], g[4]);
  int cz = cellof(p.z, g[2], g[4]);
  atomicAdd(&cnt[b * NCELL + (cz * GRID + cy) * GRID + cx], 1);
}

// ---------------------------------------------------------------- K3: exclusive scan
__global__ __launch_bounds__(1024) void k_scan(const int* __restrict__ cnt,
                                               int* __restrict__ offs,
                                               int* __restrict__ curs) {
  __shared__ int wsum[16];
  const int b = blockIdx.x, t = threadIdx.x;
  const int base = b * NCELL;
  const int base2 = b * NCELLP;
  const int lo = t * 14;
  const int hi = lo + 14 < NCELL ? lo + 14 : NCELL;
  int s = 0;
  for (int c = lo; c < hi; ++c) s += cnt[base + c];
  const int lane = t & 63, wv = t >> 6;
  int v = s;
#pragma unroll
  for (int d = 1; d < 64; d <<= 1) {
    int u = __shfl_up(v, d);
    if (lane >= d) v += u;
  }
  if (lane == 63) wsum[wv] = v;
  __syncthreads();
  if (wv == 0 && lane < 16) {
    int x = wsum[lane];
#pragma unroll
    for (int d = 1; d < 16; d <<= 1) {
      int u = __shfl_up(x, d, 16);
      if (lane >= d) x += u;
    }
    wsum[lane] = x;
  }
  __syncthreads();
  int excl = (wv > 0 ? wsum[wv - 1] : 0) + v - s;
  for (int c = lo; c < hi; ++c) {
    offs[base2 + c] = excl;
    curs[base + c] = excl;
    excl += cnt[base + c];
  }
  if (hi == NCELL) offs[base2 + NCELL] = excl;  // == NPTS
}

// ---------------------------------------------------------------- K4: scatter (cell-sorted points, sq in .w, idx in sidx)
__global__ __launch_bounds__(256) void k_scatter(const float4* __restrict__ xytp,
                                                 const float* __restrict__ gp,
                                                 int* __restrict__ curs,
                                                 float4* __restrict__ spts,
                                                 u16* __restrict__ sidx) {
  int i = blockIdx.x * 256 + threadIdx.x;
  int b = i >> 13, n = i & 8191;
  const float* g = gp + b * 8;
  float4 p = xytp[i];
  int cx = cellof(p.x, g[0], g[4]);
  int cy = cellof(p.y, g[1], g[4]);
  int cz = cellof(p.z, g[2], g[4]);
  int pos = atomicAdd(&curs[b * NCELL + (cz * GRID + cy) * GRID + cx], 1);
  float sq = fmaf(p.z, p.z, fmaf(p.y, p.y, p.x * p.x));
  spts[(b << 13) + pos] = make_float4(p.x, p.y, p.z, sq);
  sidx[(b << 13) + pos] = (u16)n;
}

// ---------------------------------------------------------------- K4b: LPT query ordering (R22)
__global__ __launch_bounds__(1024) void k_order(const float4* __restrict__ spts,
                                                const int* __restrict__ offs,
                                                const float* __restrict__ gp,
                                                u16* __restrict__ ord) {
  __shared__ int hist[32];
  __shared__ int strt[32];
  const int b = blockIdx.x, t = threadIdx.x;
  if (t < 32) hist[t] = 0;
  __syncthreads();
  const float* g = gp + b * 8;
  const int* ob = offs + b * NCELLP;
  const float4* sp = spts + (b << 13);
  int key[8];
#pragma unroll
  for (int it = 0; it < 8; ++it) {
    const int i = t + it * 1024;
    float4 p = sp[i];
    int cx = cellof(p.x, g[0], g[4]);
    int cy = cellof(p.y, g[1], g[4]);
    int cz = cellof(p.z, g[2], g[4]);
    int c = (cz * GRID + cy) * GRID + cx;
    int cc = ob[c + 1] - ob[c];  // >= 1 (query itself)
    key[it] = cc - 1 < 31 ? cc - 1 : 31;
    atomicAdd(&hist[key[it]], 1);
  }
  __syncthreads();
  if (t == 0) {
    int acc = 0;
    for (int k2 = 0; k2 < 32; ++k2) { strt[k2] = acc; acc += hist[k2]; }
  }
  __syncthreads();
  u16* ob2 = ord + (b << 13);
#pragma unroll
  for (int it = 0; it < 8; ++it) {
    const int i = t + it * 1024;
    int pos = atomicAdd(&strt[key[it]], 1);
    ob2[pos] = (u16)i;
  }
}

// ---------------------------------------------------------------- K5: grid KNN query
// R22 structure (32-wide teams, uniform-trip concat dealing, mn-
// tightened count-stop, LPT indirection) — unchanged in R14.
#define INSERTC(Af, OI)                                                      \
  {                                                                          \
    float dot = q.x * (Af).x;                                                \
    dot = fmaf(q.y, (Af).y, dot);                                            \
    dot = fmaf(q.z, (Af).z, dot);                                            \
    float d2 = (qsq + (Af).w) - 2.0f * dot;                                  \
    unsigned u = __float_as_uint(d2);                                        \
    u ^= (0x80000000u | (unsigned)((int)u >> 31));                           \
    u64 key = ((u64)u << 32) | (OI);                                         \
    if (key < lst[15]) {                                                     \
      u64 x = key;                                                           \
      _Pragma("unroll") for (int p = 0; p < 16; ++p) {                       \
        bool sw = x < lst[p];                                                \
        u64 a = lst[p];                                                      \
        lst[p] = sw ? x : a;                                                 \
        x = sw ? a : x;                                                      \
      }                                                                      \
    }                                                                        \
  }

#define CSWAP(ia, ib)                                                        \
  {                                                                          \
    u64 ta = c[ia], tb2 = c[ib];                                             \
    bool sw = ta > tb2;                                                      \
    c[ia] = sw ? tb2 : ta;                                                   \
    c[ib] = sw ? ta : tb2;                                                   \
  }

__global__ __launch_bounds__(256) void k_query(const float4* __restrict__ spts,
                                               const u16* __restrict__ sidx,
                                               const int* __restrict__ offs,
                                               const float* __restrict__ gp,
                                               const u16* __restrict__ ord,
                                               u16* __restrict__ oidx) {
  const int lane = threadIdx.x & 63;
  const int l = threadIdx.x & 31;        // team lane
  const int qid = blockIdx.x * 8 + (threadIdx.x >> 5);  // 8 teams/block
  const int b = qid >> 13;
  const int i = ord[(b << 13) + (qid & 8191)];  // LPT permutation
  const int tb = lane & 32;              // team base within wave (0 or 32)
  const float4* __restrict__ sp = spts + (b << 13);
  const u16* __restrict__ sx = sidx + (b << 13);
  const int* __restrict__ ob = offs + b * NCELLP;
  const float* g = gp + b * 8;
  float4 q = sp[i];
  const float qsq = q.w;  // sq precomputed
  const unsigned orig = sx[i];
  const int cx = cellof(q.x, g[0], g[4]);
  const int cy = cellof(q.y, g[1], g[4]);
  const int cz = cellof(q.z, g[2], g[4]);
  const float s = g[3];
  const float fx = q.x - fmaf((float)cx, s, g[0]);
  const float fy = q.y - fmaf((float)cy, s, g[1]);
  const float fz = q.z - fmaf((float)cz, s, g[2]);
  const float mn = fmaxf(
      0.0f, fminf(fminf(fminf(fx, s - fx), fminf(fy, s - fy)),
                  fminf(fz, s - fz)));

  u64 lst[16];
#pragma unroll
  for (int p = 0; p < 16; ++p) lst[p] = ~0ULL;

  for (int r = 0; r <= GRID; ++r) {
    const int W = 2 * r + 1;
    const int nent = 2 * W * W;
    for (int cb = 0; cb < nent; cb += 32) {
      int ms0 = 0, ms1 = 0;
      const int eid = cb + l;
      if (eid < nent) {
        const int rid = eid >> 1, side = eid & 1;
        const int dz = rid / W - r;
        const int dy = rid % W - r;
        const int z2 = cz + dz, y2 = cy + dy;
        if ((unsigned)z2 < GRID && (unsigned)y2 < GRID) {
          const int rowb = (z2 * GRID + y2) * GRID;
          const bool bdry = (dz == -r) || (dz == r) || (dy == -r) || (dy == r);
          if (bdry) {
            if (side == 0) {
              const int xl = cx - r < 0 ? 0 : cx - r;
              const int xh = cx + r > GRID - 1 ? GRID - 1 : cx + r;
              ms0 = ob[rowb + xl];
              ms1 = ob[rowb + xh + 1];
            }
          } else {
            const int x2 = side ? cx + r : cx - r;
            if ((unsigned)x2 < GRID) {
              ms0 = ob[rowb + x2];
              ms1 = ob[rowb + x2 + 1];
            }
          }
        }
      }
      const int len = ms1 - ms0;  // >= 0
      int pre = len;
#pragma unroll
      for (int d = 1; d < 32; d <<= 1) {
        int u2 = __shfl_up(pre, d);
        if (l >= d) pre += u2;
      }
      const int total = __shfl(pre, tb + 31);
      if (total == 0) continue;
      const int base = ms0 - (pre - len);  // ms0 - exclusive_prefix
      for (int vb = 0; vb < total; vb += 32) {
        const int vidx = vb + l;
        int e = 0;
#pragma unroll
        for (int s2 = 16; s2 >= 1; s2 >>= 1) {
          int pv = __shfl(pre, tb + e + s2 - 1);
          if (pv <= vidx) e += s2;
        }
        const int jb = __shfl(base, tb + e);
        if (vidx < total) {
          const int j = jb + vidx;
          float4 A = sp[j];
          unsigned oi = sx[j];
          INSERTC(A, oi)
        }
      }
    }
    const float rs = fmaf((float)r, s, mn);
    const float T = fmaf(rs, rs, -1e-4f);
    unsigned tu = __float_as_uint(T);
    tu ^= (0x80000000u | (unsigned)((int)tu >> 31));
    int c = 0;
#pragma unroll
    for (int p = 0; p < 16; ++p) c += ((unsigned)(lst[p] >> 32) <= tu) ? 1 : 0;
    c += __shfl_xor(c, 1);
    c += __shfl_xor(c, 2);
    c += __shfl_xor(c, 4);
    c += __shfl_xor(c, 8);
    c += __shfl_xor(c, 16);
    if (c >= 16) break;  // team-uniform break
  }

#pragma unroll
  for (int mm = 1; mm <= 16; mm <<= 1) {
    u64 c[16];
    const bool keepmin = (l & mm) == 0;
#pragma unroll
    for (int p = 0; p < 16; ++p) {
      u64 o = __shfl_xor(lst[15 - p], mm);
      u64 a = lst[p];
      u64 lo = a < o ? a : o;
      u64 hi = a < o ? o : a;
      c[p] = keepmin ? lo : hi;
    }
    CSWAP(0, 8) CSWAP(1, 9) CSWAP(2, 10) CSWAP(3, 11)
    CSWAP(4, 12) CSWAP(5, 13) CSWAP(6, 14) CSWAP(7, 15)
    CSWAP(0, 4) CSWAP(1, 5) CSWAP(2, 6) CSWAP(3, 7)
    CSWAP(8, 12) CSWAP(9, 13) CSWAP(10, 14) CSWAP(11, 15)
    CSWAP(0, 2) CSWAP(1, 3) CSWAP(4, 6) CSWAP(5, 7)
    CSWAP(8, 10) CSWAP(9, 11) CSWAP(12, 14) CSWAP(13, 15)
    CSWAP(0, 1) CSWAP(2, 3) CSWAP(4, 5) CSWAP(6, 7)
    CSWAP(8, 9) CSWAP(10, 11) CSWAP(12, 13) CSWAP(14, 15)
#pragma unroll
    for (int p = 0; p < 16; ++p) lst[p] = c[p];
  }

  if (l == 0) {  // team lane 0 holds the sorted team top-16
    unsigned pk[8];
#pragma unroll
    for (int k = 0; k < 16; k += 2)
      pk[k >> 1] = (unsigned)(lst[k] & 0xFFFFull) |
                   ((unsigned)(lst[k + 1] & 0xFFFFull) << 16);
    unsigned* od = (unsigned*)(oidx + (((size_t)(b << 13) + orig) << 4));
#pragma unroll
    for (int k = 0; k < 8; ++k) od[k] = pk[k];
  }
}

// ---------------------------------------------------------------- K6: lt = feat @ lt_w + lt_b
// R14: output row = [varphi f32 x64 | packed bf16 (psi,alp) u32 x64]
// (512B/pt, was 768B).  Thread owns the SAME 8 channels across all 3
// sections so psi/alp pairing is thread-local; RNE bf16 pack.  k_main
// then gathers ONE 256B u32 row per neighbor (was 2x256B f32) ->
// halves gather bytes + instructions.  bf16 err ~0.004 abs on O(1)
// psi/alp vs 0.09 threshold.
__global__ __launch_bounds__(256) void k_lt(const float* __restrict__ feat,
                                            const float* __restrict__ ltw,
                                            const float* __restrict__ ltb,
                                            float* __restrict__ lt) {
  __shared__ float sw[64][196];
  __shared__ float sf[32][68];
  const int tid = threadIdx.x;
  const int r0 = blockIdx.x * 32;
#pragma unroll
  for (int i = 0; i < 12; ++i) {
    int v = tid + i * 256;
    float4 w4 = ((const float4*)ltw)[v];
    int row = (v * 4) / 192, col = (v * 4) % 192;
    *(float4*)&sw[row][col] = w4;
  }
#pragma unroll
  for (int i = 0; i < 2; ++i) {
    int v = tid + i * 256;
    int row = v >> 4, c4 = v & 15;
    float4 f4 = ((const float4*)(feat + (size_t)(r0 + row) * 64))[c4];
    *(float4*)&sf[row][c4 * 4] = f4;
  }
  __syncthreads();
  const int r = tid >> 3;
  const int c0 = (tid & 7) * 8;  // 8 channels, same across 3 sections
  float acc[24];                 // [0..7]=varphi, [8..15]=psi, [16..23]=alp
#pragma unroll
  for (int m = 0; m < 8; ++m) {
    acc[m] = ltb[c0 + m];
    acc[8 + m] = ltb[64 + c0 + m];
    acc[16 + m] = ltb[128 + c0 + m];
  }
#pragma unroll 4
  for (int j = 0; j < 64; ++j) {
    float f = sf[r][j];
#pragma unroll
    for (int sec = 0; sec < 3; ++sec) {
      float4 w4a = *(const float4*)&sw[j][sec * 64 + c0];
      float4 w4b = *(const float4*)&sw[j][sec * 64 + c0 + 4];
      acc[sec * 8 + 0] = fmaf(f, w4a.x, acc[sec * 8 + 0]);
      acc[sec * 8 + 1] = fmaf(f, w4a.y, acc[sec * 8 + 1]);
      acc[sec * 8 + 2] = fmaf(f, w4a.z, acc[sec * 8 + 2]);
      acc[sec * 8 + 3] = fmaf(f, w4a.w, acc[sec * 8 + 3]);
      acc[sec * 8 + 4] = fmaf(f, w4b.x, acc[sec * 8 + 4]);
      acc[sec * 8 + 5] = fmaf(f, w4b.y, acc[sec * 8 + 5]);
      acc[sec * 8 + 6] = fmaf(f, w4b.z, acc[sec * 8 + 6]);
      acc[sec * 8 + 7] = fmaf(f, w4b.w, acc[sec * 8 + 7]);
    }
  }
  float* orow = lt + (size_t)(r0 + r) * 128;
  *(float4*)&orow[c0] = make_float4(acc[0], acc[1], acc[2], acc[3]);
  *(float4*)&orow[c0 + 4] = make_float4(acc[4], acc[5], acc[6], acc[7]);
  u32 pk[8];
#pragma unroll
  for (int m = 0; m < 8; ++m)
    pk[m] = f2bf(acc[8 + m]) | (f2bf(acc[16 + m]) << 16);
  u32* prow = (u32*)orow + 64 + c0;
  *(uint4*)&prow[0] = make_uint4(pk[0], pk[1], pk[2], pk[3]);
  *(uint4*)&prow[4] = make_uint4(pk[4], pk[5], pk[6], pk[7]);
}

// ---------------------------------------------------------------- K7: main
// R14: psi/alp gathered as ONE packed-bf16 u32 per neighbor row
// (256B coalesced; halves gather traffic).  Unpack: psi bits = v<<16,
// alp bits = v & 0xFFFF0000.  Prefetch distance 2 (static A/B slots).
// Online softmax + DPP LN reductions unchanged.
template <int CTRL>
__device__ __forceinline__ float dpp_add_f(float x) {
  int y = __builtin_amdgcn_update_dpp(0, __float_as_int(x), CTRL, 0xf, 0xf,
                                      true);
  return x + __int_as_float(y);
}
__device__ __forceinline__ float wave_sum64(float x) {
  x = dpp_add_f<0x111>(x);  // row_shr:1
  x = dpp_add_f<0x112>(x);  // row_shr:2
  x = dpp_add_f<0x114>(x);  // row_shr:4
  x = dpp_add_f<0x118>(x);  // row_shr:8
  x = dpp_add_f<0x142>(x);  // row_bcast:15
  x = dpp_add_f<0x143>(x);  // row_bcast:31
  return __int_as_float(__builtin_amdgcn_readlane(__float_as_int(x), 63));
}

__global__ __launch_bounds__(256) void k_main(
    const float4* __restrict__ xytp, const float* __restrict__ lt,
    const u16* __restrict__ knn, const float* __restrict__ pe_w1,
    const float* __restrict__ pe_b1, const float* __restrict__ pe_w2,
    const float* __restrict__ pe_b2, const float* __restrict__ ln_g,
    const float* __restrict__ ln_b, float* __restrict__ out) {
  __shared__ float s_h[4][16][64];
  const int lane = threadIdx.x & 63;
  const int wave = threadIdx.x >> 6;
  const int pid = __builtin_amdgcn_readfirstlane(blockIdx.x * 4 + wave);
  const int b = pid >> 13;
  const int n = pid & 8191;

  float w1c[4];
#pragma unroll
  for (int d = 0; d < 4; ++d) w1c[d] = pe_w1[d * 64 + lane];
  const float b1c = pe_b1[lane];
  float w2c[64];
#pragma unroll
  for (int j = 0; j < 64; ++j) w2c[j] = pe_w2[j * 64 + lane];
  const float b2c = pe_b2[lane];
  const float gc = ln_g[lane], bc = ln_b[lane];

  int nb[16];
#pragma unroll
  for (int k = 0; k < 16; ++k) nb[k] = knn[pid * 16 + k];

  const float* __restrict__ ltb = lt + (size_t)(b << 13) * 128;
  const float vc = ltb[(size_t)n * 128 + lane];

  const float4 qv = xytp[(b << 13) + n];
#pragma unroll
  for (int k = 0; k < 16; ++k) {
    float4 g = xytp[(b << 13) + nb[k]];
    float r0 = qv.x - g.x, r1 = qv.y - g.y, r2 = qv.z - g.z, r3 = qv.w - g.w;
    float h = fmaf(r3, w1c[3],
                   fmaf(r2, w1c[2], fmaf(r1, w1c[1], fmaf(r0, w1c[0], b1c))));
    s_h[wave][k][lane] = fmaxf(h, 0.0f);
  }
  __syncthreads();

  // prefetch distance 2: packed psi/alp u32, static A/B slot rotation
  u32 uA = ((const u32*)(ltb + (size_t)nb[0] * 128 + 64))[lane];
  u32 uB = ((const u32*)(ltb + (size_t)nb[1] * 128 + 64))[lane];
  float m = -INFINITY, se = 0.f, oacc = 0.f;
#pragma unroll
  for (int k = 0; k < 16; ++k) {
    const u32 uc = (k & 1) ? uB : uA;
    if (k < 14) {  // refill the slot just consumed with row k+2
      const u32* prow = (const u32*)(ltb + (size_t)nb[k + 2] * 128 + 64);
      if (k & 1) uB = prow[lane];
      else       uA = prow[lane];
    }
    const float psi_c = __uint_as_float(uc << 16);
    const float alp_c = __uint_as_float(uc & 0xFFFF0000u);
    float acc = b2c;
#pragma unroll
    for (int j4 = 0; j4 < 16; ++j4) {
      float4 h4 = *(const float4*)&s_h[wave][k][j4 * 4];
      acc = fmaf(h4.x, w2c[j4 * 4 + 0], acc);
      acc = fmaf(h4.y, w2c[j4 * 4 + 1], acc);
      acc = fmaf(h4.z, w2c[j4 * 4 + 2], acc);
      acc = fmaf(h4.w, w2c[j4 * 4 + 3], acc);
    }
    const float pre = (vc - psi_c) + acc;
    const float apd = alp_c + acc;
    const float sm = wave_sum64(pre);
    const float ssm = wave_sum64(pre * pre);
    const float mu = sm * 0.015625f;
    const float var = fmaf(ssm, 0.015625f, -mu * mu);
    const float inv = rsqrtf(var + 1e-5f);
    const float x = fmaf((pre - mu) * inv, gc, bc) * 0.125f;
    const float mn = fmaxf(m, x);
    const float corr = __expf(m - mn);
    const float e = __expf(x - mn);
    se = fmaf(se, corr, e);
    oacc = fmaf(oacc, corr, e * apd);
    m = mn;
  }
  out[(size_t)pid * 64 + lane] = oacc / se;
}

// ---------------------------------------------------------------- launch
extern "C" void kernel_launch(void* const* d_in, const int* in_sizes, int n_in,
                              void* d_out, int out_size, void* d_ws,
                              size_t ws_size, hipStream_t stream) {
  const float4* xytp = (const float4*)d_in[0];
  const float* features = (const float*)d_in[1];
  const float* pe_w1 = (const float*)d_in[2];
  const float* pe_b1 = (const float*)d_in[3];
  const float* pe_w2 = (const float*)d_in[4];
  const float* pe_b2 = (const float*)d_in[5];
  const float* lt_w = (const float*)d_in[6];
  const float* lt_b = (const float*)d_in[7];
  const float* ln_g = (const float*)d_in[8];
  const float* ln_b = (const float*)d_in[9];
  float* out = (float*)d_out;

  char* ws = (char*)d_ws;
  u16* idxbuf = (u16*)(ws + WS_IDX);
  float* lt = (float*)(ws + WS_LT);
  int* cnt = (int*)(ws + WS_CNT);
  int* offs = (int*)(ws + WS_OFF);
  int* curs = (int*)(ws + WS_CUR);
  float4* spts = (float4*)(ws + WS_SP);
  float* gp = (float*)(ws + WS_GP);
  u16* sidx = (u16*)(ws + WS_SIDX);
  u16* ordb = (u16*)(ws + WS_CNT);  // cnt is dead after k_scan

  k_bbox1<<<128, 256, 0, stream>>>(xytp, (float*)(ws + WS_CUR), cnt);
  k_bbox2<<<BATCH, 64, 0, stream>>>((const float*)(ws + WS_CUR), gp);
  k_count<<<(BATCH * NPTS) / 256, 256, 0, stream>>>(xytp, gp, cnt);
  k_scan<<<BATCH, 1024, 0, stream>>>(cnt, offs, curs);
  k_scatter<<<(BATCH * NPTS) / 256, 256, 0, stream>>>(xytp, gp, curs, spts,
                                                      sidx);
  k_order<<<BATCH, 1024, 0, stream>>>(spts, offs, gp, ordb);
  k_query<<<(BATCH * NPTS) / 8, 256, 0, stream>>>(spts, sidx, offs, gp, ordb,
                                                  idxbuf);
  k_lt<<<(BATCH * NPTS) / 32, 256, 0, stream>>>(features, lt_w, lt_b, lt);
  k_main<<<(BATCH * NPTS) / 4, 256, 0, stream>>>(xytp, lt, idxbuf, pe_w1,
                                                 pe_b1, pe_w2, pe_b2, ln_g,
                                                 ln_b, out);
}

// Round 16
// 351.045 us; speedup vs baseline: 1.3445x; 1.0810x over previous
//
#include <hip/hip_runtime.h>
#include <stdint.h>

#define BATCH 4
#define NPTS 8192
#define KNN_K 16
#define GRID 24
#define NCELL (GRID * GRID * GRID)  // 13824
#define NCELLP (NCELL + 8)          // offs stride (sentinel slot)

typedef unsigned long long u64;
typedef unsigned int u32;
typedef unsigned short u16;

// ws layout (bytes)
#define WS_IDX 0u          // u16[4*8192*16]            = 1,048,576
#define WS_LT 1048576u     // row=[varphi f32 x64 | packed bf16 (psi,alp) u32 x64] = 512B/pt
#define WS_CNT 26214400u   // int[4*13824]              = 221,184  (dead after k_scan -> ord u16[4*8192])
#define WS_OFF 26435584u   // int[4*13832]              = 221,312
#define WS_CUR 26656896u   // int[4*13824]              = 221,184  (also bbox partials before k_scan)
#define WS_SP 26878080u    // float4[4*8192]            = 524,288
#define WS_GP 27402368u    // float[4*8]                = 128
#define WS_SIDX 27402496u  // u16[4*8192]               = 65,536

__device__ __forceinline__ int cellof(float v, float o, float invs) {
  int c = (int)((v - o) * invs);
  return c < GRID - 1 ? c : GRID - 1;
}

__device__ __forceinline__ u32 f2bf(float v) {  // RNE bf16 (high 16 bits)
  u32 x = __float_as_uint(v);
  return (x + 0x7FFFu + ((x >> 16) & 1u)) >> 16;
}

typedef _Float16 hv2 __attribute__((ext_vector_type(2)));
union U32H2 { u32 u; hv2 h; };
__device__ __forceinline__ float fdot2u(u32 a, u32 b, float c) {
  U32H2 x, y; x.u = a; y.u = b;
  return __builtin_amdgcn_fdot2(x.h, y.h, c, false);
}
__device__ __forceinline__ u16 f16b(float v) {  // RNE scalar f16 bits
  union { _Float16 f; u16 b; } c; c.f = (_Float16)v; return c.b;
}
__device__ __forceinline__ u32 pkf16(float a, float b) {  // RNE pack
  return (u32)f16b(a) | ((u32)f16b(b) << 16);
}

// ---------------------------------------------------------------- K0a: partial bbox (128 blocks) + zero counters
__global__ __launch_bounds__(256) void k_bbox1(const float4* __restrict__ xytp,
                                               float* __restrict__ part,
                                               int* __restrict__ cnt) {
  const int blk = blockIdx.x;  // 0..127
  const int b = blk >> 5, sub = blk & 31;
  const int t = threadIdx.x;
#pragma unroll
  for (int i = 0; i < 2; ++i) {
    int v = t + i * 256;
    if (v < 432) cnt[blk * 432 + v] = 0;
  }
  float4 p = xytp[(b << 13) + (sub << 8) + t];
  float mnx = p.x, mny = p.y, mnz = p.z;
  float mxx = p.x, mxy = p.y, mxz = p.z;
#pragma unroll
  for (int d = 1; d < 64; d <<= 1) {
    mnx = fminf(mnx, __shfl_xor(mnx, d)); mny = fminf(mny, __shfl_xor(mny, d));
    mnz = fminf(mnz, __shfl_xor(mnz, d)); mxx = fmaxf(mxx, __shfl_xor(mxx, d));
    mxy = fmaxf(mxy, __shfl_xor(mxy, d)); mxz = fmaxf(mxz, __shfl_xor(mxz, d));
  }
  __shared__ float red[4][6];
  const int lane = t & 63, wv = t >> 6;
  if (lane == 0) {
    red[wv][0] = mnx; red[wv][1] = mny; red[wv][2] = mnz;
    red[wv][3] = mxx; red[wv][4] = mxy; red[wv][5] = mxz;
  }
  __syncthreads();
  if (t == 0) {
    for (int w = 1; w < 4; ++w) {
      red[0][0] = fminf(red[0][0], red[w][0]);
      red[0][1] = fminf(red[0][1], red[w][1]);
      red[0][2] = fminf(red[0][2], red[w][2]);
      red[0][3] = fmaxf(red[0][3], red[w][3]);
      red[0][4] = fmaxf(red[0][4], red[w][4]);
      red[0][5] = fmaxf(red[0][5], red[w][5]);
    }
    float* o = part + blk * 8;
    o[0] = red[0][0]; o[1] = red[0][1]; o[2] = red[0][2];
    o[3] = red[0][3]; o[4] = red[0][4]; o[5] = red[0][5];
  }
}

// ---------------------------------------------------------------- K0b: final bbox reduce (4 blocks x 64 thr)
__global__ __launch_bounds__(64) void k_bbox2(const float* __restrict__ part,
                                              float* __restrict__ gp) {
  const int b = blockIdx.x, t = threadIdx.x;
  const float* pp = part + (b * 32 + (t & 31)) * 8;  // lanes 32..63 duplicate
  float mnx = pp[0], mny = pp[1], mnz = pp[2];
  float mxx = pp[3], mxy = pp[4], mxz = pp[5];
#pragma unroll
  for (int d = 1; d < 64; d <<= 1) {
    mnx = fminf(mnx, __shfl_xor(mnx, d)); mny = fminf(mny, __shfl_xor(mny, d));
    mnz = fminf(mnz, __shfl_xor(mnz, d)); mxx = fmaxf(mxx, __shfl_xor(mxx, d));
    mxy = fmaxf(mxy, __shfl_xor(mxy, d)); mxz = fmaxf(mxz, __shfl_xor(mxz, d));
  }
  if (t == 0) {
    float rmax = fmaxf(mxx - mnx, fmaxf(mxy - mny, mxz - mnz));
    float s = rmax / (float)GRID;
    float* g = gp + b * 8;
    g[0] = mnx; g[1] = mny; g[2] = mnz;
    g[3] = s; g[4] = 1.0f / s;
  }
}

// ---------------------------------------------------------------- K2: count
__global__ __launch_bounds__(256) void k_count(const float4* __restrict__ xytp,
                                               const float* __restrict__ gp,
                                               int* __restrict__ cnt) {
  int i = blockIdx.x * 256 + threadIdx.x;
  int b = i >> 13;
  const float* g = gp + b * 8;
  float4 p = xytp[i];
  int cx = cellof(p.x, g[0], g[4]);
  int cy = cellof(p.y, g[1], g[4]);
  int cz = cellof(p.z, g[2], g[4]);
  atomicAdd(&cnt[b * NCELL + (cz * GRID + cy) * GRID + cx], 1);
}

// ---------------------------------------------------------------- K3: exclusive scan
__global__ __launch_bounds__(1024) void k_scan(const int* __restrict__ cnt,
                                               int* __restrict__ offs,
                                               int* __restrict__ curs) {
  __shared__ int wsum[16];
  const int b = blockIdx.x, t = threadIdx.x;
  const int base = b * NCELL;
  const int base2 = b * NCELLP;
  const int lo = t * 14;
  const int hi = lo + 14 < NCELL ? lo + 14 : NCELL;
  int s = 0;
  for (int c = lo; c < hi; ++c) s += cnt[base + c];
  const int lane = t & 63, wv = t >> 6;
  int v = s;
#pragma unroll
  for (int d = 1; d < 64; d <<= 1) {
    int u = __shfl_up(v, d);
    if (lane >= d) v += u;
  }
  if (lane == 63) wsum[wv] = v;
  __syncthreads();
  if (wv == 0 && lane < 16) {
    int x = wsum[lane];
#pragma unroll
    for (int d = 1; d < 16; d <<= 1) {
      int u = __shfl_up(x, d, 16);
      if (lane >= d) x += u;
    }
    wsum[lane] = x;
  }
  __syncthreads();
  int excl = (wv > 0 ? wsum[wv - 1] : 0) + v - s;
  for (int c = lo; c < hi; ++c) {
    offs[base2 + c] = excl;
    curs[base + c] = excl;
    excl += cnt[base + c];
  }
  if (hi == NCELL) offs[base2 + NCELL] = excl;  // == NPTS
}

// ---------------------------------------------------------------- K4: scatter (cell-sorted points, sq in .w, idx in sidx)
__global__ __launch_bounds__(256) void k_scatter(const float4* __restrict__ xytp,
                                                 const float* __restrict__ gp,
                                                 int* __restrict__ curs,
                                                 float4* __restrict__ spts,
                                                 u16* __restrict__ sidx) {
  int i = blockIdx.x * 256 + threadIdx.x;
  int b = i >> 13, n = i & 8191;
  const float* g = gp + b * 8;
  float4 p = xytp[i];
  int cx = cellof(p.x, g[0], g[4]);
  int cy = cellof(p.y, g[1], g[4]);
  int cz = cellof(p.z, g[2], g[4]);
  int pos = atomicAdd(&curs[b * NCELL + (cz * GRID + cy) * GRID + cx], 1);
  float sq = fmaf(p.z, p.z, fmaf(p.y, p.y, p.x * p.x));
  spts[(b << 13) + pos] = make_float4(p.x, p.y, p.z, sq);
  sidx[(b << 13) + pos] = (u16)n;
}

// ---------------------------------------------------------------- K4b: LPT query ordering (R22)
__global__ __launch_bounds__(1024) void k_order(const float4* __restrict__ spts,
                                                const int* __restrict__ offs,
                                                const float* __restrict__ gp,
                                                u16* __restrict__ ord) {
  __shared__ int hist[32];
  __shared__ int strt[32];
  const int b = blockIdx.x, t = threadIdx.x;
  if (t < 32) hist[t] = 0;
  __syncthreads();
  const float* g = gp + b * 8;
  const int* ob = offs + b * NCELLP;
  const float4* sp = spts + (b << 13);
  int key[8];
#pragma unroll
  for (int it = 0; it < 8; ++it) {
    const int i = t + it * 1024;
    float4 p = sp[i];
    int cx = cellof(p.x, g[0], g[4]);
    int cy = cellof(p.y, g[1], g[4]);
    int cz = cellof(p.z, g[2], g[4]);
    int c = (cz * GRID + cy) * GRID + cx;
    int cc = ob[c + 1] - ob[c];  // >= 1 (query itself)
    key[it] = cc - 1 < 31 ? cc - 1 : 31;
    atomicAdd(&hist[key[it]], 1);
  }
  __syncthreads();
  if (t == 0) {
    int acc = 0;
    for (int k2 = 0; k2 < 32; ++k2) { strt[k2] = acc; acc += hist[k2]; }
  }
  __syncthreads();
  u16* ob2 = ord + (b << 13);
#pragma unroll
  for (int it = 0; it < 8; ++it) {
    const int i = t + it * 1024;
    int pos = atomicAdd(&strt[key[it]], 1);
    ob2[pos] = (u16)i;
  }
}

// ---------------------------------------------------------------- K5: grid KNN query
// R22 structure (32-wide teams, uniform-trip concat dealing, mn-
// tightened count-stop, LPT indirection) — unchanged.
#define INSERTC(Af, OI)                                                      \
  {                                                                          \
    float dot = q.x * (Af).x;                                                \
    dot = fmaf(q.y, (Af).y, dot);                                            \
    dot = fmaf(q.z, (Af).z, dot);                                            \
    float d2 = (qsq + (Af).w) - 2.0f * dot;                                  \
    unsigned u = __float_as_uint(d2);                                        \
    u ^= (0x80000000u | (unsigned)((int)u >> 31));                           \
    u64 key = ((u64)u << 32) | (OI);                                         \
    if (key < lst[15]) {                                                     \
      u64 x = key;                                                           \
      _Pragma("unroll") for (int p = 0; p < 16; ++p) {                       \
        bool sw = x < lst[p];                                                \
        u64 a = lst[p];                                                      \
        lst[p] = sw ? x : a;                                                 \
        x = sw ? a : x;                                                      \
      }                                                                      \
    }                                                                        \
  }

#define CSWAP(ia, ib)                                                        \
  {                                                                          \
    u64 ta = c[ia], tb2 = c[ib];                                             \
    bool sw = ta > tb2;                                                      \
    c[ia] = sw ? tb2 : ta;                                                   \
    c[ib] = sw ? ta : tb2;                                                   \
  }

__global__ __launch_bounds__(256) void k_query(const float4* __restrict__ spts,
                                               const u16* __restrict__ sidx,
                                               const int* __restrict__ offs,
                                               const float* __restrict__ gp,
                                               const u16* __restrict__ ord,
                                               u16* __restrict__ oidx) {
  const int lane = threadIdx.x & 63;
  const int l = threadIdx.x & 31;        // team lane
  const int qid = blockIdx.x * 8 + (threadIdx.x >> 5);  // 8 teams/block
  const int b = qid >> 13;
  const int i = ord[(b << 13) + (qid & 8191)];  // LPT permutation
  const int tb = lane & 32;              // team base within wave (0 or 32)
  const float4* __restrict__ sp = spts + (b << 13);
  const u16* __restrict__ sx = sidx + (b << 13);
  const int* __restrict__ ob = offs + b * NCELLP;
  const float* g = gp + b * 8;
  float4 q = sp[i];
  const float qsq = q.w;  // sq precomputed
  const unsigned orig = sx[i];
  const int cx = cellof(q.x, g[0], g[4]);
  const int cy = cellof(q.y, g[1], g[4]);
  const int cz = cellof(q.z, g[2], g[4]);
  const float s = g[3];
  const float fx = q.x - fmaf((float)cx, s, g[0]);
  const float fy = q.y - fmaf((float)cy, s, g[1]);
  const float fz = q.z - fmaf((float)cz, s, g[2]);
  const float mn = fmaxf(
      0.0f, fminf(fminf(fminf(fx, s - fx), fminf(fy, s - fy)),
                  fminf(fz, s - fz)));

  u64 lst[16];
#pragma unroll
  for (int p = 0; p < 16; ++p) lst[p] = ~0ULL;

  for (int r = 0; r <= GRID; ++r) {
    const int W = 2 * r + 1;
    const int nent = 2 * W * W;
    for (int cb = 0; cb < nent; cb += 32) {
      int ms0 = 0, ms1 = 0;
      const int eid = cb + l;
      if (eid < nent) {
        const int rid = eid >> 1, side = eid & 1;
        const int dz = rid / W - r;
        const int dy = rid % W - r;
        const int z2 = cz + dz, y2 = cy + dy;
        if ((unsigned)z2 < GRID && (unsigned)y2 < GRID) {
          const int rowb = (z2 * GRID + y2) * GRID;
          const bool bdry = (dz == -r) || (dz == r) || (dy == -r) || (dy == r);
          if (bdry) {
            if (side == 0) {
              const int xl = cx - r < 0 ? 0 : cx - r;
              const int xh = cx + r > GRID - 1 ? GRID - 1 : cx + r;
              ms0 = ob[rowb + xl];
              ms1 = ob[rowb + xh + 1];
            }
          } else {
            const int x2 = side ? cx + r : cx - r;
            if ((unsigned)x2 < GRID) {
              ms0 = ob[rowb + x2];
              ms1 = ob[rowb + x2 + 1];
            }
          }
        }
      }
      const int len = ms1 - ms0;  // >= 0
      int pre = len;
#pragma unroll
      for (int d = 1; d < 32; d <<= 1) {
        int u2 = __shfl_up(pre, d);
        if (l >= d) pre += u2;
      }
      const int total = __shfl(pre, tb + 31);
      if (total == 0) continue;
      const int base = ms0 - (pre - len);  // ms0 - exclusive_prefix
      for (int vb = 0; vb < total; vb += 32) {
        const int vidx = vb + l;
        int e = 0;
#pragma unroll
        for (int s2 = 16; s2 >= 1; s2 >>= 1) {
          int pv = __shfl(pre, tb + e + s2 - 1);
          if (pv <= vidx) e += s2;
        }
        const int jb = __shfl(base, tb + e);
        if (vidx < total) {
          const int j = jb + vidx;
          float4 A = sp[j];
          unsigned oi = sx[j];
          INSERTC(A, oi)
        }
      }
    }
    const float rs = fmaf((float)r, s, mn);
    const float T = fmaf(rs, rs, -1e-4f);
    unsigned tu = __float_as_uint(T);
    tu ^= (0x80000000u | (unsigned)((int)tu >> 31));
    int c = 0;
#pragma unroll
    for (int p = 0; p < 16; ++p) c += ((unsigned)(lst[p] >> 32) <= tu) ? 1 : 0;
    c += __shfl_xor(c, 1);
    c += __shfl_xor(c, 2);
    c += __shfl_xor(c, 4);
    c += __shfl_xor(c, 8);
    c += __shfl_xor(c, 16);
    if (c >= 16) break;  // team-uniform break
  }

#pragma unroll
  for (int mm = 1; mm <= 16; mm <<= 1) {
    u64 c[16];
    const bool keepmin = (l & mm) == 0;
#pragma unroll
    for (int p = 0; p < 16; ++p) {
      u64 o = __shfl_xor(lst[15 - p], mm);
      u64 a = lst[p];
      u64 lo = a < o ? a : o;
      u64 hi = a < o ? o : a;
      c[p] = keepmin ? lo : hi;
    }
    CSWAP(0, 8) CSWAP(1, 9) CSWAP(2, 10) CSWAP(3, 11)
    CSWAP(4, 12) CSWAP(5, 13) CSWAP(6, 14) CSWAP(7, 15)
    CSWAP(0, 4) CSWAP(1, 5) CSWAP(2, 6) CSWAP(3, 7)
    CSWAP(8, 12) CSWAP(9, 13) CSWAP(10, 14) CSWAP(11, 15)
    CSWAP(0, 2) CSWAP(1, 3) CSWAP(4, 6) CSWAP(5, 7)
    CSWAP(8, 10) CSWAP(9, 11) CSWAP(12, 14) CSWAP(13, 15)
    CSWAP(0, 1) CSWAP(2, 3) CSWAP(4, 5) CSWAP(6, 7)
    CSWAP(8, 9) CSWAP(10, 11) CSWAP(12, 13) CSWAP(14, 15)
#pragma unroll
    for (int p = 0; p < 16; ++p) lst[p] = c[p];
  }

  if (l == 0) {  // team lane 0 holds the sorted team top-16
    unsigned pk[8];
#pragma unroll
    for (int k = 0; k < 16; k += 2)
      pk[k >> 1] = (unsigned)(lst[k] & 0xFFFFull) |
                   ((unsigned)(lst[k + 1] & 0xFFFFull) << 16);
    unsigned* od = (unsigned*)(oidx + (((size_t)(b << 13) + orig) << 4));
#pragma unroll
    for (int k = 0; k < 8; ++k) od[k] = pk[k];
  }
}

// ---------------------------------------------------------------- K6: lt = feat @ lt_w + lt_b
// R14 layout: row = [varphi f32 x64 | packed bf16 (psi,alp) u32 x64].
__global__ __launch_bounds__(256) void k_lt(const float* __restrict__ feat,
                                            const float* __restrict__ ltw,
                                            const float* __restrict__ ltb,
                                            float* __restrict__ lt) {
  __shared__ float sw[64][196];
  __shared__ float sf[32][68];
  const int tid = threadIdx.x;
  const int r0 = blockIdx.x * 32;
#pragma unroll
  for (int i = 0; i < 12; ++i) {
    int v = tid + i * 256;
    float4 w4 = ((const float4*)ltw)[v];
    int row = (v * 4) / 192, col = (v * 4) % 192;
    *(float4*)&sw[row][col] = w4;
  }
#pragma unroll
  for (int i = 0; i < 2; ++i) {
    int v = tid + i * 256;
    int row = v >> 4, c4 = v & 15;
    float4 f4 = ((const float4*)(feat + (size_t)(r0 + row) * 64))[c4];
    *(float4*)&sf[row][c4 * 4] = f4;
  }
  __syncthreads();
  const int r = tid >> 3;
  const int c0 = (tid & 7) * 8;  // 8 channels, same across 3 sections
  float acc[24];                 // [0..7]=varphi, [8..15]=psi, [16..23]=alp
#pragma unroll
  for (int m = 0; m < 8; ++m) {
    acc[m] = ltb[c0 + m];
    acc[8 + m] = ltb[64 + c0 + m];
    acc[16 + m] = ltb[128 + c0 + m];
  }
#pragma unroll 4
  for (int j = 0; j < 64; ++j) {
    float f = sf[r][j];
#pragma unroll
    for (int sec = 0; sec < 3; ++sec) {
      float4 w4a = *(const float4*)&sw[j][sec * 64 + c0];
      float4 w4b = *(const float4*)&sw[j][sec * 64 + c0 + 4];
      acc[sec * 8 + 0] = fmaf(f, w4a.x, acc[sec * 8 + 0]);
      acc[sec * 8 + 1] = fmaf(f, w4a.y, acc[sec * 8 + 1]);
      acc[sec * 8 + 2] = fmaf(f, w4a.z, acc[sec * 8 + 2]);
      acc[sec * 8 + 3] = fmaf(f, w4a.w, acc[sec * 8 + 3]);
      acc[sec * 8 + 4] = fmaf(f, w4b.x, acc[sec * 8 + 4]);
      acc[sec * 8 + 5] = fmaf(f, w4b.y, acc[sec * 8 + 5]);
      acc[sec * 8 + 6] = fmaf(f, w4b.z, acc[sec * 8 + 6]);
      acc[sec * 8 + 7] = fmaf(f, w4b.w, acc[sec * 8 + 7]);
    }
  }
  float* orow = lt + (size_t)(r0 + r) * 128;
  *(float4*)&orow[c0] = make_float4(acc[0], acc[1], acc[2], acc[3]);
  *(float4*)&orow[c0 + 4] = make_float4(acc[4], acc[5], acc[6], acc[7]);
  u32 pk[8];
#pragma unroll
  for (int m = 0; m < 8; ++m)
    pk[m] = f2bf(acc[8 + m]) | (f2bf(acc[16 + m]) << 16);
  u32* prow = (u32*)orow + 64 + c0;
  *(uint4*)&prow[0] = make_uint4(pk[0], pk[1], pk[2], pk[3]);
  *(uint4*)&prow[4] = make_uint4(pk[4], pk[5], pk[6], pk[7]);
}

// ---------------------------------------------------------------- K7: main
// R15b: second-layer matvec via v_dot2_f32_f16.  h stored in LDS as f16
// (RNE; 8KB), w2 cached as 32 packed-f16 u32 (RNE scalar pack — the
// cvt_pkrtz builtin's __fp16 vector type fought _Float16, and the pack
// is setup-only).  Per k: 8 ds_read_b128 + 32 fdot2 (~96cy issue, was
// ~190).  f32 accumulate; abs err ~1e-3 vs 0.09 threshold.  Packed
// bf16 psi/alp gathers + pf-2 (R13/R14) unchanged.
template <int CTRL>
__device__ __forceinline__ float dpp_add_f(float x) {
  int y = __builtin_amdgcn_update_dpp(0, __float_as_int(x), CTRL, 0xf, 0xf,
                                      true);
  return x + __int_as_float(y);
}
__device__ __forceinline__ float wave_sum64(float x) {
  x = dpp_add_f<0x111>(x);  // row_shr:1
  x = dpp_add_f<0x112>(x);  // row_shr:2
  x = dpp_add_f<0x114>(x);  // row_shr:4
  x = dpp_add_f<0x118>(x);  // row_shr:8
  x = dpp_add_f<0x142>(x);  // row_bcast:15
  x = dpp_add_f<0x143>(x);  // row_bcast:31
  return __int_as_float(__builtin_amdgcn_readlane(__float_as_int(x), 63));
}

__global__ __launch_bounds__(256) void k_main(
    const float4* __restrict__ xytp, const float* __restrict__ lt,
    const u16* __restrict__ knn, const float* __restrict__ pe_w1,
    const float* __restrict__ pe_b1, const float* __restrict__ pe_w2,
    const float* __restrict__ pe_b2, const float* __restrict__ ln_g,
    const float* __restrict__ ln_b, float* __restrict__ out) {
  __shared__ u16 s_h[4][16][64];  // f16 bits; [wave][k][channel]
  const int lane = threadIdx.x & 63;
  const int wave = threadIdx.x >> 6;
  const int pid = __builtin_amdgcn_readfirstlane(blockIdx.x * 4 + wave);
  const int b = pid >> 13;
  const int n = pid & 8191;

  float w1c[4];
#pragma unroll
  for (int d = 0; d < 4; ++d) w1c[d] = pe_w1[d * 64 + lane];
  const float b1c = pe_b1[lane];
  // w2 packed: word m = (w2[2m][lane], w2[2m+1][lane]) as f16 pair
  u32 w2pk[32];
#pragma unroll
  for (int m2 = 0; m2 < 32; ++m2) {
    float a = pe_w2[(2 * m2) * 64 + lane];
    float bb = pe_w2[(2 * m2 + 1) * 64 + lane];
    w2pk[m2] = pkf16(a, bb);
  }
  const float b2c = pe_b2[lane];
  const float gc = ln_g[lane], bc = ln_b[lane];

  int nb[16];
#pragma unroll
  for (int k = 0; k < 16; ++k) nb[k] = knn[pid * 16 + k];

  const float* __restrict__ ltb = lt + (size_t)(b << 13) * 128;
  const float vc = ltb[(size_t)n * 128 + lane];

  const float4 qv = xytp[(b << 13) + n];
#pragma unroll
  for (int k = 0; k < 16; ++k) {
    float4 g = xytp[(b << 13) + nb[k]];
    float r0 = qv.x - g.x, r1 = qv.y - g.y, r2 = qv.z - g.z, r3 = qv.w - g.w;
    float h = fmaf(r3, w1c[3],
                   fmaf(r2, w1c[2], fmaf(r1, w1c[1], fmaf(r0, w1c[0], b1c))));
    s_h[wave][k][lane] = f16b(fmaxf(h, 0.0f));
  }
  __syncthreads();

  // prefetch distance 2: packed psi/alp u32, static A/B slot rotation
  u32 uA = ((const u32*)(ltb + (size_t)nb[0] * 128 + 64))[lane];
  u32 uB = ((const u32*)(ltb + (size_t)nb[1] * 128 + 64))[lane];
  float m = -INFINITY, se = 0.f, oacc = 0.f;
#pragma unroll
  for (int k = 0; k < 16; ++k) {
    const u32 uc = (k & 1) ? uB : uA;
    if (k < 14) {  // refill the slot just consumed with row k+2
      const u32* prow = (const u32*)(ltb + (size_t)nb[k + 2] * 128 + 64);
      if (k & 1) uB = prow[lane];
      else       uA = prow[lane];
    }
    const float psi_c = __uint_as_float(uc << 16);
    const float alp_c = __uint_as_float(uc & 0xFFFF0000u);
    float acc = b2c;
    const uint4* hp = (const uint4*)&s_h[wave][k][0];  // broadcast reads
#pragma unroll
    for (int j4 = 0; j4 < 8; ++j4) {
      uint4 hv = hp[j4];
      acc = fdot2u(hv.x, w2pk[j4 * 4 + 0], acc);
      acc = fdot2u(hv.y, w2pk[j4 * 4 + 1], acc);
      acc = fdot2u(hv.z, w2pk[j4 * 4 + 2], acc);
      acc = fdot2u(hv.w, w2pk[j4 * 4 + 3], acc);
    }
    const float pre = (vc - psi_c) + acc;
    const float apd = alp_c + acc;
    const float sm = wave_sum64(pre);
    const float ssm = wave_sum64(pre * pre);
    const float mu = sm * 0.015625f;
    const float var = fmaf(ssm, 0.015625f, -mu * mu);
    const float inv = rsqrtf(var + 1e-5f);
    const float x = fmaf((pre - mu) * inv, gc, bc) * 0.125f;
    const float mn = fmaxf(m, x);
    const float corr = __expf(m - mn);
    const float e = __expf(x - mn);
    se = fmaf(se, corr, e);
    oacc = fmaf(oacc, corr, e * apd);
    m = mn;
  }
  out[(size_t)pid * 64 + lane] = oacc / se;
}

// ---------------------------------------------------------------- launch
extern "C" void kernel_launch(void* const* d_in, const int* in_sizes, int n_in,
                              void* d_out, int out_size, void* d_ws,
                              size_t ws_size, hipStream_t stream) {
  const float4* xytp = (const float4*)d_in[0];
  const float* features = (const float*)d_in[1];
  const float* pe_w1 = (const float*)d_in[2];
  const float* pe_b1 = (const float*)d_in[3];
  const float* pe_w2 = (const float*)d_in[4];
  const float* pe_b2 = (const float*)d_in[5];
  const float* lt_w = (const float*)d_in[6];
  const float* lt_b = (const float*)d_in[7];
  const float* ln_g = (const float*)d_in[8];
  const float* ln_b = (const float*)d_in[9];
  float* out = (float*)d_out;

  char* ws = (char*)d_ws;
  u16* idxbuf = (u16*)(ws + WS_IDX);
  float* lt = (float*)(ws + WS_LT);
  int* cnt = (int*)(ws + WS_CNT);
  int* offs = (int*)(ws + WS_OFF);
  int* curs = (int*)(ws + WS_CUR);
  float4* spts = (float4*)(ws + WS_SP);
  float* gp = (float*)(ws + WS_GP);
  u16* sidx = (u16*)(ws + WS_SIDX);
  u16* ordb = (u16*)(ws + WS_CNT);  // cnt is dead after k_scan

  k_bbox1<<<128, 256, 0, stream>>>(xytp, (float*)(ws + WS_CUR), cnt);
  k_bbox2<<<BATCH, 64, 0, stream>>>((const float*)(ws + WS_CUR), gp);
  k_count<<<(BATCH * NPTS) / 256, 256, 0, stream>>>(xytp, gp, cnt);
  k_scan<<<BATCH, 1024, 0, stream>>>(cnt, offs, curs);
  k_scatter<<<(BATCH * NPTS) / 256, 256, 0, stream>>>(xytp, gp, curs, spts,
                                                      sidx);
  k_order<<<BATCH, 1024, 0, stream>>>(spts, offs, gp, ordb);
  k_query<<<(BATCH * NPTS) / 8, 256, 0, stream>>>(spts, sidx, offs, gp, ordb,
                                                  idxbuf);
  k_lt<<<(BATCH * NPTS) / 32, 256, 0, stream>>>(features, lt_w, lt_b, lt);
  k_main<<<(BATCH * NPTS) / 4, 256, 0, stream>>>(xytp, lt, idxbuf, pe_w1,
                                                 pe_b1, pe_w2, pe_b2, ln_g,
                                                 ln_b, out);
}

// Round 17
// 336.050 us; speedup vs baseline: 1.4045x; 1.0446x over previous
//
#include <hip/hip_runtime.h>
#include <stdint.h>

#define BATCH 4
#define NPTS 8192
#define KNN_K 16
#define GRID 24
#define NCELL (GRID * GRID * GRID)  // 13824
#define NCELLP (NCELL + 8)          // offs stride (sentinel slot)

typedef unsigned long long u64;
typedef unsigned int u32;
typedef unsigned short u16;

// ws layout (bytes)
#define WS_IDX 0u          // u16[4*8192*16]            = 1,048,576
#define WS_LT 1048576u     // row=[varphi f32 x64 | packed bf16 (psi,alp) u32 x64] = 512B/pt
#define WS_CNT 26214400u   // int[4*13824]              = 221,184  (dead after k_scan -> ord u16[4*8192])
#define WS_OFF 26435584u   // int[4*13832]              = 221,312
#define WS_CUR 26656896u   // int[4*13824]              = 221,184  (also bbox partials before k_scan)
#define WS_SP 26878080u    // float4[4*8192]            = 524,288
#define WS_GP 27402368u    // float[4*8]                = 128
#define WS_SIDX 27402496u  // u16[4*8192]               = 65,536

#define NQBLK ((BATCH * NPTS) / 8)  // 4096 query blocks
#define NLBLK ((BATCH * NPTS) / 32) // 1024 lt blocks

__device__ __forceinline__ int cellof(float v, float o, float invs) {
  int c = (int)((v - o) * invs);
  return c < GRID - 1 ? c : GRID - 1;
}

__device__ __forceinline__ u32 f2bf(float v) {  // RNE bf16 (high 16 bits)
  u32 x = __float_as_uint(v);
  return (x + 0x7FFFu + ((x >> 16) & 1u)) >> 16;
}

typedef _Float16 hv2 __attribute__((ext_vector_type(2)));
union U32H2 { u32 u; hv2 h; };
__device__ __forceinline__ float fdot2u(u32 a, u32 b, float c) {
  U32H2 x, y; x.u = a; y.u = b;
  return __builtin_amdgcn_fdot2(x.h, y.h, c, false);
}
__device__ __forceinline__ u16 f16b(float v) {  // RNE scalar f16 bits
  union { _Float16 f; u16 b; } c; c.f = (_Float16)v; return c.b;
}
__device__ __forceinline__ u32 pkf16(float a, float b) {  // RNE pack
  return (u32)f16b(a) | ((u32)f16b(b) << 16);
}

// ---------------------------------------------------------------- K0a: partial bbox (128 blocks) + zero counters
__global__ __launch_bounds__(256) void k_bbox1(const float4* __restrict__ xytp,
                                               float* __restrict__ part,
                                               int* __restrict__ cnt) {
  const int blk = blockIdx.x;  // 0..127
  const int b = blk >> 5, sub = blk & 31;
  const int t = threadIdx.x;
#pragma unroll
  for (int i = 0; i < 2; ++i) {
    int v = t + i * 256;
    if (v < 432) cnt[blk * 432 + v] = 0;
  }
  float4 p = xytp[(b << 13) + (sub << 8) + t];
  float mnx = p.x, mny = p.y, mnz = p.z;
  float mxx = p.x, mxy = p.y, mxz = p.z;
#pragma unroll
  for (int d = 1; d < 64; d <<= 1) {
    mnx = fminf(mnx, __shfl_xor(mnx, d)); mny = fminf(mny, __shfl_xor(mny, d));
    mnz = fminf(mnz, __shfl_xor(mnz, d)); mxx = fmaxf(mxx, __shfl_xor(mxx, d));
    mxy = fmaxf(mxy, __shfl_xor(mxy, d)); mxz = fmaxf(mxz, __shfl_xor(mxz, d));
  }
  __shared__ float red[4][6];
  const int lane = t & 63, wv = t >> 6;
  if (lane == 0) {
    red[wv][0] = mnx; red[wv][1] = mny; red[wv][2] = mnz;
    red[wv][3] = mxx; red[wv][4] = mxy; red[wv][5] = mxz;
  }
  __syncthreads();
  if (t == 0) {
    for (int w = 1; w < 4; ++w) {
      red[0][0] = fminf(red[0][0], red[w][0]);
      red[0][1] = fminf(red[0][1], red[w][1]);
      red[0][2] = fminf(red[0][2], red[w][2]);
      red[0][3] = fmaxf(red[0][3], red[w][3]);
      red[0][4] = fmaxf(red[0][4], red[w][4]);
      red[0][5] = fmaxf(red[0][5], red[w][5]);
    }
    float* o = part + blk * 8;
    o[0] = red[0][0]; o[1] = red[0][1]; o[2] = red[0][2];
    o[3] = red[0][3]; o[4] = red[0][4]; o[5] = red[0][5];
  }
}

// ---------------------------------------------------------------- K0b: final bbox reduce (4 blocks x 64 thr)
__global__ __launch_bounds__(64) void k_bbox2(const float* __restrict__ part,
                                              float* __restrict__ gp) {
  const int b = blockIdx.x, t = threadIdx.x;
  const float* pp = part + (b * 32 + (t & 31)) * 8;  // lanes 32..63 duplicate
  float mnx = pp[0], mny = pp[1], mnz = pp[2];
  float mxx = pp[3], mxy = pp[4], mxz = pp[5];
#pragma unroll
  for (int d = 1; d < 64; d <<= 1) {
    mnx = fminf(mnx, __shfl_xor(mnx, d)); mny = fminf(mny, __shfl_xor(mny, d));
    mnz = fminf(mnz, __shfl_xor(mnz, d)); mxx = fmaxf(mxx, __shfl_xor(mxx, d));
    mxy = fmaxf(mxy, __shfl_xor(mxy, d)); mxz = fmaxf(mxz, __shfl_xor(mxz, d));
  }
  if (t == 0) {
    float rmax = fmaxf(mxx - mnx, fmaxf(mxy - mny, mxz - mnz));
    float s = rmax / (float)GRID;
    float* g = gp + b * 8;
    g[0] = mnx; g[1] = mny; g[2] = mnz;
    g[3] = s; g[4] = 1.0f / s;
  }
}

// ---------------------------------------------------------------- K2: count
__global__ __launch_bounds__(256) void k_count(const float4* __restrict__ xytp,
                                               const float* __restrict__ gp,
                                               int* __restrict__ cnt) {
  int i = blockIdx.x * 256 + threadIdx.x;
  int b = i >> 13;
  const float* g = gp + b * 8;
  float4 p = xytp[i];
  int cx = cellof(p.x, g[0], g[4]);
  int cy = cellof(p.y, g[1], g[4]);
  int cz = cellof(p.z, g[2], g[4]);
  atomicAdd(&cnt[b * NCELL + (cz * GRID + cy) * GRID + cx], 1);
}

// ---------------------------------------------------------------- K3: exclusive scan
__global__ __launch_bounds__(1024) void k_scan(const int* __restrict__ cnt,
                                               int* __restrict__ offs,
                                               int* __restrict__ curs) {
  __shared__ int wsum[16];
  const int b = blockIdx.x, t = threadIdx.x;
  const int base = b * NCELL;
  const int base2 = b * NCELLP;
  const int lo = t * 14;
  const int hi = lo + 14 < NCELL ? lo + 14 : NCELL;
  int s = 0;
  for (int c = lo; c < hi; ++c) s += cnt[base + c];
  const int lane = t & 63, wv = t >> 6;
  int v = s;
#pragma unroll
  for (int d = 1; d < 64; d <<= 1) {
    int u = __shfl_up(v, d);
    if (lane >= d) v += u;
  }
  if (lane == 63) wsum[wv] = v;
  __syncthreads();
  if (wv == 0 && lane < 16) {
    int x = wsum[lane];
#pragma unroll
    for (int d = 1; d < 16; d <<= 1) {
      int u = __shfl_up(x, d, 16);
      if (lane >= d) x += u;
    }
    wsum[lane] = x;
  }
  __syncthreads();
  int excl = (wv > 0 ? wsum[wv - 1] : 0) + v - s;
  for (int c = lo; c < hi; ++c) {
    offs[base2 + c] = excl;
    curs[base + c] = excl;
    excl += cnt[base + c];
  }
  if (hi == NCELL) offs[base2 + NCELL] = excl;  // == NPTS
}

// ---------------------------------------------------------------- K4: scatter (cell-sorted points, sq in .w, idx in sidx)
__global__ __launch_bounds__(256) void k_scatter(const float4* __restrict__ xytp,
                                                 const float* __restrict__ gp,
                                                 int* __restrict__ curs,
                                                 float4* __restrict__ spts,
                                                 u16* __restrict__ sidx) {
  int i = blockIdx.x * 256 + threadIdx.x;
  int b = i >> 13, n = i & 8191;
  const float* g = gp + b * 8;
  float4 p = xytp[i];
  int cx = cellof(p.x, g[0], g[4]);
  int cy = cellof(p.y, g[1], g[4]);
  int cz = cellof(p.z, g[2], g[4]);
  int pos = atomicAdd(&curs[b * NCELL + (cz * GRID + cy) * GRID + cx], 1);
  float sq = fmaf(p.z, p.z, fmaf(p.y, p.y, p.x * p.x));
  spts[(b << 13) + pos] = make_float4(p.x, p.y, p.z, sq);
  sidx[(b << 13) + pos] = (u16)n;
}

// ---------------------------------------------------------------- K4b: LPT query ordering (R22)
__global__ __launch_bounds__(1024) void k_order(const float4* __restrict__ spts,
                                                const int* __restrict__ offs,
                                                const float* __restrict__ gp,
                                                u16* __restrict__ ord) {
  __shared__ int hist[32];
  __shared__ int strt[32];
  const int b = blockIdx.x, t = threadIdx.x;
  if (t < 32) hist[t] = 0;
  __syncthreads();
  const float* g = gp + b * 8;
  const int* ob = offs + b * NCELLP;
  const float4* sp = spts + (b << 13);
  int key[8];
#pragma unroll
  for (int it = 0; it < 8; ++it) {
    const int i = t + it * 1024;
    float4 p = sp[i];
    int cx = cellof(p.x, g[0], g[4]);
    int cy = cellof(p.y, g[1], g[4]);
    int cz = cellof(p.z, g[2], g[4]);
    int c = (cz * GRID + cy) * GRID + cx;
    int cc = ob[c + 1] - ob[c];  // >= 1 (query itself)
    key[it] = cc - 1 < 31 ? cc - 1 : 31;
    atomicAdd(&hist[key[it]], 1);
  }
  __syncthreads();
  if (t == 0) {
    int acc = 0;
    for (int k2 = 0; k2 < 32; ++k2) { strt[k2] = acc; acc += hist[k2]; }
  }
  __syncthreads();
  u16* ob2 = ord + (b << 13);
#pragma unroll
  for (int it = 0; it < 8; ++it) {
    const int i = t + it * 1024;
    int pos = atomicAdd(&strt[key[it]], 1);
    ob2[pos] = (u16)i;
  }
}

// ---------------------------------------------------------------- K5: FUSED grid-KNN query + lt GEMM (R17)
// Blocks [0, NQBLK): R22 query structure (32-wide teams, uniform-trip
// concat dealing, mn-tightened count-stop, LPT) — unchanged.
// Blocks [NQBLK, NQBLK+NLBLK): k_lt work (feat @ lt_w + lt_b), which
// has NO dependency on the grid pipeline, dispatched LAST so it
// backfills CUs as query blocks drain (single-stream overlap).
// LDS re-chunked to 14.8KB (4 passes of 16 feature dims) so the
// static allocation doesn't cap query occupancy (9 blocks/CU VGPR-
// limited x 14.8KB = 133KB < 160KB).
#define INSERTC(Af, OI)                                                      \
  {                                                                          \
    float dot = q.x * (Af).x;                                                \
    dot = fmaf(q.y, (Af).y, dot);                                            \
    dot = fmaf(q.z, (Af).z, dot);                                            \
    float d2 = (qsq + (Af).w) - 2.0f * dot;                                  \
    unsigned u = __float_as_uint(d2);                                        \
    u ^= (0x80000000u | (unsigned)((int)u >> 31));                           \
    u64 key = ((u64)u << 32) | (OI);                                         \
    if (key < lst[15]) {                                                     \
      u64 x = key;                                                           \
      _Pragma("unroll") for (int p = 0; p < 16; ++p) {                       \
        bool sw = x < lst[p];                                                \
        u64 a = lst[p];                                                      \
        lst[p] = sw ? x : a;                                                 \
        x = sw ? a : x;                                                      \
      }                                                                      \
    }                                                                        \
  }

#define CSWAP(ia, ib)                                                        \
  {                                                                          \
    u64 ta = c[ia], tb2 = c[ib];                                             \
    bool sw = ta > tb2;                                                      \
    c[ia] = sw ? tb2 : ta;                                                   \
    c[ib] = sw ? ta : tb2;                                                   \
  }

__global__ __launch_bounds__(256) void k_query(
    const float4* __restrict__ spts, const u16* __restrict__ sidx,
    const int* __restrict__ offs, const float* __restrict__ gp,
    const u16* __restrict__ ord, u16* __restrict__ oidx,
    const float* __restrict__ feat, const float* __restrict__ ltw,
    const float* __restrict__ ltb, float* __restrict__ lt) {
  __shared__ float sw_c[16][196];  // lt path only (14.8KB total)
  __shared__ float sf_c[32][18];
  const int tid = threadIdx.x;

  if (blockIdx.x >= NQBLK) {
    // ---------------- lt path: 32 points per block, 4 j-chunks ----------
    const int r0 = (blockIdx.x - NQBLK) * 32;
    const int r = tid >> 3;
    const int c0 = (tid & 7) * 8;  // 8 channels, same across 3 sections
    float acc[24];                 // [0..7]=varphi, [8..15]=psi, [16..23]=alp
#pragma unroll
    for (int m = 0; m < 8; ++m) {
      acc[m] = ltb[c0 + m];
      acc[8 + m] = ltb[64 + c0 + m];
      acc[16 + m] = ltb[128 + c0 + m];
    }
    for (int ch = 0; ch < 4; ++ch) {
      // load weight chunk: rows [16ch,16ch+16) x 192 = 768 float4s
#pragma unroll
      for (int i = 0; i < 3; ++i) {
        int f = tid + i * 256;
        int row = f / 48, col4 = f % 48;
        float4 w4 = ((const float4*)ltw)[(ch * 16 + row) * 48 + col4];
        *(float4*)&sw_c[row][col4 * 4] = w4;
      }
      // load feat chunk: 32 rows x 16 = 512 floats, 2 per thread
      {
        int v = tid * 2;
        int row = v >> 4, jj = v & 15;
        const float2 f2 =
            *(const float2*)(feat + (size_t)(r0 + row) * 64 + ch * 16 + jj);
        sf_c[row][jj] = f2.x;
        sf_c[row][jj + 1] = f2.y;
      }
      __syncthreads();
#pragma unroll 4
      for (int jj = 0; jj < 16; ++jj) {
        float f = sf_c[r][jj];
#pragma unroll
        for (int sec = 0; sec < 3; ++sec) {
          float4 w4a = *(const float4*)&sw_c[jj][sec * 64 + c0];
          float4 w4b = *(const float4*)&sw_c[jj][sec * 64 + c0 + 4];
          acc[sec * 8 + 0] = fmaf(f, w4a.x, acc[sec * 8 + 0]);
          acc[sec * 8 + 1] = fmaf(f, w4a.y, acc[sec * 8 + 1]);
          acc[sec * 8 + 2] = fmaf(f, w4a.z, acc[sec * 8 + 2]);
          acc[sec * 8 + 3] = fmaf(f, w4a.w, acc[sec * 8 + 3]);
          acc[sec * 8 + 4] = fmaf(f, w4b.x, acc[sec * 8 + 4]);
          acc[sec * 8 + 5] = fmaf(f, w4b.y, acc[sec * 8 + 5]);
          acc[sec * 8 + 6] = fmaf(f, w4b.z, acc[sec * 8 + 6]);
          acc[sec * 8 + 7] = fmaf(f, w4b.w, acc[sec * 8 + 7]);
        }
      }
      __syncthreads();
    }
    float* orow = lt + (size_t)(r0 + r) * 128;
    *(float4*)&orow[c0] = make_float4(acc[0], acc[1], acc[2], acc[3]);
    *(float4*)&orow[c0 + 4] = make_float4(acc[4], acc[5], acc[6], acc[7]);
    u32 pk[8];
#pragma unroll
    for (int m = 0; m < 8; ++m)
      pk[m] = f2bf(acc[8 + m]) | (f2bf(acc[16 + m]) << 16);
    u32* prow = (u32*)orow + 64 + c0;
    *(uint4*)&prow[0] = make_uint4(pk[0], pk[1], pk[2], pk[3]);
    *(uint4*)&prow[4] = make_uint4(pk[4], pk[5], pk[6], pk[7]);
    return;
  }

  // ---------------- query path (R22, unchanged) ----------------
  const int lane = tid & 63;
  const int l = tid & 31;        // team lane
  const int qid = blockIdx.x * 8 + (tid >> 5);  // 8 teams/block
  const int b = qid >> 13;
  const int i = ord[(b << 13) + (qid & 8191)];  // LPT permutation
  const int tb = lane & 32;      // team base within wave (0 or 32)
  const float4* __restrict__ sp = spts + (b << 13);
  const u16* __restrict__ sx = sidx + (b << 13);
  const int* __restrict__ ob = offs + b * NCELLP;
  const float* g = gp + b * 8;
  float4 q = sp[i];
  const float qsq = q.w;  // sq precomputed
  const unsigned orig = sx[i];
  const int cx = cellof(q.x, g[0], g[4]);
  const int cy = cellof(q.y, g[1], g[4]);
  const int cz = cellof(q.z, g[2], g[4]);
  const float s = g[3];
  const float fx = q.x - fmaf((float)cx, s, g[0]);
  const float fy = q.y - fmaf((float)cy, s, g[1]);
  const float fz = q.z - fmaf((float)cz, s, g[2]);
  const float mn = fmaxf(
      0.0f, fminf(fminf(fminf(fx, s - fx), fminf(fy, s - fy)),
                  fminf(fz, s - fz)));

  u64 lst[16];
#pragma unroll
  for (int p = 0; p < 16; ++p) lst[p] = ~0ULL;

  for (int r = 0; r <= GRID; ++r) {
    const int W = 2 * r + 1;
    const int nent = 2 * W * W;
    for (int cb = 0; cb < nent; cb += 32) {
      int ms0 = 0, ms1 = 0;
      const int eid = cb + l;
      if (eid < nent) {
        const int rid = eid >> 1, side = eid & 1;
        const int dz = rid / W - r;
        const int dy = rid % W - r;
        const int z2 = cz + dz, y2 = cy + dy;
        if ((unsigned)z2 < GRID && (unsigned)y2 < GRID) {
          const int rowb = (z2 * GRID + y2) * GRID;
          const bool bdry = (dz == -r) || (dz == r) || (dy == -r) || (dy == r);
          if (bdry) {
            if (side == 0) {
              const int xl = cx - r < 0 ? 0 : cx - r;
              const int xh = cx + r > GRID - 1 ? GRID - 1 : cx + r;
              ms0 = ob[rowb + xl];
              ms1 = ob[rowb + xh + 1];
            }
          } else {
            const int x2 = side ? cx + r : cx - r;
            if ((unsigned)x2 < GRID) {
              ms0 = ob[rowb + x2];
              ms1 = ob[rowb + x2 + 1];
            }
          }
        }
      }
      const int len = ms1 - ms0;  // >= 0
      int pre = len;
#pragma unroll
      for (int d = 1; d < 32; d <<= 1) {
        int u2 = __shfl_up(pre, d);
        if (l >= d) pre += u2;
      }
      const int total = __shfl(pre, tb + 31);
      if (total == 0) continue;
      const int base = ms0 - (pre - len);  // ms0 - exclusive_prefix
      for (int vb = 0; vb < total; vb += 32) {
        const int vidx = vb + l;
        int e = 0;
#pragma unroll
        for (int s2 = 16; s2 >= 1; s2 >>= 1) {
          int pv = __shfl(pre, tb + e + s2 - 1);
          if (pv <= vidx) e += s2;
        }
        const int jb = __shfl(base, tb + e);
        if (vidx < total) {
          const int j = jb + vidx;
          float4 A = sp[j];
          unsigned oi = sx[j];
          INSERTC(A, oi)
        }
      }
    }
    const float rs = fmaf((float)r, s, mn);
    const float T = fmaf(rs, rs, -1e-4f);
    unsigned tu = __float_as_uint(T);
    tu ^= (0x80000000u | (unsigned)((int)tu >> 31));
    int c = 0;
#pragma unroll
    for (int p = 0; p < 16; ++p) c += ((unsigned)(lst[p] >> 32) <= tu) ? 1 : 0;
    c += __shfl_xor(c, 1);
    c += __shfl_xor(c, 2);
    c += __shfl_xor(c, 4);
    c += __shfl_xor(c, 8);
    c += __shfl_xor(c, 16);
    if (c >= 16) break;  // team-uniform break
  }

#pragma unroll
  for (int mm = 1; mm <= 16; mm <<= 1) {
    u64 c[16];
    const bool keepmin = (l & mm) == 0;
#pragma unroll
    for (int p = 0; p < 16; ++p) {
      u64 o = __shfl_xor(lst[15 - p], mm);
      u64 a = lst[p];
      u64 lo = a < o ? a : o;
      u64 hi = a < o ? o : a;
      c[p] = keepmin ? lo : hi;
    }
    CSWAP(0, 8) CSWAP(1, 9) CSWAP(2, 10) CSWAP(3, 11)
    CSWAP(4, 12) CSWAP(5, 13) CSWAP(6, 14) CSWAP(7, 15)
    CSWAP(0, 4) CSWAP(1, 5) CSWAP(2, 6) CSWAP(3, 7)
    CSWAP(8, 12) CSWAP(9, 13) CSWAP(10, 14) CSWAP(11, 15)
    CSWAP(0, 2) CSWAP(1, 3) CSWAP(4, 6) CSWAP(5, 7)
    CSWAP(8, 10) CSWAP(9, 11) CSWAP(12, 14) CSWAP(13, 15)
    CSWAP(0, 1) CSWAP(2, 3) CSWAP(4, 5) CSWAP(6, 7)
    CSWAP(8, 9) CSWAP(10, 11) CSWAP(12, 13) CSWAP(14, 15)
#pragma unroll
    for (int p = 0; p < 16; ++p) lst[p] = c[p];
  }

  if (l == 0) {  // team lane 0 holds the sorted team top-16
    unsigned pk[8];
#pragma unroll
    for (int k = 0; k < 16; k += 2)
      pk[k >> 1] = (unsigned)(lst[k] & 0xFFFFull) |
                   ((unsigned)(lst[k + 1] & 0xFFFFull) << 16);
    unsigned* od = (unsigned*)(oidx + (((size_t)(b << 13) + orig) << 4));
#pragma unroll
    for (int k = 0; k < 8; ++k) od[k] = pk[k];
  }
}

// ---------------------------------------------------------------- K7: main
// R15b: second-layer matvec via v_dot2_f32_f16 (h in LDS as f16, w2 as
// packed-f16 u32).  Packed bf16 psi/alp gathers + pf-2 unchanged.
template <int CTRL>
__device__ __forceinline__ float dpp_add_f(float x) {
  int y = __builtin_amdgcn_update_dpp(0, __float_as_int(x), CTRL, 0xf, 0xf,
                                      true);
  return x + __int_as_float(y);
}
__device__ __forceinline__ float wave_sum64(float x) {
  x = dpp_add_f<0x111>(x);  // row_shr:1
  x = dpp_add_f<0x112>(x);  // row_shr:2
  x = dpp_add_f<0x114>(x);  // row_shr:4
  x = dpp_add_f<0x118>(x);  // row_shr:8
  x = dpp_add_f<0x142>(x);  // row_bcast:15
  x = dpp_add_f<0x143>(x);  // row_bcast:31
  return __int_as_float(__builtin_amdgcn_readlane(__float_as_int(x), 63));
}

__global__ __launch_bounds__(256) void k_main(
    const float4* __restrict__ xytp, const float* __restrict__ lt,
    const u16* __restrict__ knn, const float* __restrict__ pe_w1,
    const float* __restrict__ pe_b1, const float* __restrict__ pe_w2,
    const float* __restrict__ pe_b2, const float* __restrict__ ln_g,
    const float* __restrict__ ln_b, float* __restrict__ out) {
  __shared__ u16 s_h[4][16][64];  // f16 bits; [wave][k][channel]
  const int lane = threadIdx.x & 63;
  const int wave = threadIdx.x >> 6;
  const int pid = __builtin_amdgcn_readfirstlane(blockIdx.x * 4 + wave);
  const int b = pid >> 13;
  const int n = pid & 8191;

  float w1c[4];
#pragma unroll
  for (int d = 0; d < 4; ++d) w1c[d] = pe_w1[d * 64 + lane];
  const float b1c = pe_b1[lane];
  // w2 packed: word m = (w2[2m][lane], w2[2m+1][lane]) as f16 pair
  u32 w2pk[32];
#pragma unroll
  for (int m2 = 0; m2 < 32; ++m2) {
    float a = pe_w2[(2 * m2) * 64 + lane];
    float bb = pe_w2[(2 * m2 + 1) * 64 + lane];
    w2pk[m2] = pkf16(a, bb);
  }
  const float b2c = pe_b2[lane];
  const float gc = ln_g[lane], bc = ln_b[lane];

  int nb[16];
#pragma unroll
  for (int k = 0; k < 16; ++k) nb[k] = knn[pid * 16 + k];

  const float* __restrict__ ltb = lt + (size_t)(b << 13) * 128;
  const float vc = ltb[(size_t)n * 128 + lane];

  const float4 qv = xytp[(b << 13) + n];
#pragma unroll
  for (int k = 0; k < 16; ++k) {
    float4 g = xytp[(b << 13) + nb[k]];
    float r0 = qv.x - g.x, r1 = qv.y - g.y, r2 = qv.z - g.z, r3 = qv.w - g.w;
    float h = fmaf(r3, w1c[3],
                   fmaf(r2, w1c[2], fmaf(r1, w1c[1], fmaf(r0, w1c[0], b1c))));
    s_h[wave][k][lane] = f16b(fmaxf(h, 0.0f));
  }
  __syncthreads();

  // prefetch distance 2: packed psi/alp u32, static A/B slot rotation
  u32 uA = ((const u32*)(ltb + (size_t)nb[0] * 128 + 64))[lane];
  u32 uB = ((const u32*)(ltb + (size_t)nb[1] * 128 + 64))[lane];
  float m = -INFINITY, se = 0.f, oacc = 0.f;
#pragma unroll
  for (int k = 0; k < 16; ++k) {
    const u32 uc = (k & 1) ? uB : uA;
    if (k < 14) {  // refill the slot just consumed with row k+2
      const u32* prow = (const u32*)(ltb + (size_t)nb[k + 2] * 128 + 64);
      if (k & 1) uB = prow[lane];
      else       uA = prow[lane];
    }
    const float psi_c = __uint_as_float(uc << 16);
    const float alp_c = __uint_as_float(uc & 0xFFFF0000u);
    float acc = b2c;
    const uint4* hp = (const uint4*)&s_h[wave][k][0];  // broadcast reads
#pragma unroll
    for (int j4 = 0; j4 < 8; ++j4) {
      uint4 hv = hp[j4];
      acc = fdot2u(hv.x, w2pk[j4 * 4 + 0], acc);
      acc = fdot2u(hv.y, w2pk[j4 * 4 + 1], acc);
      acc = fdot2u(hv.z, w2pk[j4 * 4 + 2], acc);
      acc = fdot2u(hv.w, w2pk[j4 * 4 + 3], acc);
    }
    const float pre = (vc - psi_c) + acc;
    const float apd = alp_c + acc;
    const float sm = wave_sum64(pre);
    const float ssm = wave_sum64(pre * pre);
    const float mu = sm * 0.015625f;
    const float var = fmaf(ssm, 0.015625f, -mu * mu);
    const float inv = rsqrtf(var + 1e-5f);
    const float x = fmaf((pre - mu) * inv, gc, bc) * 0.125f;
    const float mn = fmaxf(m, x);
    const float corr = __expf(m - mn);
    const float e = __expf(x - mn);
    se = fmaf(se, corr, e);
    oacc = fmaf(oacc, corr, e * apd);
    m = mn;
  }
  out[(size_t)pid * 64 + lane] = oacc / se;
}

// ---------------------------------------------------------------- launch
extern "C" void kernel_launch(void* const* d_in, const int* in_sizes, int n_in,
                              void* d_out, int out_size, void* d_ws,
                              size_t ws_size, hipStream_t stream) {
  const float4* xytp = (const float4*)d_in[0];
  const float* features = (const float*)d_in[1];
  const float* pe_w1 = (const float*)d_in[2];
  const float* pe_b1 = (const float*)d_in[3];
  const float* pe_w2 = (const float*)d_in[4];
  const float* pe_b2 = (const float*)d_in[5];
  const float* lt_w = (const float*)d_in[6];
  const float* lt_b = (const float*)d_in[7];
  const float* ln_g = (const float*)d_in[8];
  const float* ln_b = (const float*)d_in[9];
  float* out = (float*)d_out;

  char* ws = (char*)d_ws;
  u16* idxbuf = (u16*)(ws + WS_IDX);
  float* lt = (float*)(ws + WS_LT);
  int* cnt = (int*)(ws + WS_CNT);
  int* offs = (int*)(ws + WS_OFF);
  int* curs = (int*)(ws + WS_CUR);
  float4* spts = (float4*)(ws + WS_SP);
  float* gp = (float*)(ws + WS_GP);
  u16* sidx = (u16*)(ws + WS_SIDX);
  u16* ordb = (u16*)(ws + WS_CNT);  // cnt is dead after k_scan

  k_bbox1<<<128, 256, 0, stream>>>(xytp, (float*)(ws + WS_CUR), cnt);
  k_bbox2<<<BATCH, 64, 0, stream>>>((const float*)(ws + WS_CUR), gp);
  k_count<<<(BATCH * NPTS) / 256, 256, 0, stream>>>(xytp, gp, cnt);
  k_scan<<<BATCH, 1024, 0, stream>>>(cnt, offs, curs);
  k_scatter<<<(BATCH * NPTS) / 256, 256, 0, stream>>>(xytp, gp, curs, spts,
                                                      sidx);
  k_order<<<BATCH, 1024, 0, stream>>>(spts, offs, gp, ordb);
  k_query<<<NQBLK + NLBLK, 256, 0, stream>>>(spts, sidx, offs, gp, ordb,
                                             idxbuf, features, lt_w, lt_b,
                                             lt);
  k_main<<<(BATCH * NPTS) / 4, 256, 0, stream>>>(xytp, lt, idxbuf, pe_w1,
                                                 pe_b1, pe_w2, pe_b2, ln_g,
                                                 ln_b, out);
}

// Round 18
// 327.103 us; speedup vs baseline: 1.4429x; 1.0274x over previous
//
#include <hip/hip_runtime.h>
#include <stdint.h>

#define BATCH 4
#define NPTS 8192
#define KNN_K 16
#define GRID 24
#define NCELL (GRID * GRID * GRID)  // 13824
#define NCELLP (NCELL + 8)          // offs stride (sentinel slot)

typedef unsigned long long u64;
typedef unsigned int u32;
typedef unsigned short u16;

// ws layout (bytes)
#define WS_IDX 0u          // u16[4*8192*16]            = 1,048,576
#define WS_LT 1048576u     // row=[varphi f32 x64 | packed bf16 (psi,alp) u32 x64] = 512B/pt -> 16MB of the 25MB slot
#define WS_ORD 17825792u   // u16[4*8192] = 65,536 (dead space inside lt slot; avoids cnt aliasing)
#define WS_CNT 26214400u   // int[4*13824]              = 221,184
#define WS_OFF 26435584u   // int[4*13832]              = 221,312
#define WS_CUR 26656896u   // int[4*13824]              = 221,184  (bbox partials before k_scan)
#define WS_SP 26878080u    // float4[4*8192]            = 524,288
#define WS_GP 27402368u    // float[4*8]                = 128
#define WS_SIDX 27402496u  // u16[4*8192]               = 65,536

#define NQBLK ((BATCH * NPTS) / 8)  // 4096 query blocks
#define NLBLK ((BATCH * NPTS) / 32) // 1024 lt blocks

__device__ __forceinline__ int cellof(float v, float o, float invs) {
  int c = (int)((v - o) * invs);
  return c < GRID - 1 ? c : GRID - 1;
}

__device__ __forceinline__ u32 f2bf(float v) {  // RNE bf16 (high 16 bits)
  u32 x = __float_as_uint(v);
  return (x + 0x7FFFu + ((x >> 16) & 1u)) >> 16;
}

typedef _Float16 hv2 __attribute__((ext_vector_type(2)));
union U32H2 { u32 u; hv2 h; };
__device__ __forceinline__ float fdot2u(u32 a, u32 b, float c) {
  U32H2 x, y; x.u = a; y.u = b;
  return __builtin_amdgcn_fdot2(x.h, y.h, c, false);
}
__device__ __forceinline__ u16 f16b(float v) {  // RNE scalar f16 bits
  union { _Float16 f; u16 b; } c; c.f = (_Float16)v; return c.b;
}
__device__ __forceinline__ u32 pkf16(float a, float b) {  // RNE pack
  return (u32)f16b(a) | ((u32)f16b(b) << 16);
}

// ---------------------------------------------------------------- K0a: partial bbox (128 blocks) + zero counters
__global__ __launch_bounds__(256) void k_bbox1(const float4* __restrict__ xytp,
                                               float* __restrict__ part,
                                               int* __restrict__ cnt) {
  const int blk = blockIdx.x;  // 0..127
  const int b = blk >> 5, sub = blk & 31;
  const int t = threadIdx.x;
#pragma unroll
  for (int i = 0; i < 2; ++i) {
    int v = t + i * 256;
    if (v < 432) cnt[blk * 432 + v] = 0;
  }
  float4 p = xytp[(b << 13) + (sub << 8) + t];
  float mnx = p.x, mny = p.y, mnz = p.z;
  float mxx = p.x, mxy = p.y, mxz = p.z;
#pragma unroll
  for (int d = 1; d < 64; d <<= 1) {
    mnx = fminf(mnx, __shfl_xor(mnx, d)); mny = fminf(mny, __shfl_xor(mny, d));
    mnz = fminf(mnz, __shfl_xor(mnz, d)); mxx = fmaxf(mxx, __shfl_xor(mxx, d));
    mxy = fmaxf(mxy, __shfl_xor(mxy, d)); mxz = fmaxf(mxz, __shfl_xor(mxz, d));
  }
  __shared__ float red[4][6];
  const int lane = t & 63, wv = t >> 6;
  if (lane == 0) {
    red[wv][0] = mnx; red[wv][1] = mny; red[wv][2] = mnz;
    red[wv][3] = mxx; red[wv][4] = mxy; red[wv][5] = mxz;
  }
  __syncthreads();
  if (t == 0) {
    for (int w = 1; w < 4; ++w) {
      red[0][0] = fminf(red[0][0], red[w][0]);
      red[0][1] = fminf(red[0][1], red[w][1]);
      red[0][2] = fminf(red[0][2], red[w][2]);
      red[0][3] = fmaxf(red[0][3], red[w][3]);
      red[0][4] = fmaxf(red[0][4], red[w][4]);
      red[0][5] = fmaxf(red[0][5], red[w][5]);
    }
    float* o = part + blk * 8;
    o[0] = red[0][0]; o[1] = red[0][1]; o[2] = red[0][2];
    o[3] = red[0][3]; o[4] = red[0][4]; o[5] = red[0][5];
  }
}

// ---------------------------------------------------------------- K2: count (R18: bbox final reduce folded in)
// Each block redundantly reduces its batch's 32 partials in-register
// (butterfly -> every lane holds the result) and computes cells from
// the local values; the first block of each batch also publishes gp
// for downstream kernels (scatter/query/main; in-order stream).
__global__ __launch_bounds__(256) void k_count(const float4* __restrict__ xytp,
                                               const float* __restrict__ part,
                                               float* __restrict__ gp,
                                               int* __restrict__ cnt) {
  int i = blockIdx.x * 256 + threadIdx.x;
  int b = i >> 13;
  const int lane = threadIdx.x & 63;
  const float* pp = part + (b * 32 + (lane & 31)) * 8;  // lanes 32..63 dup
  float mnx = pp[0], mny = pp[1], mnz = pp[2];
  float mxx = pp[3], mxy = pp[4], mxz = pp[5];
#pragma unroll
  for (int d = 1; d < 64; d <<= 1) {
    mnx = fminf(mnx, __shfl_xor(mnx, d)); mny = fminf(mny, __shfl_xor(mny, d));
    mnz = fminf(mnz, __shfl_xor(mnz, d)); mxx = fmaxf(mxx, __shfl_xor(mxx, d));
    mxy = fmaxf(mxy, __shfl_xor(mxy, d)); mxz = fmaxf(mxz, __shfl_xor(mxz, d));
  }
  float rmax = fmaxf(mxx - mnx, fmaxf(mxy - mny, mxz - mnz));
  float s = rmax / (float)GRID;
  float invs = 1.0f / s;
  if ((blockIdx.x & 31) == 0 && threadIdx.x == 0) {
    float* g = gp + b * 8;
    g[0] = mnx; g[1] = mny; g[2] = mnz;
    g[3] = s; g[4] = invs;
  }
  float4 p = xytp[i];
  int cx = cellof(p.x, mnx, invs);
  int cy = cellof(p.y, mny, invs);
  int cz = cellof(p.z, mnz, invs);
  atomicAdd(&cnt[b * NCELL + (cz * GRID + cy) * GRID + cx], 1);
}

// ---------------------------------------------------------------- K3: exclusive scan + LPT ordering (R18 fused)
// ord needs only per-cell counts/offsets (all points of a cell share
// key=min(cc-1,31); their sorted indices are [excl, excl+cc)).  After
// the scan phase: LDS histogram of POINTS per key, 32-bin prefix, then
// each cell writes its consecutive slot range.  Same LPT permutation
// as the old k_order; one launch + one memory round-trip removed.
__global__ __launch_bounds__(1024) void k_scan(const int* __restrict__ cnt,
                                               int* __restrict__ offs,
                                               int* __restrict__ curs,
                                               u16* __restrict__ ord) {
  __shared__ int wsum[16];
  __shared__ int hist[32];
  __shared__ int strt[32];
  const int b = blockIdx.x, t = threadIdx.x;
  const int base = b * NCELL;
  const int base2 = b * NCELLP;
  const int lo = t * 14;
  const int hi = lo + 14 < NCELL ? lo + 14 : NCELL;
  const int nc = hi - lo;  // <= 14
  int c14[14];
  int s = 0;
  for (int j = 0; j < nc; ++j) {
    c14[j] = cnt[base + lo + j];
    s += c14[j];
  }
  if (t < 32) hist[t] = 0;
  const int lane = t & 63, wv = t >> 6;
  int v = s;
#pragma unroll
  for (int d = 1; d < 64; d <<= 1) {
    int u = __shfl_up(v, d);
    if (lane >= d) v += u;
  }
  if (lane == 63) wsum[wv] = v;
  __syncthreads();
  if (wv == 0 && lane < 16) {
    int x = wsum[lane];
#pragma unroll
    for (int d = 1; d < 16; d <<= 1) {
      int u = __shfl_up(x, d, 16);
      if (lane >= d) x += u;
    }
    wsum[lane] = x;
  }
  __syncthreads();
  const int excl0 = (wv > 0 ? wsum[wv - 1] : 0) + v - s;
  int excl = excl0;
  for (int j = 0; j < nc; ++j) {
    offs[base2 + lo + j] = excl;
    curs[base + lo + j] = excl;
    excl += c14[j];
  }
  if (hi == NCELL) offs[base2 + NCELL] = excl;  // == NPTS
  // ---- LPT ordering phase ----
  for (int j = 0; j < nc; ++j) {
    int cc = c14[j];
    if (cc > 0) {
      int key = cc - 1 < 31 ? cc - 1 : 31;
      atomicAdd(&hist[key], cc);
    }
  }
  __syncthreads();
  if (t == 0) {
    int acc = 0;
    for (int k2 = 0; k2 < 32; ++k2) { strt[k2] = acc; acc += hist[k2]; }
  }
  __syncthreads();
  u16* ob2 = ord + (b << 13);
  int e = excl0;
  for (int j = 0; j < nc; ++j) {
    int cc = c14[j];
    if (cc > 0) {
      int key = cc - 1 < 31 ? cc - 1 : 31;
      int pos = atomicAdd(&strt[key], cc);
      for (int q2 = 0; q2 < cc; ++q2) ob2[pos + q2] = (u16)(e + q2);
    }
    e += cc;
  }
}

// ---------------------------------------------------------------- K4: scatter (cell-sorted points, sq in .w, idx in sidx)
__global__ __launch_bounds__(256) void k_scatter(const float4* __restrict__ xytp,
                                                 const float* __restrict__ gp,
                                                 int* __restrict__ curs,
                                                 float4* __restrict__ spts,
                                                 u16* __restrict__ sidx) {
  int i = blockIdx.x * 256 + threadIdx.x;
  int b = i >> 13, n = i & 8191;
  const float* g = gp + b * 8;
  float4 p = xytp[i];
  int cx = cellof(p.x, g[0], g[4]);
  int cy = cellof(p.y, g[1], g[4]);
  int cz = cellof(p.z, g[2], g[4]);
  int pos = atomicAdd(&curs[b * NCELL + (cz * GRID + cy) * GRID + cx], 1);
  float sq = fmaf(p.z, p.z, fmaf(p.y, p.y, p.x * p.x));
  spts[(b << 13) + pos] = make_float4(p.x, p.y, p.z, sq);
  sidx[(b << 13) + pos] = (u16)n;
}

// ---------------------------------------------------------------- K5: FUSED grid-KNN query + lt GEMM (R17)
#define INSERTC(Af, OI)                                                      \
  {                                                                          \
    float dot = q.x * (Af).x;                                                \
    dot = fmaf(q.y, (Af).y, dot);                                            \
    dot = fmaf(q.z, (Af).z, dot);                                            \
    float d2 = (qsq + (Af).w) - 2.0f * dot;                                  \
    unsigned u = __float_as_uint(d2);                                        \
    u ^= (0x80000000u | (unsigned)((int)u >> 31));                           \
    u64 key = ((u64)u << 32) | (OI);                                         \
    if (key < lst[15]) {                                                     \
      u64 x = key;                                                           \
      _Pragma("unroll") for (int p = 0; p < 16; ++p) {                       \
        bool sw = x < lst[p];                                                \
        u64 a = lst[p];                                                      \
        lst[p] = sw ? x : a;                                                 \
        x = sw ? a : x;                                                      \
      }                                                                      \
    }                                                                        \
  }

#define CSWAP(ia, ib)                                                        \
  {                                                                          \
    u64 ta = c[ia], tb2 = c[ib];                                             \
    bool sw = ta > tb2;                                                      \
    c[ia] = sw ? tb2 : ta;                                                   \
    c[ib] = sw ? ta : tb2;                                                   \
  }

__global__ __launch_bounds__(256) void k_query(
    const float4* __restrict__ spts, const u16* __restrict__ sidx,
    const int* __restrict__ offs, const float* __restrict__ gp,
    const u16* __restrict__ ord, u16* __restrict__ oidx,
    const float* __restrict__ feat, const float* __restrict__ ltw,
    const float* __restrict__ ltb, float* __restrict__ lt) {
  __shared__ float sw_c[16][196];  // lt path only (14.8KB total)
  __shared__ float sf_c[32][18];
  const int tid = threadIdx.x;

  if (blockIdx.x >= NQBLK) {
    // ---------------- lt path: 32 points per block, 4 j-chunks ----------
    const int r0 = (blockIdx.x - NQBLK) * 32;
    const int r = tid >> 3;
    const int c0 = (tid & 7) * 8;  // 8 channels, same across 3 sections
    float acc[24];                 // [0..7]=varphi, [8..15]=psi, [16..23]=alp
#pragma unroll
    for (int m = 0; m < 8; ++m) {
      acc[m] = ltb[c0 + m];
      acc[8 + m] = ltb[64 + c0 + m];
      acc[16 + m] = ltb[128 + c0 + m];
    }
    for (int ch = 0; ch < 4; ++ch) {
#pragma unroll
      for (int i = 0; i < 3; ++i) {
        int f = tid + i * 256;
        int row = f / 48, col4 = f % 48;
        float4 w4 = ((const float4*)ltw)[(ch * 16 + row) * 48 + col4];
        *(float4*)&sw_c[row][col4 * 4] = w4;
      }
      {
        int v = tid * 2;
        int row = v >> 4, jj = v & 15;
        const float2 f2 =
            *(const float2*)(feat + (size_t)(r0 + row) * 64 + ch * 16 + jj);
        sf_c[row][jj] = f2.x;
        sf_c[row][jj + 1] = f2.y;
      }
      __syncthreads();
#pragma unroll 4
      for (int jj = 0; jj < 16; ++jj) {
        float f = sf_c[r][jj];
#pragma unroll
        for (int sec = 0; sec < 3; ++sec) {
          float4 w4a = *(const float4*)&sw_c[jj][sec * 64 + c0];
          float4 w4b = *(const float4*)&sw_c[jj][sec * 64 + c0 + 4];
          acc[sec * 8 + 0] = fmaf(f, w4a.x, acc[sec * 8 + 0]);
          acc[sec * 8 + 1] = fmaf(f, w4a.y, acc[sec * 8 + 1]);
          acc[sec * 8 + 2] = fmaf(f, w4a.z, acc[sec * 8 + 2]);
          acc[sec * 8 + 3] = fmaf(f, w4a.w, acc[sec * 8 + 3]);
          acc[sec * 8 + 4] = fmaf(f, w4b.x, acc[sec * 8 + 4]);
          acc[sec * 8 + 5] = fmaf(f, w4b.y, acc[sec * 8 + 5]);
          acc[sec * 8 + 6] = fmaf(f, w4b.z, acc[sec * 8 + 6]);
          acc[sec * 8 + 7] = fmaf(f, w4b.w, acc[sec * 8 + 7]);
        }
      }
      __syncthreads();
    }
    float* orow = lt + (size_t)(r0 + r) * 128;
    *(float4*)&orow[c0] = make_float4(acc[0], acc[1], acc[2], acc[3]);
    *(float4*)&orow[c0 + 4] = make_float4(acc[4], acc[5], acc[6], acc[7]);
    u32 pk[8];
#pragma unroll
    for (int m = 0; m < 8; ++m)
      pk[m] = f2bf(acc[8 + m]) | (f2bf(acc[16 + m]) << 16);
    u32* prow = (u32*)orow + 64 + c0;
    *(uint4*)&prow[0] = make_uint4(pk[0], pk[1], pk[2], pk[3]);
    *(uint4*)&prow[4] = make_uint4(pk[4], pk[5], pk[6], pk[7]);
    return;
  }

  // ---------------- query path (R22, unchanged) ----------------
  const int lane = tid & 63;
  const int l = tid & 31;        // team lane
  const int qid = blockIdx.x * 8 + (tid >> 5);  // 8 teams/block
  const int b = qid >> 13;
  const int i = ord[(b << 13) + (qid & 8191)];  // LPT permutation
  const int tb = lane & 32;      // team base within wave (0 or 32)
  const float4* __restrict__ sp = spts + (b << 13);
  const u16* __restrict__ sx = sidx + (b << 13);
  const int* __restrict__ ob = offs + b * NCELLP;
  const float* g = gp + b * 8;
  float4 q = sp[i];
  const float qsq = q.w;  // sq precomputed
  const unsigned orig = sx[i];
  const int cx = cellof(q.x, g[0], g[4]);
  const int cy = cellof(q.y, g[1], g[4]);
  const int cz = cellof(q.z, g[2], g[4]);
  const float s = g[3];
  const float fx = q.x - fmaf((float)cx, s, g[0]);
  const float fy = q.y - fmaf((float)cy, s, g[1]);
  const float fz = q.z - fmaf((float)cz, s, g[2]);
  const float mn = fmaxf(
      0.0f, fminf(fminf(fminf(fx, s - fx), fminf(fy, s - fy)),
                  fminf(fz, s - fz)));

  u64 lst[16];
#pragma unroll
  for (int p = 0; p < 16; ++p) lst[p] = ~0ULL;

  for (int r = 0; r <= GRID; ++r) {
    const int W = 2 * r + 1;
    const int nent = 2 * W * W;
    for (int cb = 0; cb < nent; cb += 32) {
      int ms0 = 0, ms1 = 0;
      const int eid = cb + l;
      if (eid < nent) {
        const int rid = eid >> 1, side = eid & 1;
        const int dz = rid / W - r;
        const int dy = rid % W - r;
        const int z2 = cz + dz, y2 = cy + dy;
        if ((unsigned)z2 < GRID && (unsigned)y2 < GRID) {
          const int rowb = (z2 * GRID + y2) * GRID;
          const bool bdry = (dz == -r) || (dz == r) || (dy == -r) || (dy == r);
          if (bdry) {
            if (side == 0) {
              const int xl = cx - r < 0 ? 0 : cx - r;
              const int xh = cx + r > GRID - 1 ? GRID - 1 : cx + r;
              ms0 = ob[rowb + xl];
              ms1 = ob[rowb + xh + 1];
            }
          } else {
            const int x2 = side ? cx + r : cx - r;
            if ((unsigned)x2 < GRID) {
              ms0 = ob[rowb + x2];
              ms1 = ob[rowb + x2 + 1];
            }
          }
        }
      }
      const int len = ms1 - ms0;  // >= 0
      int pre = len;
#pragma unroll
      for (int d = 1; d < 32; d <<= 1) {
        int u2 = __shfl_up(pre, d);
        if (l >= d) pre += u2;
      }
      const int total = __shfl(pre, tb + 31);
      if (total == 0) continue;
      const int base = ms0 - (pre - len);  // ms0 - exclusive_prefix
      for (int vb = 0; vb < total; vb += 32) {
        const int vidx = vb + l;
        int e = 0;
#pragma unroll
        for (int s2 = 16; s2 >= 1; s2 >>= 1) {
          int pv = __shfl(pre, tb + e + s2 - 1);
          if (pv <= vidx) e += s2;
        }
        const int jb = __shfl(base, tb + e);
        if (vidx < total) {
          const int j = jb + vidx;
          float4 A = sp[j];
          unsigned oi = sx[j];
          INSERTC(A, oi)
        }
      }
    }
    const float rs = fmaf((float)r, s, mn);
    const float T = fmaf(rs, rs, -1e-4f);
    unsigned tu = __float_as_uint(T);
    tu ^= (0x80000000u | (unsigned)((int)tu >> 31));
    int c = 0;
#pragma unroll
    for (int p = 0; p < 16; ++p) c += ((unsigned)(lst[p] >> 32) <= tu) ? 1 : 0;
    c += __shfl_xor(c, 1);
    c += __shfl_xor(c, 2);
    c += __shfl_xor(c, 4);
    c += __shfl_xor(c, 8);
    c += __shfl_xor(c, 16);
    if (c >= 16) break;  // team-uniform break
  }

#pragma unroll
  for (int mm = 1; mm <= 16; mm <<= 1) {
    u64 c[16];
    const bool keepmin = (l & mm) == 0;
#pragma unroll
    for (int p = 0; p < 16; ++p) {
      u64 o = __shfl_xor(lst[15 - p], mm);
      u64 a = lst[p];
      u64 lo = a < o ? a : o;
      u64 hi = a < o ? o : a;
      c[p] = keepmin ? lo : hi;
    }
    CSWAP(0, 8) CSWAP(1, 9) CSWAP(2, 10) CSWAP(3, 11)
    CSWAP(4, 12) CSWAP(5, 13) CSWAP(6, 14) CSWAP(7, 15)
    CSWAP(0, 4) CSWAP(1, 5) CSWAP(2, 6) CSWAP(3, 7)
    CSWAP(8, 12) CSWAP(9, 13) CSWAP(10, 14) CSWAP(11, 15)
    CSWAP(0, 2) CSWAP(1, 3) CSWAP(4, 6) CSWAP(5, 7)
    CSWAP(8, 10) CSWAP(9, 11) CSWAP(12, 14) CSWAP(13, 15)
    CSWAP(0, 1) CSWAP(2, 3) CSWAP(4, 5) CSWAP(6, 7)
    CSWAP(8, 9) CSWAP(10, 11) CSWAP(12, 13) CSWAP(14, 15)
#pragma unroll
    for (int p = 0; p < 16; ++p) lst[p] = c[p];
  }

  if (l == 0) {  // team lane 0 holds the sorted team top-16
    unsigned pk[8];
#pragma unroll
    for (int k = 0; k < 16; k += 2)
      pk[k >> 1] = (unsigned)(lst[k] & 0xFFFFull) |
                   ((unsigned)(lst[k + 1] & 0xFFFFull) << 16);
    unsigned* od = (unsigned*)(oidx + (((size_t)(b << 13) + orig) << 4));
#pragma unroll
    for (int k = 0; k < 8; ++k) od[k] = pk[k];
  }
}

// ---------------------------------------------------------------- K7: main
// R15b: second-layer matvec via v_dot2_f32_f16 (h in LDS as f16, w2 as
// packed-f16 u32).  Packed bf16 psi/alp gathers + pf-2 unchanged.
template <int CTRL>
__device__ __forceinline__ float dpp_add_f(float x) {
  int y = __builtin_amdgcn_update_dpp(0, __float_as_int(x), CTRL, 0xf, 0xf,
                                      true);
  return x + __int_as_float(y);
}
__device__ __forceinline__ float wave_sum64(float x) {
  x = dpp_add_f<0x111>(x);  // row_shr:1
  x = dpp_add_f<0x112>(x);  // row_shr:2
  x = dpp_add_f<0x114>(x);  // row_shr:4
  x = dpp_add_f<0x118>(x);  // row_shr:8
  x = dpp_add_f<0x142>(x);  // row_bcast:15
  x = dpp_add_f<0x143>(x);  // row_bcast:31
  return __int_as_float(__builtin_amdgcn_readlane(__float_as_int(x), 63));
}

__global__ __launch_bounds__(256) void k_main(
    const float4* __restrict__ xytp, const float* __restrict__ lt,
    const u16* __restrict__ knn, const float* __restrict__ pe_w1,
    const float* __restrict__ pe_b1, const float* __restrict__ pe_w2,
    const float* __restrict__ pe_b2, const float* __restrict__ ln_g,
    const float* __restrict__ ln_b, float* __restrict__ out) {
  __shared__ u16 s_h[4][16][64];  // f16 bits; [wave][k][channel]
  const int lane = threadIdx.x & 63;
  const int wave = threadIdx.x >> 6;
  const int pid = __builtin_amdgcn_readfirstlane(blockIdx.x * 4 + wave);
  const int b = pid >> 13;
  const int n = pid & 8191;

  float w1c[4];
#pragma unroll
  for (int d = 0; d < 4; ++d) w1c[d] = pe_w1[d * 64 + lane];
  const float b1c = pe_b1[lane];
  // w2 packed: word m = (w2[2m][lane], w2[2m+1][lane]) as f16 pair
  u32 w2pk[32];
#pragma unroll
  for (int m2 = 0; m2 < 32; ++m2) {
    float a = pe_w2[(2 * m2) * 64 + lane];
    float bb = pe_w2[(2 * m2 + 1) * 64 + lane];
    w2pk[m2] = pkf16(a, bb);
  }
  const float b2c = pe_b2[lane];
  const float gc = ln_g[lane], bc = ln_b[lane];

  int nb[16];
#pragma unroll
  for (int k = 0; k < 16; ++k) nb[k] = knn[pid * 16 + k];

  const float* __restrict__ ltb = lt + (size_t)(b << 13) * 128;
  const float vc = ltb[(size_t)n * 128 + lane];

  const float4 qv = xytp[(b << 13) + n];
#pragma unroll
  for (int k = 0; k < 16; ++k) {
    float4 g = xytp[(b << 13) + nb[k]];
    float r0 = qv.x - g.x, r1 = qv.y - g.y, r2 = qv.z - g.z, r3 = qv.w - g.w;
    float h = fmaf(r3, w1c[3],
                   fmaf(r2, w1c[2], fmaf(r1, w1c[1], fmaf(r0, w1c[0], b1c))));
    s_h[wave][k][lane] = f16b(fmaxf(h, 0.0f));
  }
  __syncthreads();

  // prefetch distance 2: packed psi/alp u32, static A/B slot rotation
  u32 uA = ((const u32*)(ltb + (size_t)nb[0] * 128 + 64))[lane];
  u32 uB = ((const u32*)(ltb + (size_t)nb[1] * 128 + 64))[lane];
  float m = -INFINITY, se = 0.f, oacc = 0.f;
#pragma unroll
  for (int k = 0; k < 16; ++k) {
    const u32 uc = (k & 1) ? uB : uA;
    if (k < 14) {  // refill the slot just consumed with row k+2
      const u32* prow = (const u32*)(ltb + (size_t)nb[k + 2] * 128 + 64);
      if (k & 1) uB = prow[lane];
      else       uA = prow[lane];
    }
    const float psi_c = __uint_as_float(uc << 16);
    const float alp_c = __uint_as_float(uc & 0xFFFF0000u);
    float acc = b2c;
    const uint4* hp = (const uint4*)&s_h[wave][k][0];  // broadcast reads
#pragma unroll
    for (int j4 = 0; j4 < 8; ++j4) {
      uint4 hv = hp[j4];
      acc = fdot2u(hv.x, w2pk[j4 * 4 + 0], acc);
      acc = fdot2u(hv.y, w2pk[j4 * 4 + 1], acc);
      acc = fdot2u(hv.z, w2pk[j4 * 4 + 2], acc);
      acc = fdot2u(hv.w, w2pk[j4 * 4 + 3], acc);
    }
    const float pre = (vc - psi_c) + acc;
    const float apd = alp_c + acc;
    const float sm = wave_sum64(pre);
    const float ssm = wave_sum64(pre * pre);
    const float mu = sm * 0.015625f;
    const float var = fmaf(ssm, 0.015625f, -mu * mu);
    const float inv = rsqrtf(var + 1e-5f);
    const float x = fmaf((pre - mu) * inv, gc, bc) * 0.125f;
    const float mn = fmaxf(m, x);
    const float corr = __expf(m - mn);
    const float e = __expf(x - mn);
    se = fmaf(se, corr, e);
    oacc = fmaf(oacc, corr, e * apd);
    m = mn;
  }
  out[(size_t)pid * 64 + lane] = oacc / se;
}

// ---------------------------------------------------------------- launch
extern "C" void kernel_launch(void* const* d_in, const int* in_sizes, int n_in,
                              void* d_out, int out_size, void* d_ws,
                              size_t ws_size, hipStream_t stream) {
  const float4* xytp = (const float4*)d_in[0];
  const float* features = (const float*)d_in[1];
  const float* pe_w1 = (const float*)d_in[2];
  const float* pe_b1 = (const float*)d_in[3];
  const float* pe_w2 = (const float*)d_in[4];
  const float* pe_b2 = (const float*)d_in[5];
  const float* lt_w = (const float*)d_in[6];
  const float* lt_b = (const float*)d_in[7];
  const float* ln_g = (const float*)d_in[8];
  const float* ln_b = (const float*)d_in[9];
  float* out = (float*)d_out;

  char* ws = (char*)d_ws;
  u16* idxbuf = (u16*)(ws + WS_IDX);
  float* lt = (float*)(ws + WS_LT);
  int* cnt = (int*)(ws + WS_CNT);
  int* offs = (int*)(ws + WS_OFF);
  int* curs = (int*)(ws + WS_CUR);
  float4* spts = (float4*)(ws + WS_SP);
  float* gp = (float*)(ws + WS_GP);
  u16* sidx = (u16*)(ws + WS_SIDX);
  u16* ordb = (u16*)(ws + WS_ORD);  // dead space inside lt slot

  k_bbox1<<<128, 256, 0, stream>>>(xytp, (float*)(ws + WS_CUR), cnt);
  k_count<<<(BATCH * NPTS) / 256, 256, 0, stream>>>(
      xytp, (const float*)(ws + WS_CUR), gp, cnt);
  k_scan<<<BATCH, 1024, 0, stream>>>(cnt, offs, curs, ordb);
  k_scatter<<<(BATCH * NPTS) / 256, 256, 0, stream>>>(xytp, gp, curs, spts,
                                                      sidx);
  k_query<<<NQBLK + NLBLK, 256, 0, stream>>>(spts, sidx, offs, gp, ordb,
                                             idxbuf, features, lt_w, lt_b,
                                             lt);
  k_main<<<(BATCH * NPTS) / 4, 256, 0, stream>>>(xytp, lt, idxbuf, pe_w1,
                                                 pe_b1, pe_w2, pe_b2, ln_g,
                                                 ln_b, out);
}